// Round 13
// baseline (886.239 us; speedup 1.0000x reference)
//
#include <hip/hip_runtime.h>
#include <math.h>

constexpr int cB = 128, cS = 256, cF = 10, cE = 40, cNH = 8, cDH = 5;
constexpr int cI = 128, cMDH = 16, cK = 4;

typedef __attribute__((ext_vector_type(8))) short short8v;   // 8 bf16 (4 VGPRs)
typedef __attribute__((ext_vector_type(4))) float f32x4;

#define BC8(v, l) __uint_as_float(__builtin_amdgcn_ds_swizzle(__float_as_uint(v), ((l) << 5) | 0x18))

__device__ __forceinline__ short f2bf(float f) {      // fp32 -> bf16 RTNE
    unsigned u = __float_as_uint(f);
    u += 0x7FFF + ((u >> 16) & 1);
    return (short)(u >> 16);
}

// ---------------- h = x @ in_w.T + in_b + pos_encoding ----------------
__global__ __launch_bounds__(256) void init_k(const float* __restrict__ x, const float* __restrict__ w,
                                              const float* __restrict__ b, float* __restrict__ h) {
    int idx = blockIdx.x * 256 + threadIdx.x;     // B*S*E
    int e = idx % cE; int bs = idx / cE; int s = bs % cS;
    float acc = b[e];
    const float* xr = x + (size_t)bs * cF;
#pragma unroll
    for (int f = 0; f < cF; ++f) acc += xr[f] * w[e * cF + f];
    int i2 = e >> 1;
    float div = expf(-(float)(2 * i2) * (logf(10000.f) / 40.0f));
    float arg = (float)s * div;
    acc += (e & 1) ? cosf(arg) : sinf(arg);
    h[idx] = acc;
}

// ---------------- fused LayerNorm + up-projection (E=40 -> 256) v3 ----------------
// Writes xm (first 128 outs) and z (last 128) to SEPARATE dense arrays so every
// downstream read (conv taps, qkv-v, down_mhn-z) is stride-free.
__global__ __launch_bounds__(256) void ln_up_k(const float* __restrict__ h, const float* __restrict__ lnw,
                                               const float* __restrict__ upw,
                                               float* __restrict__ xm, float* __restrict__ zb) {
    __shared__ float lnr[16][cE];
    __shared__ float wT[cE * 257];
    int row0 = blockIdx.x * 16;
    int tid = threadIdx.x;
    for (int j = tid; j < 2560; j += 256) {       // 256*40/4 float4s
        float4 v = ((const float4*)upw)[j];
        int o = j / 10, kq = (j - o * 10) * 4;
        wT[(kq + 0) * 257 + o] = v.x;
        wT[(kq + 1) * 257 + o] = v.y;
        wT[(kq + 2) * 257 + o] = v.z;
        wT[(kq + 3) * 257 + o] = v.w;
    }
    if (tid < 16) {
        const float* r = h + (size_t)(row0 + tid) * cE;
        float mu = 0.f;
        for (int k = 0; k < cE; ++k) mu += r[k];
        mu *= (1.f / cE);
        float va = 0.f;
        for (int k = 0; k < cE; ++k) { float d = r[k] - mu; va += d * d; }
        va *= (1.f / cE);
        float rs = rsqrtf(va + 1e-5f);
        for (int k = 0; k < cE; ++k) lnr[tid][k] = (r[k] - mu) * rs * lnw[k];
    }
    __syncthreads();
    int o = tid;
    float acc[16];
#pragma unroll
    for (int r = 0; r < 16; ++r) acc[r] = 0.f;
    for (int k = 0; k < cE; ++k) {
        float wv = wT[k * 257 + o];
#pragma unroll
        for (int r = 0; r < 16; ++r) acc[r] = fmaf(lnr[r][k], wv, acc[r]);
    }
    if (o < 128) {
#pragma unroll
        for (int r = 0; r < 16; ++r) xm[(size_t)(row0 + r) * cI + o] = acc[r];
    } else {
#pragma unroll
        for (int r = 0; r < 16; ++r) zb[(size_t)(row0 + r) * cI + (o - 128)] = acc[r];
    }
}

// ---------------- fused depthwise causal conv (K=4) + SiLU + block-diag qkv ----------------
// Thread = (row, 4-channel group n): 4 coalesced float4 conv taps from dense xm,
// silu, then the 4x4 block-diagonal q,k,v (weights L1-resident). Replaces the
// separate conv_silu<128> + qkv_k kernels and qkv's 16.7MB xc re-read.
__global__ __launch_bounds__(256) void convqkv_k(const float* __restrict__ xm, const float* __restrict__ cw,
                                                 const float* __restrict__ cb,
                                                 const float* __restrict__ qw, const float* __restrict__ kw,
                                                 const float* __restrict__ vw,
                                                 float* __restrict__ xc, float* __restrict__ qb,
                                                 float* __restrict__ kb, float* __restrict__ vb) {
    int idx = blockIdx.x * 256 + threadIdx.x;   // B*S*32
    int n = idx & 31; int bs = idx >> 5; int s = bs & 255;
    int c0 = n * 4;
    float4 acc = ((const float4*)cb)[n];
#pragma unroll
    for (int j = 0; j < 4; ++j) {
        int sj = s - 3 + j;
        if (sj >= 0) {
            float4 t = ((const float4*)(xm + (size_t)(bs - 3 + j) * cI))[n];
            acc.x = fmaf(t.x, cw[(c0 + 0) * 4 + j], acc.x);
            acc.y = fmaf(t.y, cw[(c0 + 1) * 4 + j], acc.y);
            acc.z = fmaf(t.z, cw[(c0 + 2) * 4 + j], acc.z);
            acc.w = fmaf(t.w, cw[(c0 + 3) * 4 + j], acc.w);
        }
    }
    float xv[4];
    xv[0] = acc.x / (1.f + __expf(-acc.x));
    xv[1] = acc.y / (1.f + __expf(-acc.y));
    xv[2] = acc.z / (1.f + __expf(-acc.z));
    xv[3] = acc.w / (1.f + __expf(-acc.w));
    ((float4*)(xc + (size_t)bs * cI))[n] = make_float4(xv[0], xv[1], xv[2], xv[3]);

    float4 m4 = ((const float4*)(xm + (size_t)bs * cI))[n];
    float mv[4] = {m4.x, m4.y, m4.z, m4.w};
    const float* qwp = qw + n * 16;
    const float* kwp = kw + n * 16;
    const float* vwp = vw + n * 16;
    float qo[4], ko[4], vo[4];
#pragma unroll
    for (int o = 0; o < 4; ++o) {
        float aq = 0.f, ak = 0.f, av = 0.f;
#pragma unroll
        for (int i = 0; i < 4; ++i) {
            aq = fmaf(xv[i], qwp[o * 4 + i], aq);
            ak = fmaf(xv[i], kwp[o * 4 + i], ak);
            av = fmaf(mv[i], vwp[o * 4 + i], av);
        }
        qo[o] = aq; ko[o] = ak; vo[o] = av;
    }
    ((float4*)(qb + (size_t)bs * cI))[n] = make_float4(qo[0], qo[1], qo[2], qo[3]);
    ((float4*)(kb + (size_t)bs * cI))[n] = make_float4(ko[0], ko[1], ko[2], ko[3]);
    ((float4*)(vb + (size_t)bs * cI))[n] = make_float4(vo[0], vo[1], vo[2], vo[3]);
}

// ---------------- depthwise causal conv (K=4) + SiLU (slstm path, C=40) ----------------
template <int C>
__global__ __launch_bounds__(256) void conv_silu_k(const float* __restrict__ in, int instride,
                                                   const float* __restrict__ w, const float* __restrict__ bias,
                                                   float* __restrict__ out) {
    int idx = blockIdx.x * 256 + threadIdx.x;   // B*S*C
    int c = idx % C; int bs = idx / C; int s = bs % cS;
    float acc = bias[c];
#pragma unroll
    for (int j = 0; j < cK; ++j) {
        int sj = s - 3 + j;
        if (sj >= 0) acc += in[(size_t)(bs + j - 3) * instride + c] * w[c * cK + j];
    }
    float sg = 1.f / (1.f + __expf(-acc));
    out[idx] = acc * sg;
}

// ---------------- input/forget gate pre-activations ip, fp (B,NH,S) v3 ----------------
__global__ __launch_bounds__(256, 2) void gates_k(const float* __restrict__ qb, const float* __restrict__ kb,
                                                  const float* __restrict__ vb, const float* __restrict__ igw,
                                                  const float* __restrict__ igb, const float* __restrict__ fgw,
                                                  const float* __restrict__ fgb,
                                                  float* __restrict__ ipb, float* __restrict__ fpb) {
    __shared__ float g[32 * 388];
    __shared__ float w[16 * 388];
    int row0 = blockIdx.x * 32;
    int tid = threadIdx.x;

    for (int i = tid; i < 16 * 96; i += 256) {
        int r = i / 96, c4 = i - r * 96;
        const float* src = (r < 8) ? (igw + r * 384) : (fgw + (r - 8) * 384);
        *(float4*)&w[r * 388 + c4 * 4] = ((const float4*)src)[c4];
    }
    for (int i = tid; i < 32 * 96; i += 256) {
        int r = i / 96, c4 = i - r * 96;
        size_t gr = (size_t)(row0 + r) * cI;
        const float4* src = (c4 < 32) ? (const float4*)(qb + gr) + c4
                          : (c4 < 64) ? (const float4*)(kb + gr) + (c4 - 32)
                                      : (const float4*)(vb + gr) + (c4 - 64);
        *(float4*)&g[r * 388 + c4 * 4] = *src;
    }
    __syncthreads();

    int rp = tid >> 3;              // row 0..31
    int hp = tid & 7;               // out-pair 0..7
    int o0 = 2 * hp, o1 = o0 + 1;

    const float4* gp = (const float4*)(g + rp * 388);
    const float4* w0p = (const float4*)(w + o0 * 388);
    const float4* w1p = (const float4*)(w + o1 * 388);

    float a0e = 0.f, a0o = 0.f, a1e = 0.f, a1o = 0.f;
#pragma unroll 2
    for (int c4 = 0; c4 < 96; c4 += 2) {
        float4 gv0 = gp[c4], gv1 = gp[c4 + 1];
        float4 wa0 = w0p[c4], wa1 = w0p[c4 + 1];
        float4 wb0 = w1p[c4], wb1 = w1p[c4 + 1];
        a0e = fmaf(gv0.x, wa0.x, a0e); a0e = fmaf(gv0.y, wa0.y, a0e);
        a0e = fmaf(gv0.z, wa0.z, a0e); a0e = fmaf(gv0.w, wa0.w, a0e);
        a1e = fmaf(gv0.x, wb0.x, a1e); a1e = fmaf(gv0.y, wb0.y, a1e);
        a1e = fmaf(gv0.z, wb0.z, a1e); a1e = fmaf(gv0.w, wb0.w, a1e);
        a0o = fmaf(gv1.x, wa1.x, a0o); a0o = fmaf(gv1.y, wa1.y, a0o);
        a0o = fmaf(gv1.z, wa1.z, a0o); a0o = fmaf(gv1.w, wa1.w, a0o);
        a1o = fmaf(gv1.x, wb1.x, a1o); a1o = fmaf(gv1.y, wb1.y, a1o);
        a1o = fmaf(gv1.z, wb1.z, a1o); a1o = fmaf(gv1.w, wb1.w, a1o);
    }
    float a0 = a0e + a0o, a1 = a1e + a1o;

    int h0 = o0 & 7, wch0 = o0 >> 3;
    int h1 = o1 & 7, wch1 = o1 >> 3;
    float b0 = wch0 ? fgb[h0] : igb[h0];
    float b1 = wch1 ? fgb[h1] : igb[h1];
    int grow = row0 + rp;
    int bb = grow >> 8, ss = grow & 255;
    float* d0 = (wch0 ? fpb : ipb) + (size_t)(bb * cNH + h0) * cS + ss;
    float* d1 = (wch1 ? fpb : ipb) + (size_t)(bb * cNH + h1) * cS + ss;
    *d0 = a0 + b0; *d1 = a1 + b1;
}

// ---------------- fused mLSTM attention v7: MFMA (bf16), balanced tiles ----------------
constexpr int QKW = 24;    // Qb/Kb row width (shorts)
constexpr int VTW = 264;   // Vt row width
constexpr int CBW = 280;   // C row width

__global__ __launch_bounds__(256, 2) void attn_k(const float* __restrict__ qg, const float* __restrict__ kg,
                                                 const float* __restrict__ vg, const float* __restrict__ ipg,
                                                 const float* __restrict__ fpg, float* __restrict__ hatt) {
    int bh = blockIdx.x; int b = bh >> 3, h = bh & 7;
    int tid = threadIdx.x;
    int wid = tid >> 6, lane = tid & 63;
    int colL = lane & 15, grp = lane >> 4;

    __shared__ float sEA[cS], sMx[cS], sFc[cS];
    __shared__ short sQ[cS * QKW], sK[cS * QKW];
    __shared__ short sVt[cMDH * VTW];
    __shared__ short sC[4][16 * CBW];

    {
        const float4 fp4 = ((const float4*)(fpg + (size_t)bh * cS))[lane];
        const float4 ip4 = ((const float4*)(ipg + (size_t)bh * cS))[lane];
        float fpa[4] = {fp4.x, fp4.y, fp4.z, fp4.w};
        float ipa[4] = {ip4.x, ip4.y, ip4.z, ip4.w};
        float p[4];
        float run = 0.f;
#pragma unroll
        for (int i = 0; i < 4; ++i) {
            float xx = fpa[i];
            float lsg = fminf(xx, 0.f) - log1pf(expf(-fabsf(xx)));
            run += lsg; p[i] = run;
        }
        float cum = p[3];
#pragma unroll
        for (int off = 1; off < 64; off <<= 1) { float t = __shfl_up(cum, off); if (lane >= off) cum += t; }
        float excl = cum - p[3];
        float aa[4];
#pragma unroll
        for (int i = 0; i < 4; ++i) {
            float fcv = excl + p[i];
            aa[i] = ipa[i] - fcv;
            sFc[lane * 4 + i] = fcv;
            sEA[lane * 4 + i] = __expf(aa[i]);
        }
        float mq[4]; mq[0] = aa[0];
#pragma unroll
        for (int i = 1; i < 4; ++i) mq[i] = fmaxf(mq[i - 1], aa[i]);
        float cm = mq[3];
#pragma unroll
        for (int off = 1; off < 64; off <<= 1) { float t = __shfl_up(cm, off); if (lane >= off) cm = fmaxf(cm, t); }
        float exm = __shfl_up(cm, 1);
        if (lane == 0) exm = -3.0e38f;
#pragma unroll
        for (int i = 0; i < 4; ++i) sMx[lane * 4 + i] = fmaxf(exm, mq[i]);
    }

    {
        int t = tid;
        const float4* qp = (const float4*)(qg + ((size_t)(b * cS) + t) * cI + h * cMDH);
        const float4* kp = (const float4*)(kg + ((size_t)(b * cS) + t) * cI + h * cMDH);
        const float4* vp = (const float4*)(vg + ((size_t)(b * cS) + t) * cI + h * cMDH);
        float4 q0 = qp[0], q1 = qp[1], q2 = qp[2], q3 = qp[3];
        float4 k0 = kp[0], k1 = kp[1], k2 = kp[2], k3 = kp[3];
        float4 v0 = vp[0], v1 = vp[1], v2 = vp[2], v3 = vp[3];
        short8v qa, qbv, ka, kbv;
        qa[0] = f2bf(q0.x); qa[1] = f2bf(q0.y); qa[2] = f2bf(q0.z); qa[3] = f2bf(q0.w);
        qa[4] = f2bf(q1.x); qa[5] = f2bf(q1.y); qa[6] = f2bf(q1.z); qa[7] = f2bf(q1.w);
        qbv[0] = f2bf(q2.x); qbv[1] = f2bf(q2.y); qbv[2] = f2bf(q2.z); qbv[3] = f2bf(q2.w);
        qbv[4] = f2bf(q3.x); qbv[5] = f2bf(q3.y); qbv[6] = f2bf(q3.z); qbv[7] = f2bf(q3.w);
        ka[0] = f2bf(k0.x); ka[1] = f2bf(k0.y); ka[2] = f2bf(k0.z); ka[3] = f2bf(k0.w);
        ka[4] = f2bf(k1.x); ka[5] = f2bf(k1.y); ka[6] = f2bf(k1.z); ka[7] = f2bf(k1.w);
        kbv[0] = f2bf(k2.x); kbv[1] = f2bf(k2.y); kbv[2] = f2bf(k2.z); kbv[3] = f2bf(k2.w);
        kbv[4] = f2bf(k3.x); kbv[5] = f2bf(k3.y); kbv[6] = f2bf(k3.z); kbv[7] = f2bf(k3.w);
        *(short8v*)(sQ + t * QKW) = qa;
        *(short8v*)(sQ + t * QKW + 8) = qbv;
        *(short8v*)(sK + t * QKW) = ka;
        *(short8v*)(sK + t * QKW + 8) = kbv;
        sVt[0 * VTW + t] = f2bf(v0.x);  sVt[1 * VTW + t] = f2bf(v0.y);
        sVt[2 * VTW + t] = f2bf(v0.z);  sVt[3 * VTW + t] = f2bf(v0.w);
        sVt[4 * VTW + t] = f2bf(v1.x);  sVt[5 * VTW + t] = f2bf(v1.y);
        sVt[6 * VTW + t] = f2bf(v1.z);  sVt[7 * VTW + t] = f2bf(v1.w);
        sVt[8 * VTW + t] = f2bf(v2.x);  sVt[9 * VTW + t] = f2bf(v2.y);
        sVt[10 * VTW + t] = f2bf(v2.z); sVt[11 * VTW + t] = f2bf(v2.w);
        sVt[12 * VTW + t] = f2bf(v3.x); sVt[13 * VTW + t] = f2bf(v3.y);
        sVt[14 * VTW + t] = f2bf(v3.z); sVt[15 * VTW + t] = f2bf(v3.w);
    }
    __syncthreads();

    const short one_bf = (short)0x3F80;
    short8v ones = {one_bf, one_bf, one_bf, one_bf, one_bf, one_bf, one_bf, one_bf};
    short8v kz = {0, 0, 0, 0, 0, 0, 0, 0};
    short* Cb = sC[wid];
    const int tiles[4] = {wid, 7 - wid, 8 + wid, 15 - wid};   // balanced triangle

    for (int sti = 0; sti < 4; ++sti) {
        int st = tiles[sti];
        int s0 = st * 16;

        float eMx4[4], flr4[4];
#pragma unroll
        for (int j = 0; j < 4; ++j) {
            int sg = s0 + grp * 4 + j;
            eMx4[j] = 0.25f * __expf(-sMx[sg]);
            flr4[j] = __expf(-(sFc[sg] + sMx[sg]));
        }

        if ((st & 1) == 0) {
#pragma unroll
            for (int z = 0; z < 4; ++z) {
                int idx = lane * 4 + z;
                Cb[(idx >> 4) * CBW + (st + 1) * 16 + (idx & 15)] = 0;
            }
        }

        short8v aQ = (grp < 2) ? *(const short8v*)(sQ + (s0 + colL) * QKW + grp * 8) : kz;

        for (int tt = 0; tt <= st; ++tt) {
            int t0 = tt * 16;
            short8v bK = (grp < 2) ? *(const short8v*)(sK + (t0 + colL) * QKW + grp * 8) : kz;
            f32x4 zacc = {0.f, 0.f, 0.f, 0.f};
            f32x4 d = __builtin_amdgcn_mfma_f32_16x16x32_bf16(aQ, bK, zacc, 0, 0, 0);
            float ea = sEA[t0 + colL];
#pragma unroll
            for (int j = 0; j < 4; ++j) {
                float v = d[j] * (ea * eMx4[j]);
                if (tt == st) v = (colL <= grp * 4 + j) ? v : 0.f;
                Cb[(grp * 4 + j) * CBW + t0 + colL] = f2bf(v);
            }
        }

        f32x4 hacc = {0.f, 0.f, 0.f, 0.f};
        f32x4 sacc = {0.f, 0.f, 0.f, 0.f};
        int nch = (st + 2) >> 1;
        for (int c = 0; c < nch; ++c) {
            int tc = c * 32;
            short8v aC = *(const short8v*)(Cb + colL * CBW + tc + grp * 8);
            short8v bV = *(const short8v*)(sVt + colL * VTW + tc + grp * 8);
            hacc = __builtin_amdgcn_mfma_f32_16x16x32_bf16(aC, bV, hacc, 0, 0, 0);
            sacc = __builtin_amdgcn_mfma_f32_16x16x32_bf16(aC, ones, sacc, 0, 0, 0);
        }

#pragma unroll
        for (int j = 0; j < 4; ++j) {
            int sg = s0 + grp * 4 + j;
            float nrm = fmaxf(fabsf(sacc[j]), flr4[j]) + 1e-6f;
            hatt[((size_t)(b * cS) + sg) * cI + h * cMDH + colL] = hacc[j] / nrm;
        }
    }
}

// ---------------- fused multihead-norm + gate + down-projection + residual ----------------
__global__ __launch_bounds__(320) void down_mhn_k(const float* __restrict__ hatt, const float* __restrict__ xc,
                                                  const float* __restrict__ zb, const float* __restrict__ mhnw,
                                                  const float* __restrict__ skip, const float* __restrict__ dw,
                                                  float* __restrict__ h) {
    __shared__ float yl[8 * 128];
    int row0 = blockIdx.x * 8;
    int tid = threadIdx.x;
    for (int i = tid; i < 1024; i += 320) yl[i] = hatt[(size_t)row0 * cI + i];
    __syncthreads();
    if (tid < 64) {
        int r = tid >> 3, hh = tid & 7;
        int row = row0 + r;
        float* g = yl + r * 128 + hh * 16;
        float xv[16];
        float mu = 0.f;
#pragma unroll
        for (int d = 0; d < 16; ++d) { xv[d] = g[d]; mu += xv[d]; }
        mu *= (1.f / 16);
        float va = 0.f;
#pragma unroll
        for (int d = 0; d < 16; ++d) { float dd = xv[d] - mu; va += dd * dd; }
        va *= (1.f / 16);
        float rs = rsqrtf(va + 1e-5f);
        const float* xcr = xc + (size_t)row * cI + hh * 16;
        const float* zr  = zb + (size_t)row * cI + hh * 16;
#pragma unroll
        for (int d = 0; d < 16; ++d) {
            int i = hh * 16 + d;
            float z = zr[d];
            float sg = 1.f / (1.f + __expf(-z));
            g[d] = ((xv[d] - mu) * rs * mhnw[i] + skip[i] * xcr[d]) * (z * sg);
        }
    }
    __syncthreads();
    int r = tid / 40, e = tid % 40;
    const float* dr = dw + e * cI;
    const float* yr = yl + r * cI;
    float acc = 0.f;
    for (int i = 0; i < cI; ++i) acc += yr[i] * dr[i];
    h[(size_t)(row0 + r) * cE + e] += acc;
}

// ---------------- plain row LayerNorm (E=40) ----------------
__global__ __launch_bounds__(256) void ln_rows_k(const float* __restrict__ h, const float* __restrict__ w,
                                                 float* __restrict__ out) {
    int rid = blockIdx.x * 256 + threadIdx.x;
    const float* r = h + (size_t)rid * cE;
    float mu = 0;
    for (int k = 0; k < cE; ++k) mu += r[k];
    mu *= (1.f / cE);
    float va = 0;
    for (int k = 0; k < cE; ++k) { float d = r[k] - mu; va += d * d; }
    va *= (1.f / cE);
    float rs = rsqrtf(va + 1e-5f);
    float* o = out + (size_t)rid * cE;
    for (int k = 0; k < cE; ++k) o[k] = (r[k] - mu) * rs * w[k];
}

// ---------------- sLSTM gate pre-activations; gall layout (S, B*NH, E=5, G=4) ----------------
__global__ __launch_bounds__(256) void sgates_k(const float* __restrict__ xcs, const float* __restrict__ ln1,
                                                const float* __restrict__ wi, const float* __restrict__ wf,
                                                const float* __restrict__ wz, const float* __restrict__ wo,
                                                float* __restrict__ gall) {
    int idx = blockIdx.x * 256 + threadIdx.x;   // S*1024*5*4
    int g = idx & 3; int r1 = idx >> 2;
    int e = r1 % 5; int r2 = r1 / 5;
    int bh = r2 & 1023; int s = r2 >> 10;
    int b = bh >> 3, h = bh & 7;
    const float* in = (g < 2) ? xcs : ln1;
    const float* w = (g == 0) ? wi : (g == 1) ? wf : (g == 2) ? wz : wo;
    const float* ir = in + ((size_t)(b * cS) + s) * cE + h * cDH;
    const float* wp = w + h * 25 + e * 5;
    float acc = 0.f;
#pragma unroll
    for (int i = 0; i < 5; ++i) acc += ir[i] * wp[i];
    gall[idx] = acc;
}

// ---------------- sLSTM sequential scan: 8 chains per wave ----------------
__global__ __launch_bounds__(64) void scan_k(const float* __restrict__ gall, const float* __restrict__ R,
                                             const float* __restrict__ bias, const float* __restrict__ mhnw,
                                             float* __restrict__ hbuf) {
    int lane = threadIdx.x;
    int grp = lane >> 3;
    int e = lane & 7;
    int ee = e < 5 ? e : 4;
    int bh = blockIdx.x * 8 + grp;
    int h = bh & 7;

    __shared__ float sOut[8][1285];

    float Rr[4][5];
#pragma unroll
    for (int g = 0; g < 4; ++g)
#pragma unroll
        for (int d = 0; d < 5; ++d) Rr[g][d] = R[h * 100 + g * 25 + d * 5 + ee];
    float bg[4];
#pragma unroll
    for (int g = 0; g < 4; ++g) bg[g] = bias[h * 20 + g * 5 + ee];
    float wmh = mhnw[h * 5 + ee];

    const float4* gp = (const float4*)gall + ((size_t)bh * 5 + ee);

    float4 rg[16];
#pragma unroll
    for (int j = 0; j < 16; ++j) rg[j] = gp[(size_t)j * 5120];

    float cstate = 0.f, nstate = 0.f, mstate = 0.f;
    float hs0 = 0.f, hs1 = 0.f, hs2 = 0.f, hs3 = 0.f, hs4 = 0.f;

    for (int t = 0; t < cS; t += 16) {
#pragma unroll
        for (int j = 0; j < 16; ++j) {
            float4 g4 = rg[j];
            rg[j] = gp[(size_t)(t + j + 16) * 5120];

            float ir = g4.x + bg[0], fr = g4.y + bg[1], zr = g4.z + bg[2], orr = g4.w + bg[3];
            ir = fmaf(hs0, Rr[0][0], ir); fr = fmaf(hs0, Rr[1][0], fr);
            zr = fmaf(hs0, Rr[2][0], zr); orr = fmaf(hs0, Rr[3][0], orr);
            ir = fmaf(hs1, Rr[0][1], ir); fr = fmaf(hs1, Rr[1][1], fr);
            zr = fmaf(hs1, Rr[2][1], zr); orr = fmaf(hs1, Rr[3][1], orr);
            ir = fmaf(hs2, Rr[0][2], ir); fr = fmaf(hs2, Rr[1][2], fr);
            zr = fmaf(hs2, Rr[2][2], zr); orr = fmaf(hs2, Rr[3][2], orr);
            ir = fmaf(hs3, Rr[0][3], ir); fr = fmaf(hs3, Rr[1][3], fr);
            zr = fmaf(hs3, Rr[2][3], zr); orr = fmaf(hs3, Rr[3][3], orr);
            ir = fmaf(hs4, Rr[0][4], ir); fr = fmaf(hs4, Rr[1][4], fr);
            zr = fmaf(hs4, Rr[2][4], zr); orr = fmaf(hs4, Rr[3][4], orr);

            float lsg = fminf(fr, 0.f) - __logf(1.f + __expf(-fabsf(fr)));
            float lfm = mstate + lsg;
            float mn = fmaxf(ir, lfm);
            float ig = __expf(ir - mn), fg = __expf(lfm - mn);
            float th = 1.f - 2.f * __builtin_amdgcn_rcpf(__expf(2.f * zr) + 1.f);
            float cn = fg * cstate + ig * th;
            float nn = fg * nstate + ig;
            float sg = __builtin_amdgcn_rcpf(1.f + __expf(-orr));
            float hn = sg * cn * __builtin_amdgcn_rcpf(nn);
            cstate = cn; nstate = nn; mstate = mn;

            hs0 = BC8(hn, 0); hs1 = BC8(hn, 1); hs2 = BC8(hn, 2);
            hs3 = BC8(hn, 3); hs4 = BC8(hn, 4);
            float mu = ((hs0 + hs1) + (hs2 + hs3) + hs4) * 0.2f;
            float d0 = hs0 - mu, d1 = hs1 - mu, d2 = hs2 - mu, d3 = hs3 - mu, d4 = hs4 - mu;
            float va = (d0 * d0 + d1 * d1 + d2 * d2 + d3 * d3 + d4 * d4) * 0.2f;
            float rs = __builtin_amdgcn_rsqf(va + 1e-5f);
            if (e < 5) sOut[grp][(t + j) * 5 + e] = (hn - mu) * rs * wmh;
        }
    }
    __syncthreads();

    for (int i = lane; i < 8 * 1280; i += 64) {
        int c = i / 1280;
        int r = i - c * 1280;
        int tt = r / 5, e2 = r - tt * 5;
        int bh2 = blockIdx.x * 8 + c;
        int b2 = bh2 >> 3, h2 = bh2 & 7;
        float* hp = hbuf + ((size_t)b2 * cS + tt) * cE + h2 * cDH + e2;
        *hp += sOut[c][r];
    }
}

// ---------------- FFN: fused LN + up-proj + exact GELU gate ----------------
__global__ __launch_bounds__(256) void ff1_k(const float* __restrict__ h, const float* __restrict__ lnw,
                                             const float* __restrict__ upw, float* __restrict__ ff) {
    __shared__ float lnr[4][cE];
    int row0 = blockIdx.x * 4;
    int tid = threadIdx.x;
    if (tid < 4) {
        const float* r = h + (size_t)(row0 + tid) * cE;
        float mu = 0;
        for (int k = 0; k < cE; ++k) mu += r[k];
        mu *= (1.f / cE);
        float va = 0;
        for (int k = 0; k < cE; ++k) { float d = r[k] - mu; va += d * d; }
        va *= (1.f / cE);
        float rs = rsqrtf(va + 1e-5f);
        for (int k = 0; k < cE; ++k) lnr[tid][k] = (r[k] - mu) * rs * lnw[k];
    }
    __syncthreads();
    int r = tid >> 6, f = tid & 63;
    float a = 0, u = 0;
    for (int k = 0; k < cE; ++k) {
        float xv = lnr[r][k];
        a += xv * upw[f * cE + k];
        u += xv * upw[(64 + f) * cE + k];
    }
    float g = 0.5f * a * (1.f + erff(a * 0.70710678118f));
    ff[(size_t)(row0 + r) * 64 + f] = g * u;
}

__global__ __launch_bounds__(320) void ff2_k(const float* __restrict__ ff, const float* __restrict__ dw,
                                             float* __restrict__ h) {
    __shared__ float fl[8 * 64];
    int row0 = blockIdx.x * 8;
    for (int i = threadIdx.x; i < 512; i += 320) fl[i] = ff[(size_t)row0 * 64 + i];
    __syncthreads();
    int r = threadIdx.x / 40, e = threadIdx.x % 40;
    const float* dr = dw + e * 64;
    const float* fr = fl + r * 64;
    float acc = 0.f;
    for (int i = 0; i < 64; ++i) acc += fr[i] * dr[i];
    h[(size_t)(row0 + r) * cE + e] += acc;
}

// ---------------- final LN + out projection ----------------
__global__ __launch_bounds__(256) void final_k(const float* __restrict__ h, const float* __restrict__ lnw,
                                               const float* __restrict__ ow, const float* __restrict__ ob,
                                               float* __restrict__ out) {
    int rid = blockIdx.x * 256 + threadIdx.x;
    const float* r = h + (size_t)rid * cE;
    float mu = 0;
    for (int k = 0; k < cE; ++k) mu += r[k];
    mu *= (1.f / cE);
    float va = 0;
    for (int k = 0; k < cE; ++k) { float d = r[k] - mu; va += d * d; }
    va *= (1.f / cE);
    float rs = rsqrtf(va + 1e-5f);
    float acc = ob[0];
    for (int k = 0; k < cE; ++k) acc += (r[k] - mu) * rs * lnw[k] * ow[k];
    out[rid] = acc;
}

extern "C" void kernel_launch(void* const* d_in, const int* in_sizes, int n_in,
                              void* d_out, int out_size, void* d_ws, size_t ws_size,
                              hipStream_t stream) {
    const float* x        = (const float*)d_in[0];
    const float* in_w     = (const float*)d_in[1];
    const float* in_b     = (const float*)d_in[2];
    const float* m_ln_w   = (const float*)d_in[3];
    const float* m_up_w   = (const float*)d_in[4];
    const float* m_conv_w = (const float*)d_in[5];
    const float* m_conv_b = (const float*)d_in[6];
    const float* m_q_w    = (const float*)d_in[7];
    const float* m_k_w    = (const float*)d_in[8];
    const float* m_v_w    = (const float*)d_in[9];
    const float* m_ig_w   = (const float*)d_in[10];
    const float* m_ig_b   = (const float*)d_in[11];
    const float* m_fg_w   = (const float*)d_in[12];
    const float* m_fg_b   = (const float*)d_in[13];
    const float* m_mhn_w  = (const float*)d_in[14];
    const float* m_skip   = (const float*)d_in[15];
    const float* m_down_w = (const float*)d_in[16];
    const float* s_ln1_w  = (const float*)d_in[17];
    const float* s_conv_w = (const float*)d_in[18];
    const float* s_conv_b = (const float*)d_in[19];
    const float* s_wi     = (const float*)d_in[20];
    const float* s_wf     = (const float*)d_in[21];
    const float* s_wz     = (const float*)d_in[22];
    const float* s_wo     = (const float*)d_in[23];
    const float* s_R      = (const float*)d_in[24];
    const float* s_bias   = (const float*)d_in[25];
    const float* s_mhn_w  = (const float*)d_in[26];
    const float* s_ln2_w  = (const float*)d_in[27];
    const float* s_ff_up  = (const float*)d_in[28];
    const float* s_ff_dn  = (const float*)d_in[29];
    const float* post_ln_w= (const float*)d_in[30];
    const float* out_w    = (const float*)d_in[31];
    const float* out_b    = (const float*)d_in[32];

    float* ws   = (float*)d_ws;
    float* h    = ws;                     // 1,310,720
    float* xm   = h + 1310720;            // 4,194,304  (dense x_m)
    float* zb   = xm + 4194304;           // 4,194,304  (dense z)
    float* xc   = zb + 4194304;           // 4,194,304
    float* qb   = xc + 4194304;           // 4,194,304
    float* kb   = qb + 4194304;           // 4,194,304
    float* vb   = kb + 4194304;           // 4,194,304
    float* ipb  = vb + 4194304;           //   262,144
    float* fpb  = ipb + 262144;           //   262,144
    float* hatt = fpb + 262144;           // 4,194,304
    // slstm / ff aliases into the xm+zb region (dead there); scan's 16-step
    // overread past gall end stays inside xm+zb (8.19M < 8.39M)
    float* lnbuf = xm;
    float* xcs   = xm + 1310720;
    float* gall  = xm + 2621440;
    float* ffbuf = xm;

    init_k<<<5120, 256, 0, stream>>>(x, in_w, in_b, h);

    auto mlstm = [&](int j) {
        ln_up_k<<<2048, 256, 0, stream>>>(h, m_ln_w + j * cE, m_up_w + (size_t)j * 256 * cE, xm, zb);
        convqkv_k<<<4096, 256, 0, stream>>>(xm, m_conv_w + j * cI * cK, m_conv_b + j * cI,
                                            m_q_w + j * 512, m_k_w + j * 512, m_v_w + j * 512,
                                            xc, qb, kb, vb);
        gates_k<<<1024, 256, 0, stream>>>(qb, kb, vb, m_ig_w + j * cNH * 384, m_ig_b + j * cNH,
                                          m_fg_w + j * cNH * 384, m_fg_b + j * cNH, ipb, fpb);
        attn_k<<<1024, 256, 0, stream>>>(qb, kb, vb, ipb, fpb, hatt);
        down_mhn_k<<<4096, 320, 0, stream>>>(hatt, xc, zb, m_mhn_w + j * cI, m_skip + j * cI,
                                             m_down_w + j * cE * cI, h);
    };

    mlstm(0);

    ln_rows_k<<<128, 256, 0, stream>>>(h, s_ln1_w, lnbuf);
    conv_silu_k<40><<<5120, 256, 0, stream>>>(lnbuf, 40, s_conv_w, s_conv_b, xcs);
    sgates_k<<<20480, 256, 0, stream>>>(xcs, lnbuf, s_wi, s_wf, s_wz, s_wo, gall);
    scan_k<<<128, 64, 0, stream>>>(gall, s_R, s_bias, s_mhn_w, h);

    ff1_k<<<8192, 256, 0, stream>>>(h, s_ln2_w, s_ff_up, ffbuf);
    ff2_k<<<4096, 320, 0, stream>>>(ffbuf, s_ff_dn, h);

    mlstm(1);
    mlstm(2);

    final_k<<<128, 256, 0, stream>>>(h, post_ln_w, out_w, out_b, (float*)d_out);
}

// Round 14
// 851.857 us; speedup vs baseline: 1.0404x; 1.0404x over previous
//
#include <hip/hip_runtime.h>
#include <math.h>

constexpr int cB = 128, cS = 256, cF = 10, cE = 40, cNH = 8, cDH = 5;
constexpr int cI = 128, cMDH = 16, cK = 4;

typedef __attribute__((ext_vector_type(8))) short short8v;   // 8 bf16 (4 VGPRs)
typedef __attribute__((ext_vector_type(4))) float f32x4;

#define BC8(v, l) __uint_as_float(__builtin_amdgcn_ds_swizzle(__float_as_uint(v), ((l) << 5) | 0x18))

__device__ __forceinline__ short f2bf(float f) {      // fp32 -> bf16 RTNE
    unsigned u = __float_as_uint(f);
    u += 0x7FFF + ((u >> 16) & 1);
    return (short)(u >> 16);
}

// ---------------- h = x @ in_w.T + in_b + pos_encoding ----------------
__global__ __launch_bounds__(256) void init_k(const float* __restrict__ x, const float* __restrict__ w,
                                              const float* __restrict__ b, float* __restrict__ h) {
    int idx = blockIdx.x * 256 + threadIdx.x;     // B*S*E
    int e = idx % cE; int bs = idx / cE; int s = bs % cS;
    float acc = b[e];
    const float* xr = x + (size_t)bs * cF;
#pragma unroll
    for (int f = 0; f < cF; ++f) acc += xr[f] * w[e * cF + f];
    int i2 = e >> 1;
    float div = expf(-(float)(2 * i2) * (logf(10000.f) / 40.0f));
    float arg = (float)s * div;
    acc += (e & 1) ? cosf(arg) : sinf(arg);
    h[idx] = acc;
}

// ---------------- fused LayerNorm + up-projection (E=40 -> 256) v2 ----------------
// 16 rows/block; upw staged TRANSPOSED in LDS (pad 257). R11 version (measured good).
__global__ __launch_bounds__(256) void ln_up_k(const float* __restrict__ h, const float* __restrict__ lnw,
                                               const float* __restrict__ upw, float* __restrict__ xmz) {
    __shared__ float lnr[16][cE];
    __shared__ float wT[cE * 257];
    int row0 = blockIdx.x * 16;
    int tid = threadIdx.x;
    for (int j = tid; j < 2560; j += 256) {       // 256*40/4 float4s
        float4 v = ((const float4*)upw)[j];
        int o = j / 10, kq = (j - o * 10) * 4;
        wT[(kq + 0) * 257 + o] = v.x;
        wT[(kq + 1) * 257 + o] = v.y;
        wT[(kq + 2) * 257 + o] = v.z;
        wT[(kq + 3) * 257 + o] = v.w;
    }
    if (tid < 16) {
        const float* r = h + (size_t)(row0 + tid) * cE;
        float mu = 0.f;
        for (int k = 0; k < cE; ++k) mu += r[k];
        mu *= (1.f / cE);
        float va = 0.f;
        for (int k = 0; k < cE; ++k) { float d = r[k] - mu; va += d * d; }
        va *= (1.f / cE);
        float rs = rsqrtf(va + 1e-5f);
        for (int k = 0; k < cE; ++k) lnr[tid][k] = (r[k] - mu) * rs * lnw[k];
    }
    __syncthreads();
    int o = tid;
    float acc[16];
#pragma unroll
    for (int r = 0; r < 16; ++r) acc[r] = 0.f;
    for (int k = 0; k < cE; ++k) {
        float wv = wT[k * 257 + o];
#pragma unroll
        for (int r = 0; r < 16; ++r) acc[r] = fmaf(lnr[r][k], wv, acc[r]);
    }
#pragma unroll
    for (int r = 0; r < 16; ++r) xmz[(size_t)(row0 + r) * 256 + o] = acc[r];
}

// ---------------- depthwise causal conv (K=4) + SiLU ----------------
template <int C>
__global__ __launch_bounds__(256) void conv_silu_k(const float* __restrict__ in, int instride,
                                                   const float* __restrict__ w, const float* __restrict__ bias,
                                                   float* __restrict__ out) {
    int idx = blockIdx.x * 256 + threadIdx.x;   // B*S*C
    int c = idx % C; int bs = idx / C; int s = bs % cS;
    float acc = bias[c];
#pragma unroll
    for (int j = 0; j < cK; ++j) {
        int sj = s - 3 + j;
        if (sj >= 0) acc += in[(size_t)(bs + j - 3) * instride + c] * w[c * cK + j];
    }
    float sg = 1.f / (1.f + __expf(-acc));
    out[idx] = acc * sg;
}

// ---------------- block-diagonal headwise q,k,v ----------------
__global__ __launch_bounds__(256) void qkv_k(const float* __restrict__ xc, const float* __restrict__ xmz,
                                             const float* __restrict__ qw, const float* __restrict__ kw,
                                             const float* __restrict__ vw,
                                             float* __restrict__ qb, float* __restrict__ kb, float* __restrict__ vb) {
    int idx = blockIdx.x * 256 + threadIdx.x;   // B*S*I
    int c = idx & 127; int bs = idx >> 7;
    int n = c >> 2, o = c & 3;
    const float* xcr = xc + (size_t)bs * cI + n * 4;
    const float* xmr = xmz + (size_t)bs * 256 + n * 4;
    const float* qwp = qw + n * 16 + o * 4;
    const float* kwp = kw + n * 16 + o * 4;
    const float* vwp = vw + n * 16 + o * 4;
    float aq = 0, ak = 0, av = 0;
#pragma unroll
    for (int i = 0; i < 4; ++i) { float a = xcr[i], m = xmr[i]; aq += a * qwp[i]; ak += a * kwp[i]; av += m * vwp[i]; }
    qb[idx] = aq; kb[idx] = ak; vb[idx] = av;
}

// ---------------- input/forget gate pre-activations ip, fp (B,NH,S) v3 ----------------
__global__ __launch_bounds__(256, 2) void gates_k(const float* __restrict__ qb, const float* __restrict__ kb,
                                                  const float* __restrict__ vb, const float* __restrict__ igw,
                                                  const float* __restrict__ igb, const float* __restrict__ fgw,
                                                  const float* __restrict__ fgb,
                                                  float* __restrict__ ipb, float* __restrict__ fpb) {
    __shared__ float g[32 * 388];
    __shared__ float w[16 * 388];
    int row0 = blockIdx.x * 32;
    int tid = threadIdx.x;

    for (int i = tid; i < 16 * 96; i += 256) {
        int r = i / 96, c4 = i - r * 96;
        const float* src = (r < 8) ? (igw + r * 384) : (fgw + (r - 8) * 384);
        *(float4*)&w[r * 388 + c4 * 4] = ((const float4*)src)[c4];
    }
    for (int i = tid; i < 32 * 96; i += 256) {
        int r = i / 96, c4 = i - r * 96;
        size_t gr = (size_t)(row0 + r) * cI;
        const float4* src = (c4 < 32) ? (const float4*)(qb + gr) + c4
                          : (c4 < 64) ? (const float4*)(kb + gr) + (c4 - 32)
                                      : (const float4*)(vb + gr) + (c4 - 64);
        *(float4*)&g[r * 388 + c4 * 4] = *src;
    }
    __syncthreads();

    int rp = tid >> 3;              // row 0..31
    int hp = tid & 7;               // out-pair 0..7
    int o0 = 2 * hp, o1 = o0 + 1;

    const float4* gp = (const float4*)(g + rp * 388);
    const float4* w0p = (const float4*)(w + o0 * 388);
    const float4* w1p = (const float4*)(w + o1 * 388);

    float a0e = 0.f, a0o = 0.f, a1e = 0.f, a1o = 0.f;
#pragma unroll 2
    for (int c4 = 0; c4 < 96; c4 += 2) {
        float4 gv0 = gp[c4], gv1 = gp[c4 + 1];
        float4 wa0 = w0p[c4], wa1 = w0p[c4 + 1];
        float4 wb0 = w1p[c4], wb1 = w1p[c4 + 1];
        a0e = fmaf(gv0.x, wa0.x, a0e); a0e = fmaf(gv0.y, wa0.y, a0e);
        a0e = fmaf(gv0.z, wa0.z, a0e); a0e = fmaf(gv0.w, wa0.w, a0e);
        a1e = fmaf(gv0.x, wb0.x, a1e); a1e = fmaf(gv0.y, wb0.y, a1e);
        a1e = fmaf(gv0.z, wb0.z, a1e); a1e = fmaf(gv0.w, wb0.w, a1e);
        a0o = fmaf(gv1.x, wa1.x, a0o); a0o = fmaf(gv1.y, wa1.y, a0o);
        a0o = fmaf(gv1.z, wa1.z, a0o); a0o = fmaf(gv1.w, wa1.w, a0o);
        a1o = fmaf(gv1.x, wb1.x, a1o); a1o = fmaf(gv1.y, wb1.y, a1o);
        a1o = fmaf(gv1.z, wb1.z, a1o); a1o = fmaf(gv1.w, wb1.w, a1o);
    }
    float a0 = a0e + a0o, a1 = a1e + a1o;

    int h0 = o0 & 7, wch0 = o0 >> 3;
    int h1 = o1 & 7, wch1 = o1 >> 3;
    float b0 = wch0 ? fgb[h0] : igb[h0];
    float b1 = wch1 ? fgb[h1] : igb[h1];
    int grow = row0 + rp;
    int bb = grow >> 8, ss = grow & 255;
    float* d0 = (wch0 ? fpb : ipb) + (size_t)(bb * cNH + h0) * cS + ss;
    float* d1 = (wch1 ? fpb : ipb) + (size_t)(bb * cNH + h1) * cS + ss;
    *d0 = a0 + b0; *d1 = a1 + b1;
}

// ---------------- fused mLSTM attention v7: MFMA (bf16), balanced tiles ----------------
constexpr int QKW = 24;    // Qb/Kb row width (shorts)
constexpr int VTW = 264;   // Vt row width
constexpr int CBW = 280;   // C row width

__global__ __launch_bounds__(256, 2) void attn_k(const float* __restrict__ qg, const float* __restrict__ kg,
                                                 const float* __restrict__ vg, const float* __restrict__ ipg,
                                                 const float* __restrict__ fpg, float* __restrict__ hatt) {
    int bh = blockIdx.x; int b = bh >> 3, h = bh & 7;
    int tid = threadIdx.x;
    int wid = tid >> 6, lane = tid & 63;
    int colL = lane & 15, grp = lane >> 4;

    __shared__ float sEA[cS], sMx[cS], sFc[cS];
    __shared__ short sQ[cS * QKW], sK[cS * QKW];
    __shared__ short sVt[cMDH * VTW];
    __shared__ short sC[4][16 * CBW];

    {
        const float4 fp4 = ((const float4*)(fpg + (size_t)bh * cS))[lane];
        const float4 ip4 = ((const float4*)(ipg + (size_t)bh * cS))[lane];
        float fpa[4] = {fp4.x, fp4.y, fp4.z, fp4.w};
        float ipa[4] = {ip4.x, ip4.y, ip4.z, ip4.w};
        float p[4];
        float run = 0.f;
#pragma unroll
        for (int i = 0; i < 4; ++i) {
            float xx = fpa[i];
            float lsg = fminf(xx, 0.f) - log1pf(expf(-fabsf(xx)));
            run += lsg; p[i] = run;
        }
        float cum = p[3];
#pragma unroll
        for (int off = 1; off < 64; off <<= 1) { float t = __shfl_up(cum, off); if (lane >= off) cum += t; }
        float excl = cum - p[3];
        float aa[4];
#pragma unroll
        for (int i = 0; i < 4; ++i) {
            float fcv = excl + p[i];
            aa[i] = ipa[i] - fcv;
            sFc[lane * 4 + i] = fcv;
            sEA[lane * 4 + i] = __expf(aa[i]);
        }
        float mq[4]; mq[0] = aa[0];
#pragma unroll
        for (int i = 1; i < 4; ++i) mq[i] = fmaxf(mq[i - 1], aa[i]);
        float cm = mq[3];
#pragma unroll
        for (int off = 1; off < 64; off <<= 1) { float t = __shfl_up(cm, off); if (lane >= off) cm = fmaxf(cm, t); }
        float exm = __shfl_up(cm, 1);
        if (lane == 0) exm = -3.0e38f;
#pragma unroll
        for (int i = 0; i < 4; ++i) sMx[lane * 4 + i] = fmaxf(exm, mq[i]);
    }

    {
        int t = tid;
        const float4* qp = (const float4*)(qg + ((size_t)(b * cS) + t) * cI + h * cMDH);
        const float4* kp = (const float4*)(kg + ((size_t)(b * cS) + t) * cI + h * cMDH);
        const float4* vp = (const float4*)(vg + ((size_t)(b * cS) + t) * cI + h * cMDH);
        float4 q0 = qp[0], q1 = qp[1], q2 = qp[2], q3 = qp[3];
        float4 k0 = kp[0], k1 = kp[1], k2 = kp[2], k3 = kp[3];
        float4 v0 = vp[0], v1 = vp[1], v2 = vp[2], v3 = vp[3];
        short8v qa, qbv, ka, kbv;
        qa[0] = f2bf(q0.x); qa[1] = f2bf(q0.y); qa[2] = f2bf(q0.z); qa[3] = f2bf(q0.w);
        qa[4] = f2bf(q1.x); qa[5] = f2bf(q1.y); qa[6] = f2bf(q1.z); qa[7] = f2bf(q1.w);
        qbv[0] = f2bf(q2.x); qbv[1] = f2bf(q2.y); qbv[2] = f2bf(q2.z); qbv[3] = f2bf(q2.w);
        qbv[4] = f2bf(q3.x); qbv[5] = f2bf(q3.y); qbv[6] = f2bf(q3.z); qbv[7] = f2bf(q3.w);
        ka[0] = f2bf(k0.x); ka[1] = f2bf(k0.y); ka[2] = f2bf(k0.z); ka[3] = f2bf(k0.w);
        ka[4] = f2bf(k1.x); ka[5] = f2bf(k1.y); ka[6] = f2bf(k1.z); ka[7] = f2bf(k1.w);
        kbv[0] = f2bf(k2.x); kbv[1] = f2bf(k2.y); kbv[2] = f2bf(k2.z); kbv[3] = f2bf(k2.w);
        kbv[4] = f2bf(k3.x); kbv[5] = f2bf(k3.y); kbv[6] = f2bf(k3.z); kbv[7] = f2bf(k3.w);
        *(short8v*)(sQ + t * QKW) = qa;
        *(short8v*)(sQ + t * QKW + 8) = qbv;
        *(short8v*)(sK + t * QKW) = ka;
        *(short8v*)(sK + t * QKW + 8) = kbv;
        sVt[0 * VTW + t] = f2bf(v0.x);  sVt[1 * VTW + t] = f2bf(v0.y);
        sVt[2 * VTW + t] = f2bf(v0.z);  sVt[3 * VTW + t] = f2bf(v0.w);
        sVt[4 * VTW + t] = f2bf(v1.x);  sVt[5 * VTW + t] = f2bf(v1.y);
        sVt[6 * VTW + t] = f2bf(v1.z);  sVt[7 * VTW + t] = f2bf(v1.w);
        sVt[8 * VTW + t] = f2bf(v2.x);  sVt[9 * VTW + t] = f2bf(v2.y);
        sVt[10 * VTW + t] = f2bf(v2.z); sVt[11 * VTW + t] = f2bf(v2.w);
        sVt[12 * VTW + t] = f2bf(v3.x); sVt[13 * VTW + t] = f2bf(v3.y);
        sVt[14 * VTW + t] = f2bf(v3.z); sVt[15 * VTW + t] = f2bf(v3.w);
    }
    __syncthreads();

    const short one_bf = (short)0x3F80;
    short8v ones = {one_bf, one_bf, one_bf, one_bf, one_bf, one_bf, one_bf, one_bf};
    short8v kz = {0, 0, 0, 0, 0, 0, 0, 0};
    short* Cb = sC[wid];
    const int tiles[4] = {wid, 7 - wid, 8 + wid, 15 - wid};   // balanced triangle

    for (int sti = 0; sti < 4; ++sti) {
        int st = tiles[sti];
        int s0 = st * 16;

        float eMx4[4], flr4[4];
#pragma unroll
        for (int j = 0; j < 4; ++j) {
            int sg = s0 + grp * 4 + j;
            eMx4[j] = 0.25f * __expf(-sMx[sg]);
            flr4[j] = __expf(-(sFc[sg] + sMx[sg]));
        }

        if ((st & 1) == 0) {
#pragma unroll
            for (int z = 0; z < 4; ++z) {
                int idx = lane * 4 + z;
                Cb[(idx >> 4) * CBW + (st + 1) * 16 + (idx & 15)] = 0;
            }
        }

        short8v aQ = (grp < 2) ? *(const short8v*)(sQ + (s0 + colL) * QKW + grp * 8) : kz;

        for (int tt = 0; tt <= st; ++tt) {
            int t0 = tt * 16;
            short8v bK = (grp < 2) ? *(const short8v*)(sK + (t0 + colL) * QKW + grp * 8) : kz;
            f32x4 zacc = {0.f, 0.f, 0.f, 0.f};
            f32x4 d = __builtin_amdgcn_mfma_f32_16x16x32_bf16(aQ, bK, zacc, 0, 0, 0);
            float ea = sEA[t0 + colL];
#pragma unroll
            for (int j = 0; j < 4; ++j) {
                float v = d[j] * (ea * eMx4[j]);
                if (tt == st) v = (colL <= grp * 4 + j) ? v : 0.f;
                Cb[(grp * 4 + j) * CBW + t0 + colL] = f2bf(v);
            }
        }

        f32x4 hacc = {0.f, 0.f, 0.f, 0.f};
        f32x4 sacc = {0.f, 0.f, 0.f, 0.f};
        int nch = (st + 2) >> 1;
        for (int c = 0; c < nch; ++c) {
            int tc = c * 32;
            short8v aC = *(const short8v*)(Cb + colL * CBW + tc + grp * 8);
            short8v bV = *(const short8v*)(sVt + colL * VTW + tc + grp * 8);
            hacc = __builtin_amdgcn_mfma_f32_16x16x32_bf16(aC, bV, hacc, 0, 0, 0);
            sacc = __builtin_amdgcn_mfma_f32_16x16x32_bf16(aC, ones, sacc, 0, 0, 0);
        }

#pragma unroll
        for (int j = 0; j < 4; ++j) {
            int sg = s0 + grp * 4 + j;
            float nrm = fmaxf(fabsf(sacc[j]), flr4[j]) + 1e-6f;
            hatt[((size_t)(b * cS) + sg) * cI + h * cMDH + colL] = hacc[j] / nrm;
        }
    }
}

// ---------------- fused multihead-norm + gate + down-projection + residual ----------------
__global__ __launch_bounds__(320) void down_mhn_k(const float* __restrict__ hatt, const float* __restrict__ xc,
                                                  const float* __restrict__ xmz, const float* __restrict__ mhnw,
                                                  const float* __restrict__ skip, const float* __restrict__ dw,
                                                  float* __restrict__ h) {
    __shared__ float yl[8 * 128];
    int row0 = blockIdx.x * 8;
    int tid = threadIdx.x;
    for (int i = tid; i < 1024; i += 320) yl[i] = hatt[(size_t)row0 * cI + i];
    __syncthreads();
    if (tid < 64) {
        int r = tid >> 3, hh = tid & 7;
        int row = row0 + r;
        float* g = yl + r * 128 + hh * 16;
        float xv[16];
        float mu = 0.f;
#pragma unroll
        for (int d = 0; d < 16; ++d) { xv[d] = g[d]; mu += xv[d]; }
        mu *= (1.f / 16);
        float va = 0.f;
#pragma unroll
        for (int d = 0; d < 16; ++d) { float dd = xv[d] - mu; va += dd * dd; }
        va *= (1.f / 16);
        float rs = rsqrtf(va + 1e-5f);
        const float* xcr = xc + (size_t)row * cI + hh * 16;
        const float* zr  = xmz + (size_t)row * 256 + 128 + hh * 16;
#pragma unroll
        for (int d = 0; d < 16; ++d) {
            int i = hh * 16 + d;
            float z = zr[d];
            float sg = 1.f / (1.f + __expf(-z));
            g[d] = ((xv[d] - mu) * rs * mhnw[i] + skip[i] * xcr[d]) * (z * sg);
        }
    }
    __syncthreads();
    int r = tid / 40, e = tid % 40;
    const float* dr = dw + e * cI;
    const float* yr = yl + r * cI;
    float acc = 0.f;
    for (int i = 0; i < cI; ++i) acc += yr[i] * dr[i];
    h[(size_t)(row0 + r) * cE + e] += acc;
}

// ---------------- plain row LayerNorm (E=40) ----------------
__global__ __launch_bounds__(256) void ln_rows_k(const float* __restrict__ h, const float* __restrict__ w,
                                                 float* __restrict__ out) {
    int rid = blockIdx.x * 256 + threadIdx.x;
    const float* r = h + (size_t)rid * cE;
    float mu = 0;
    for (int k = 0; k < cE; ++k) mu += r[k];
    mu *= (1.f / cE);
    float va = 0;
    for (int k = 0; k < cE; ++k) { float d = r[k] - mu; va += d * d; }
    va *= (1.f / cE);
    float rs = rsqrtf(va + 1e-5f);
    float* o = out + (size_t)rid * cE;
    for (int k = 0; k < cE; ++k) o[k] = (r[k] - mu) * rs * w[k];
}

// ---------------- sLSTM gate pre-activations; gall layout (S, B*NH, E=5, G=4) ----------------
__global__ __launch_bounds__(256) void sgates_k(const float* __restrict__ xcs, const float* __restrict__ ln1,
                                                const float* __restrict__ wi, const float* __restrict__ wf,
                                                const float* __restrict__ wz, const float* __restrict__ wo,
                                                float* __restrict__ gall) {
    int idx = blockIdx.x * 256 + threadIdx.x;   // S*1024*5*4
    int g = idx & 3; int r1 = idx >> 2;
    int e = r1 % 5; int r2 = r1 / 5;
    int bh = r2 & 1023; int s = r2 >> 10;
    int b = bh >> 3, h = bh & 7;
    const float* in = (g < 2) ? xcs : ln1;
    const float* w = (g == 0) ? wi : (g == 1) ? wf : (g == 2) ? wz : wo;
    const float* ir = in + ((size_t)(b * cS) + s) * cE + h * cDH;
    const float* wp = w + h * 25 + e * 5;
    float acc = 0.f;
#pragma unroll
    for (int i = 0; i < 5; ++i) acc += ir[i] * wp[i];
    gall[idx] = acc;
}

// ---------------- sLSTM sequential scan: 8 chains per wave ----------------
__global__ __launch_bounds__(64) void scan_k(const float* __restrict__ gall, const float* __restrict__ R,
                                             const float* __restrict__ bias, const float* __restrict__ mhnw,
                                             float* __restrict__ hbuf) {
    int lane = threadIdx.x;
    int grp = lane >> 3;
    int e = lane & 7;
    int ee = e < 5 ? e : 4;
    int bh = blockIdx.x * 8 + grp;
    int h = bh & 7;

    __shared__ float sOut[8][1285];

    float Rr[4][5];
#pragma unroll
    for (int g = 0; g < 4; ++g)
#pragma unroll
        for (int d = 0; d < 5; ++d) Rr[g][d] = R[h * 100 + g * 25 + d * 5 + ee];
    float bg[4];
#pragma unroll
    for (int g = 0; g < 4; ++g) bg[g] = bias[h * 20 + g * 5 + ee];
    float wmh = mhnw[h * 5 + ee];

    const float4* gp = (const float4*)gall + ((size_t)bh * 5 + ee);

    float4 rg[16];
#pragma unroll
    for (int j = 0; j < 16; ++j) rg[j] = gp[(size_t)j * 5120];

    float cstate = 0.f, nstate = 0.f, mstate = 0.f;
    float hs0 = 0.f, hs1 = 0.f, hs2 = 0.f, hs3 = 0.f, hs4 = 0.f;

    for (int t = 0; t < cS; t += 16) {
#pragma unroll
        for (int j = 0; j < 16; ++j) {
            float4 g4 = rg[j];
            rg[j] = gp[(size_t)(t + j + 16) * 5120];

            float ir = g4.x + bg[0], fr = g4.y + bg[1], zr = g4.z + bg[2], orr = g4.w + bg[3];
            ir = fmaf(hs0, Rr[0][0], ir); fr = fmaf(hs0, Rr[1][0], fr);
            zr = fmaf(hs0, Rr[2][0], zr); orr = fmaf(hs0, Rr[3][0], orr);
            ir = fmaf(hs1, Rr[0][1], ir); fr = fmaf(hs1, Rr[1][1], fr);
            zr = fmaf(hs1, Rr[2][1], zr); orr = fmaf(hs1, Rr[3][1], orr);
            ir = fmaf(hs2, Rr[0][2], ir); fr = fmaf(hs2, Rr[1][2], fr);
            zr = fmaf(hs2, Rr[2][2], zr); orr = fmaf(hs2, Rr[3][2], orr);
            ir = fmaf(hs3, Rr[0][3], ir); fr = fmaf(hs3, Rr[1][3], fr);
            zr = fmaf(hs3, Rr[2][3], zr); orr = fmaf(hs3, Rr[3][3], orr);
            ir = fmaf(hs4, Rr[0][4], ir); fr = fmaf(hs4, Rr[1][4], fr);
            zr = fmaf(hs4, Rr[2][4], zr); orr = fmaf(hs4, Rr[3][4], orr);

            float lsg = fminf(fr, 0.f) - __logf(1.f + __expf(-fabsf(fr)));
            float lfm = mstate + lsg;
            float mn = fmaxf(ir, lfm);
            float ig = __expf(ir - mn), fg = __expf(lfm - mn);
            float th = 1.f - 2.f * __builtin_amdgcn_rcpf(__expf(2.f * zr) + 1.f);
            float cn = fg * cstate + ig * th;
            float nn = fg * nstate + ig;
            float sg = __builtin_amdgcn_rcpf(1.f + __expf(-orr));
            float hn = sg * cn * __builtin_amdgcn_rcpf(nn);
            cstate = cn; nstate = nn; mstate = mn;

            hs0 = BC8(hn, 0); hs1 = BC8(hn, 1); hs2 = BC8(hn, 2);
            hs3 = BC8(hn, 3); hs4 = BC8(hn, 4);
            float mu = ((hs0 + hs1) + (hs2 + hs3) + hs4) * 0.2f;
            float d0 = hs0 - mu, d1 = hs1 - mu, d2 = hs2 - mu, d3 = hs3 - mu, d4 = hs4 - mu;
            float va = (d0 * d0 + d1 * d1 + d2 * d2 + d3 * d3 + d4 * d4) * 0.2f;
            float rs = __builtin_amdgcn_rsqf(va + 1e-5f);
            if (e < 5) sOut[grp][(t + j) * 5 + e] = (hn - mu) * rs * wmh;
        }
    }
    __syncthreads();

    for (int i = lane; i < 8 * 1280; i += 64) {
        int c = i / 1280;
        int r = i - c * 1280;
        int tt = r / 5, e2 = r - tt * 5;
        int bh2 = blockIdx.x * 8 + c;
        int b2 = bh2 >> 3, h2 = bh2 & 7;
        float* hp = hbuf + ((size_t)b2 * cS + tt) * cE + h2 * cDH + e2;
        *hp += sOut[c][r];
    }
}

// ---------------- FFN fused: LN + up-proj + GELU gate + down-proj + residual ----------------
// 8 rows/block; phases keep all 256 threads dense (R12 lesson: don't shrink
// parallelism). Removes ffbuf round-trip (2+8MB) and one launch.
__global__ __launch_bounds__(256) void ff_k(float* __restrict__ h, const float* __restrict__ lnw,
                                            const float* __restrict__ upw, const float* __restrict__ dnw) {
    __shared__ float lnr[8][cE];
    __shared__ float ffr[8][64];
    int row0 = blockIdx.x * 8;
    int tid = threadIdx.x;
    if (tid < 8) {
        const float* r = h + (size_t)(row0 + tid) * cE;
        float mu = 0;
        for (int k = 0; k < cE; ++k) mu += r[k];
        mu *= (1.f / cE);
        float va = 0;
        for (int k = 0; k < cE; ++k) { float d = r[k] - mu; va += d * d; }
        va *= (1.f / cE);
        float rs = rsqrtf(va + 1e-5f);
        for (int k = 0; k < cE; ++k) lnr[tid][k] = (r[k] - mu) * rs * lnw[k];
    }
    __syncthreads();
    // 8 rows x 64 f-outs = 512 -> 2 per thread
    {
        int r = tid >> 5;            // 0..7
        int f0 = (tid & 31) * 2;
#pragma unroll
        for (int ff = 0; ff < 2; ++ff) {
            int f = f0 + ff;
            float a = 0, u = 0;
            const float* wa = upw + f * cE;
            const float* wu = upw + (64 + f) * cE;
            for (int k = 0; k < cE; ++k) {
                float xv = lnr[r][k];
                a = fmaf(xv, wa[k], a);
                u = fmaf(xv, wu[k], u);
            }
            float g = 0.5f * a * (1.f + erff(a * 0.70710678118f));
            ffr[r][f] = g * u;
        }
    }
    __syncthreads();
    // 8 rows x 40 outs = 320 -> stride loop
    for (int i = tid; i < 320; i += 256) {
        int r = i / 40, e = i - r * 40;
        const float* dr = dnw + e * 64;
        const float* fr = ffr[r];
        float acc = 0.f;
        for (int k = 0; k < 64; ++k) acc = fmaf(fr[k], dr[k], acc);
        h[(size_t)(row0 + r) * cE + e] += acc;
    }
}

// ---------------- final LN + out projection ----------------
__global__ __launch_bounds__(256) void final_k(const float* __restrict__ h, const float* __restrict__ lnw,
                                               const float* __restrict__ ow, const float* __restrict__ ob,
                                               float* __restrict__ out) {
    int rid = blockIdx.x * 256 + threadIdx.x;
    const float* r = h + (size_t)rid * cE;
    float mu = 0;
    for (int k = 0; k < cE; ++k) mu += r[k];
    mu *= (1.f / cE);
    float va = 0;
    for (int k = 0; k < cE; ++k) { float d = r[k] - mu; va += d * d; }
    va *= (1.f / cE);
    float rs = rsqrtf(va + 1e-5f);
    float acc = ob[0];
    for (int k = 0; k < cE; ++k) acc += (r[k] - mu) * rs * lnw[k] * ow[k];
    out[rid] = acc;
}

extern "C" void kernel_launch(void* const* d_in, const int* in_sizes, int n_in,
                              void* d_out, int out_size, void* d_ws, size_t ws_size,
                              hipStream_t stream) {
    const float* x        = (const float*)d_in[0];
    const float* in_w     = (const float*)d_in[1];
    const float* in_b     = (const float*)d_in[2];
    const float* m_ln_w   = (const float*)d_in[3];
    const float* m_up_w   = (const float*)d_in[4];
    const float* m_conv_w = (const float*)d_in[5];
    const float* m_conv_b = (const float*)d_in[6];
    const float* m_q_w    = (const float*)d_in[7];
    const float* m_k_w    = (const float*)d_in[8];
    const float* m_v_w    = (const float*)d_in[9];
    const float* m_ig_w   = (const float*)d_in[10];
    const float* m_ig_b   = (const float*)d_in[11];
    const float* m_fg_w   = (const float*)d_in[12];
    const float* m_fg_b   = (const float*)d_in[13];
    const float* m_mhn_w  = (const float*)d_in[14];
    const float* m_skip   = (const float*)d_in[15];
    const float* m_down_w = (const float*)d_in[16];
    const float* s_ln1_w  = (const float*)d_in[17];
    const float* s_conv_w = (const float*)d_in[18];
    const float* s_conv_b = (const float*)d_in[19];
    const float* s_wi     = (const float*)d_in[20];
    const float* s_wf     = (const float*)d_in[21];
    const float* s_wz     = (const float*)d_in[22];
    const float* s_wo     = (const float*)d_in[23];
    const float* s_R      = (const float*)d_in[24];
    const float* s_bias   = (const float*)d_in[25];
    const float* s_mhn_w  = (const float*)d_in[26];
    const float* s_ln2_w  = (const float*)d_in[27];
    const float* s_ff_up  = (const float*)d_in[28];
    const float* s_ff_dn  = (const float*)d_in[29];
    const float* post_ln_w= (const float*)d_in[30];
    const float* out_w    = (const float*)d_in[31];
    const float* out_b    = (const float*)d_in[32];

    float* ws   = (float*)d_ws;
    float* h    = ws;                     // 1,310,720
    float* xmz  = h + 1310720;            // 8,388,608
    float* xc   = xmz + 8388608;          // 4,194,304
    float* qb   = xc + 4194304;           // 4,194,304
    float* kb   = qb + 4194304;           // 4,194,304
    float* vb   = kb + 4194304;           // 4,194,304
    float* ipb  = vb + 4194304;           //   262,144
    float* fpb  = ipb + 262144;           //   262,144
    float* hatt = fpb + 262144;           // 4,194,304
    // slstm aliases into the xmz region (dead there); scan's 16-step overread
    // past gall end stays inside the region
    float* lnbuf = xmz;
    float* xcs   = xmz + 1310720;
    float* gall  = xmz + 2621440;

    init_k<<<5120, 256, 0, stream>>>(x, in_w, in_b, h);

    auto mlstm = [&](int j) {
        ln_up_k<<<2048, 256, 0, stream>>>(h, m_ln_w + j * cE, m_up_w + (size_t)j * 256 * cE, xmz);
        conv_silu_k<128><<<16384, 256, 0, stream>>>(xmz, 256, m_conv_w + j * cI * cK, m_conv_b + j * cI, xc);
        qkv_k<<<16384, 256, 0, stream>>>(xc, xmz, m_q_w + j * 512, m_k_w + j * 512, m_v_w + j * 512, qb, kb, vb);
        gates_k<<<1024, 256, 0, stream>>>(qb, kb, vb, m_ig_w + j * cNH * 384, m_ig_b + j * cNH,
                                          m_fg_w + j * cNH * 384, m_fg_b + j * cNH, ipb, fpb);
        attn_k<<<1024, 256, 0, stream>>>(qb, kb, vb, ipb, fpb, hatt);
        down_mhn_k<<<4096, 320, 0, stream>>>(hatt, xc, xmz, m_mhn_w + j * cI, m_skip + j * cI,
                                             m_down_w + j * cE * cI, h);
    };

    mlstm(0);

    ln_rows_k<<<128, 256, 0, stream>>>(h, s_ln1_w, lnbuf);
    conv_silu_k<40><<<5120, 256, 0, stream>>>(lnbuf, 40, s_conv_w, s_conv_b, xcs);
    sgates_k<<<20480, 256, 0, stream>>>(xcs, lnbuf, s_wi, s_wf, s_wz, s_wo, gall);
    scan_k<<<128, 64, 0, stream>>>(gall, s_R, s_bias, s_mhn_w, h);

    ff_k<<<4096, 256, 0, stream>>>(h, s_ln2_w, s_ff_up, s_ff_dn);

    mlstm(1);
    mlstm(2);

    final_k<<<128, 256, 0, stream>>>(h, post_ln_w, out_w, out_b, (float*)d_out);
}

// Round 15
// 841.182 us; speedup vs baseline: 1.0536x; 1.0127x over previous
//
#include <hip/hip_runtime.h>
#include <math.h>

constexpr int cB = 128, cS = 256, cF = 10, cE = 40, cNH = 8, cDH = 5;
constexpr int cI = 128, cMDH = 16, cK = 4;

typedef __attribute__((ext_vector_type(8))) short short8v;   // 8 bf16 (4 VGPRs)
typedef __attribute__((ext_vector_type(4))) float f32x4;
typedef __attribute__((ext_vector_type(16))) float f32x16;

#define BC8(v, l) __uint_as_float(__builtin_amdgcn_ds_swizzle(__float_as_uint(v), ((l) << 5) | 0x18))

__device__ __forceinline__ short f2bf(float f) {      // fp32 -> bf16 RTNE
    unsigned u = __float_as_uint(f);
    u += 0x7FFF + ((u >> 16) & 1);
    return (short)(u >> 16);
}

// ---------------- h = x @ in_w.T + in_b + pos_encoding ----------------
__global__ __launch_bounds__(256) void init_k(const float* __restrict__ x, const float* __restrict__ w,
                                              const float* __restrict__ b, float* __restrict__ h) {
    int idx = blockIdx.x * 256 + threadIdx.x;     // B*S*E
    int e = idx % cE; int bs = idx / cE; int s = bs % cS;
    float acc = b[e];
    const float* xr = x + (size_t)bs * cF;
#pragma unroll
    for (int f = 0; f < cF; ++f) acc += xr[f] * w[e * cF + f];
    int i2 = e >> 1;
    float div = expf(-(float)(2 * i2) * (logf(10000.f) / 40.0f));
    float arg = (float)s * div;
    acc += (e & 1) ? cosf(arg) : sinf(arg);
    h[idx] = acc;
}

// ---------------- fused LayerNorm + up-projection (E=40 -> 256) v2 ----------------
__global__ __launch_bounds__(256) void ln_up_k(const float* __restrict__ h, const float* __restrict__ lnw,
                                               const float* __restrict__ upw, float* __restrict__ xmz) {
    __shared__ float lnr[16][cE];
    __shared__ float wT[cE * 257];
    int row0 = blockIdx.x * 16;
    int tid = threadIdx.x;
    for (int j = tid; j < 2560; j += 256) {       // 256*40/4 float4s
        float4 v = ((const float4*)upw)[j];
        int o = j / 10, kq = (j - o * 10) * 4;
        wT[(kq + 0) * 257 + o] = v.x;
        wT[(kq + 1) * 257 + o] = v.y;
        wT[(kq + 2) * 257 + o] = v.z;
        wT[(kq + 3) * 257 + o] = v.w;
    }
    if (tid < 16) {
        const float* r = h + (size_t)(row0 + tid) * cE;
        float mu = 0.f;
        for (int k = 0; k < cE; ++k) mu += r[k];
        mu *= (1.f / cE);
        float va = 0.f;
        for (int k = 0; k < cE; ++k) { float d = r[k] - mu; va += d * d; }
        va *= (1.f / cE);
        float rs = rsqrtf(va + 1e-5f);
        for (int k = 0; k < cE; ++k) lnr[tid][k] = (r[k] - mu) * rs * lnw[k];
    }
    __syncthreads();
    int o = tid;
    float acc[16];
#pragma unroll
    for (int r = 0; r < 16; ++r) acc[r] = 0.f;
    for (int k = 0; k < cE; ++k) {
        float wv = wT[k * 257 + o];
#pragma unroll
        for (int r = 0; r < 16; ++r) acc[r] = fmaf(lnr[r][k], wv, acc[r]);
    }
#pragma unroll
    for (int r = 0; r < 16; ++r) xmz[(size_t)(row0 + r) * 256 + o] = acc[r];
}

// ---------------- depthwise causal conv (K=4) + SiLU ----------------
template <int C>
__global__ __launch_bounds__(256) void conv_silu_k(const float* __restrict__ in, int instride,
                                                   const float* __restrict__ w, const float* __restrict__ bias,
                                                   float* __restrict__ out) {
    int idx = blockIdx.x * 256 + threadIdx.x;   // B*S*C
    int c = idx % C; int bs = idx / C; int s = bs % cS;
    float acc = bias[c];
#pragma unroll
    for (int j = 0; j < cK; ++j) {
        int sj = s - 3 + j;
        if (sj >= 0) acc += in[(size_t)(bs + j - 3) * instride + c] * w[c * cK + j];
    }
    float sg = 1.f / (1.f + __expf(-acc));
    out[idx] = acc * sg;
}

// ---------------- block-diagonal headwise q,k,v ----------------
__global__ __launch_bounds__(256) void qkv_k(const float* __restrict__ xc, const float* __restrict__ xmz,
                                             const float* __restrict__ qw, const float* __restrict__ kw,
                                             const float* __restrict__ vw,
                                             float* __restrict__ qb, float* __restrict__ kb, float* __restrict__ vb) {
    int idx = blockIdx.x * 256 + threadIdx.x;   // B*S*I
    int c = idx & 127; int bs = idx >> 7;
    int n = c >> 2, o = c & 3;
    const float* xcr = xc + (size_t)bs * cI + n * 4;
    const float* xmr = xmz + (size_t)bs * 256 + n * 4;
    const float* qwp = qw + n * 16 + o * 4;
    const float* kwp = kw + n * 16 + o * 4;
    const float* vwp = vw + n * 16 + o * 4;
    float aq = 0, ak = 0, av = 0;
#pragma unroll
    for (int i = 0; i < 4; ++i) { float a = xcr[i], m = xmr[i]; aq += a * qwp[i]; ak += a * kwp[i]; av += m * vwp[i]; }
    qb[idx] = aq; kb[idx] = ak; vb[idx] = av;
}

// ---------------- input/forget gate pre-activations ip, fp (B,NH,S) v3 ----------------
__global__ __launch_bounds__(256, 2) void gates_k(const float* __restrict__ qb, const float* __restrict__ kb,
                                                  const float* __restrict__ vb, const float* __restrict__ igw,
                                                  const float* __restrict__ igb, const float* __restrict__ fgw,
                                                  const float* __restrict__ fgb,
                                                  float* __restrict__ ipb, float* __restrict__ fpb) {
    __shared__ float g[32 * 388];
    __shared__ float w[16 * 388];
    int row0 = blockIdx.x * 32;
    int tid = threadIdx.x;

    for (int i = tid; i < 16 * 96; i += 256) {
        int r = i / 96, c4 = i - r * 96;
        const float* src = (r < 8) ? (igw + r * 384) : (fgw + (r - 8) * 384);
        *(float4*)&w[r * 388 + c4 * 4] = ((const float4*)src)[c4];
    }
    for (int i = tid; i < 32 * 96; i += 256) {
        int r = i / 96, c4 = i - r * 96;
        size_t gr = (size_t)(row0 + r) * cI;
        const float4* src = (c4 < 32) ? (const float4*)(qb + gr) + c4
                          : (c4 < 64) ? (const float4*)(kb + gr) + (c4 - 32)
                                      : (const float4*)(vb + gr) + (c4 - 64);
        *(float4*)&g[r * 388 + c4 * 4] = *src;
    }
    __syncthreads();

    int rp = tid >> 3;              // row 0..31
    int hp = tid & 7;               // out-pair 0..7
    int o0 = 2 * hp, o1 = o0 + 1;

    const float4* gp = (const float4*)(g + rp * 388);
    const float4* w0p = (const float4*)(w + o0 * 388);
    const float4* w1p = (const float4*)(w + o1 * 388);

    float a0e = 0.f, a0o = 0.f, a1e = 0.f, a1o = 0.f;
#pragma unroll 2
    for (int c4 = 0; c4 < 96; c4 += 2) {
        float4 gv0 = gp[c4], gv1 = gp[c4 + 1];
        float4 wa0 = w0p[c4], wa1 = w0p[c4 + 1];
        float4 wb0 = w1p[c4], wb1 = w1p[c4 + 1];
        a0e = fmaf(gv0.x, wa0.x, a0e); a0e = fmaf(gv0.y, wa0.y, a0e);
        a0e = fmaf(gv0.z, wa0.z, a0e); a0e = fmaf(gv0.w, wa0.w, a0e);
        a1e = fmaf(gv0.x, wb0.x, a1e); a1e = fmaf(gv0.y, wb0.y, a1e);
        a1e = fmaf(gv0.z, wb0.z, a1e); a1e = fmaf(gv0.w, wb0.w, a1e);
        a0o = fmaf(gv1.x, wa1.x, a0o); a0o = fmaf(gv1.y, wa1.y, a0o);
        a0o = fmaf(gv1.z, wa1.z, a0o); a0o = fmaf(gv1.w, wa1.w, a0o);
        a1o = fmaf(gv1.x, wb1.x, a1o); a1o = fmaf(gv1.y, wb1.y, a1o);
        a1o = fmaf(gv1.z, wb1.z, a1o); a1o = fmaf(gv1.w, wb1.w, a1o);
    }
    float a0 = a0e + a0o, a1 = a1e + a1o;

    int h0 = o0 & 7, wch0 = o0 >> 3;
    int h1 = o1 & 7, wch1 = o1 >> 3;
    float b0 = wch0 ? fgb[h0] : igb[h0];
    float b1 = wch1 ? fgb[h1] : igb[h1];
    int grow = row0 + rp;
    int bb = grow >> 8, ss = grow & 255;
    float* d0 = (wch0 ? fpb : ipb) + (size_t)(bb * cNH + h0) * cS + ss;
    float* d1 = (wch1 ? fpb : ipb) + (size_t)(bb * cNH + h1) * cS + ss;
    *d0 = a0 + b0; *d1 = a1 + b1;
}

// ---------------- fused mLSTM attention v8: native-K 32x32 MFMA ----------------
// QK^T via mfma_f32_32x32x16_bf16 (K=16=d exactly, no zero pad): 36 MFMA vs 136,
// 4x fewer chunk-units. PV (16x16x32) chunk-interleaved right after each 32-col
// QK chunk -> C buffer is only 32x40/wave (LDS ~47KB -> 3 blocks/CU). Normalizer
// row-sums in fp32 registers + shfl_xor reduce (ones-MFMA removed).
// Layouts: D32 col=lane&31,row=(reg&3)+8*(reg>>2)+4*(lane>>5); A row/B col=lane&31,
// same k-slot map both operands (pairing-invariant).
constexpr int QKW = 24;    // Q/K row width (shorts), rows 48B (16B-aligned)
constexpr int VTW = 264;   // Vt row width (528B, 16B-aligned)
constexpr int CBW = 40;    // C chunk row width (80B, 16B-aligned)

__global__ __launch_bounds__(256, 3) void attn_k(const float* __restrict__ qg, const float* __restrict__ kg,
                                                 const float* __restrict__ vg, const float* __restrict__ ipg,
                                                 const float* __restrict__ fpg, float* __restrict__ hatt) {
    int bh = blockIdx.x; int b = bh >> 3, h = bh & 7;
    int tid = threadIdx.x;
    int wid = tid >> 6, lane = tid & 63;
    int colL = lane & 15, grp = lane >> 4;       // PV-space
    int col32 = lane & 31, hi = lane >> 5;       // QK-space

    __shared__ float sEA[cS], sEMx[cS], sFlr[cS];
    __shared__ short sQ[cS * QKW], sK[cS * QKW];
    __shared__ short sVt[cMDH * VTW];
    __shared__ short sCb[4][32 * CBW];
    __shared__ float sSum[4][32];

    // --- gate scans; store derived sEA / sEMx / sFlr directly ---
    {
        const float4 fp4 = ((const float4*)(fpg + (size_t)bh * cS))[lane];
        const float4 ip4 = ((const float4*)(ipg + (size_t)bh * cS))[lane];
        float fpa[4] = {fp4.x, fp4.y, fp4.z, fp4.w};
        float ipa[4] = {ip4.x, ip4.y, ip4.z, ip4.w};
        float p[4];
        float run = 0.f;
#pragma unroll
        for (int i = 0; i < 4; ++i) {
            float xx = fpa[i];
            float lsg = fminf(xx, 0.f) - log1pf(expf(-fabsf(xx)));
            run += lsg; p[i] = run;
        }
        float cum = p[3];
#pragma unroll
        for (int off = 1; off < 64; off <<= 1) { float t = __shfl_up(cum, off); if (lane >= off) cum += t; }
        float excl = cum - p[3];
        float aa[4], fcv4[4];
#pragma unroll
        for (int i = 0; i < 4; ++i) {
            fcv4[i] = excl + p[i];
            aa[i] = ipa[i] - fcv4[i];
            sEA[lane * 4 + i] = __expf(aa[i]);
        }
        float mq[4]; mq[0] = aa[0];
#pragma unroll
        for (int i = 1; i < 4; ++i) mq[i] = fmaxf(mq[i - 1], aa[i]);
        float cm = mq[3];
#pragma unroll
        for (int off = 1; off < 64; off <<= 1) { float t = __shfl_up(cm, off); if (lane >= off) cm = fmaxf(cm, t); }
        float exm = __shfl_up(cm, 1);
        if (lane == 0) exm = -3.0e38f;
#pragma unroll
        for (int i = 0; i < 4; ++i) {
            float Mx = fmaxf(exm, mq[i]);
            sEMx[lane * 4 + i] = 0.25f * __expf(-Mx);
            sFlr[lane * 4 + i] = __expf(-(fcv4[i] + Mx));
        }
    }

    // --- stage Q,K (bf16 row-major) and V^T (bf16) ---
    {
        int t = tid;
        const float4* qp = (const float4*)(qg + ((size_t)(b * cS) + t) * cI + h * cMDH);
        const float4* kp = (const float4*)(kg + ((size_t)(b * cS) + t) * cI + h * cMDH);
        const float4* vp = (const float4*)(vg + ((size_t)(b * cS) + t) * cI + h * cMDH);
        float4 q0 = qp[0], q1 = qp[1], q2 = qp[2], q3 = qp[3];
        float4 k0 = kp[0], k1 = kp[1], k2 = kp[2], k3 = kp[3];
        float4 v0 = vp[0], v1 = vp[1], v2 = vp[2], v3 = vp[3];
        short8v qa, qbv, ka, kbv;
        qa[0] = f2bf(q0.x); qa[1] = f2bf(q0.y); qa[2] = f2bf(q0.z); qa[3] = f2bf(q0.w);
        qa[4] = f2bf(q1.x); qa[5] = f2bf(q1.y); qa[6] = f2bf(q1.z); qa[7] = f2bf(q1.w);
        qbv[0] = f2bf(q2.x); qbv[1] = f2bf(q2.y); qbv[2] = f2bf(q2.z); qbv[3] = f2bf(q2.w);
        qbv[4] = f2bf(q3.x); qbv[5] = f2bf(q3.y); qbv[6] = f2bf(q3.z); qbv[7] = f2bf(q3.w);
        ka[0] = f2bf(k0.x); ka[1] = f2bf(k0.y); ka[2] = f2bf(k0.z); ka[3] = f2bf(k0.w);
        ka[4] = f2bf(k1.x); ka[5] = f2bf(k1.y); ka[6] = f2bf(k1.z); ka[7] = f2bf(k1.w);
        kbv[0] = f2bf(k2.x); kbv[1] = f2bf(k2.y); kbv[2] = f2bf(k2.z); kbv[3] = f2bf(k2.w);
        kbv[4] = f2bf(k3.x); kbv[5] = f2bf(k3.y); kbv[6] = f2bf(k3.z); kbv[7] = f2bf(k3.w);
        *(short8v*)(sQ + t * QKW) = qa;
        *(short8v*)(sQ + t * QKW + 8) = qbv;
        *(short8v*)(sK + t * QKW) = ka;
        *(short8v*)(sK + t * QKW + 8) = kbv;
        sVt[0 * VTW + t] = f2bf(v0.x);  sVt[1 * VTW + t] = f2bf(v0.y);
        sVt[2 * VTW + t] = f2bf(v0.z);  sVt[3 * VTW + t] = f2bf(v0.w);
        sVt[4 * VTW + t] = f2bf(v1.x);  sVt[5 * VTW + t] = f2bf(v1.y);
        sVt[6 * VTW + t] = f2bf(v1.z);  sVt[7 * VTW + t] = f2bf(v1.w);
        sVt[8 * VTW + t] = f2bf(v2.x);  sVt[9 * VTW + t] = f2bf(v2.y);
        sVt[10 * VTW + t] = f2bf(v2.z); sVt[11 * VTW + t] = f2bf(v2.w);
        sVt[12 * VTW + t] = f2bf(v3.x); sVt[13 * VTW + t] = f2bf(v3.y);
        sVt[14 * VTW + t] = f2bf(v3.z); sVt[15 * VTW + t] = f2bf(v3.w);
    }
    __syncthreads();

    short* Cb = sCb[wid];
    float* Sm = sSum[wid];
    const int tiles2[2] = {wid, 7 - wid};        // 32-row s-tiles, balanced (9 chunks each)

    for (int sti = 0; sti < 2; ++sti) {
        int st = tiles2[sti];
        int s0 = st * 32;

        short8v aQ = *(const short8v*)(sQ + (s0 + col32) * QKW + hi * 8);
        int r16[16]; float eMx16[16];
#pragma unroll
        for (int reg = 0; reg < 16; ++reg) {
            int r = (reg & 3) + 8 * (reg >> 2) + 4 * hi;
            r16[reg] = r;
            eMx16[reg] = sEMx[s0 + r];
        }
        float sum16[16];
#pragma unroll
        for (int reg = 0; reg < 16; ++reg) sum16[reg] = 0.f;
        f32x4 hacc0 = {0.f, 0.f, 0.f, 0.f}, hacc1 = {0.f, 0.f, 0.f, 0.f};

        for (int tt = 0; tt <= st; ++tt) {
            int t0 = tt * 32;
            short8v bK = *(const short8v*)(sK + (t0 + col32) * QKW + hi * 8);
            f32x16 zz = {0.f, 0.f, 0.f, 0.f, 0.f, 0.f, 0.f, 0.f,
                         0.f, 0.f, 0.f, 0.f, 0.f, 0.f, 0.f, 0.f};
            f32x16 d = __builtin_amdgcn_mfma_f32_32x32x16_bf16(aQ, bK, zz, 0, 0, 0);
            float ea = sEA[t0 + col32];
            bool diag = (tt == st);
#pragma unroll
            for (int reg = 0; reg < 16; ++reg) {
                float v = d[reg] * (ea * eMx16[reg]);
                if (diag && col32 > r16[reg]) v = 0.f;
                sum16[reg] += v;
                Cb[r16[reg] * CBW + col32] = f2bf(v);
            }
            // PV on this 32-col chunk (K=32 over t)
            short8v bV  = *(const short8v*)(sVt + colL * VTW + t0 + grp * 8);
            short8v aC0 = *(const short8v*)(Cb + colL * CBW + grp * 8);
            hacc0 = __builtin_amdgcn_mfma_f32_16x16x32_bf16(aC0, bV, hacc0, 0, 0, 0);
            short8v aC1 = *(const short8v*)(Cb + (16 + colL) * CBW + grp * 8);
            hacc1 = __builtin_amdgcn_mfma_f32_16x16x32_bf16(aC1, bV, hacc1, 0, 0, 0);
        }

        // row sums: reduce across the 32 lanes of each half
#pragma unroll
        for (int reg = 0; reg < 16; ++reg) {
            float s = sum16[reg];
#pragma unroll
            for (int m = 1; m < 32; m <<= 1) s += __shfl_xor(s, m);
            sum16[reg] = s;
        }
        if (col32 == 0) {
#pragma unroll
            for (int reg = 0; reg < 16; ++reg) Sm[r16[reg]] = sum16[reg];
        }

        // outputs (within-wave LDS ordering via compiler lgkmcnt)
#pragma unroll
        for (int sub = 0; sub < 2; ++sub) {
            f32x4 hacc = sub ? hacc1 : hacc0;
#pragma unroll
            for (int j = 0; j < 4; ++j) {
                int rloc = sub * 16 + grp * 4 + j;
                int sr = s0 + rloc;
                float sC = Sm[rloc];
                float nrm = fmaxf(fabsf(sC), sFlr[sr]) + 1e-6f;
                hatt[((size_t)(b * cS) + sr) * cI + h * cMDH + colL] = hacc[j] / nrm;
            }
        }
    }
}

// ---------------- fused multihead-norm + gate + down-projection + residual ----------------
__global__ __launch_bounds__(320) void down_mhn_k(const float* __restrict__ hatt, const float* __restrict__ xc,
                                                  const float* __restrict__ xmz, const float* __restrict__ mhnw,
                                                  const float* __restrict__ skip, const float* __restrict__ dw,
                                                  float* __restrict__ h) {
    __shared__ float yl[8 * 128];
    int row0 = blockIdx.x * 8;
    int tid = threadIdx.x;
    for (int i = tid; i < 1024; i += 320) yl[i] = hatt[(size_t)row0 * cI + i];
    __syncthreads();
    if (tid < 64) {
        int r = tid >> 3, hh = tid & 7;
        int row = row0 + r;
        float* g = yl + r * 128 + hh * 16;
        float xv[16];
        float mu = 0.f;
#pragma unroll
        for (int d = 0; d < 16; ++d) { xv[d] = g[d]; mu += xv[d]; }
        mu *= (1.f / 16);
        float va = 0.f;
#pragma unroll
        for (int d = 0; d < 16; ++d) { float dd = xv[d] - mu; va += dd * dd; }
        va *= (1.f / 16);
        float rs = rsqrtf(va + 1e-5f);
        const float* xcr = xc + (size_t)row * cI + hh * 16;
        const float* zr  = xmz + (size_t)row * 256 + 128 + hh * 16;
#pragma unroll
        for (int d = 0; d < 16; ++d) {
            int i = hh * 16 + d;
            float z = zr[d];
            float sg = 1.f / (1.f + __expf(-z));
            g[d] = ((xv[d] - mu) * rs * mhnw[i] + skip[i] * xcr[d]) * (z * sg);
        }
    }
    __syncthreads();
    int r = tid / 40, e = tid % 40;
    const float* dr = dw + e * cI;
    const float* yr = yl + r * cI;
    float acc = 0.f;
    for (int i = 0; i < cI; ++i) acc += yr[i] * dr[i];
    h[(size_t)(row0 + r) * cE + e] += acc;
}

// ---------------- plain row LayerNorm (E=40) ----------------
__global__ __launch_bounds__(256) void ln_rows_k(const float* __restrict__ h, const float* __restrict__ w,
                                                 float* __restrict__ out) {
    int rid = blockIdx.x * 256 + threadIdx.x;
    const float* r = h + (size_t)rid * cE;
    float mu = 0;
    for (int k = 0; k < cE; ++k) mu += r[k];
    mu *= (1.f / cE);
    float va = 0;
    for (int k = 0; k < cE; ++k) { float d = r[k] - mu; va += d * d; }
    va *= (1.f / cE);
    float rs = rsqrtf(va + 1e-5f);
    float* o = out + (size_t)rid * cE;
    for (int k = 0; k < cE; ++k) o[k] = (r[k] - mu) * rs * w[k];
}

// ---------------- sLSTM gate pre-activations; gall layout (S, B*NH, E=5, G=4) ----------------
__global__ __launch_bounds__(256) void sgates_k(const float* __restrict__ xcs, const float* __restrict__ ln1,
                                                const float* __restrict__ wi, const float* __restrict__ wf,
                                                const float* __restrict__ wz, const float* __restrict__ wo,
                                                float* __restrict__ gall) {
    int idx = blockIdx.x * 256 + threadIdx.x;   // S*1024*5*4
    int g = idx & 3; int r1 = idx >> 2;
    int e = r1 % 5; int r2 = r1 / 5;
    int bh = r2 & 1023; int s = r2 >> 10;
    int b = bh >> 3, h = bh & 7;
    const float* in = (g < 2) ? xcs : ln1;
    const float* w = (g == 0) ? wi : (g == 1) ? wf : (g == 2) ? wz : wo;
    const float* ir = in + ((size_t)(b * cS) + s) * cE + h * cDH;
    const float* wp = w + h * 25 + e * 5;
    float acc = 0.f;
#pragma unroll
    for (int i = 0; i < 5; ++i) acc += ir[i] * wp[i];
    gall[idx] = acc;
}

// ---------------- sLSTM sequential scan: 8 chains per wave ----------------
__global__ __launch_bounds__(64) void scan_k(const float* __restrict__ gall, const float* __restrict__ R,
                                             const float* __restrict__ bias, const float* __restrict__ mhnw,
                                             float* __restrict__ hbuf) {
    int lane = threadIdx.x;
    int grp = lane >> 3;
    int e = lane & 7;
    int ee = e < 5 ? e : 4;
    int bh = blockIdx.x * 8 + grp;
    int h = bh & 7;

    __shared__ float sOut[8][1285];

    float Rr[4][5];
#pragma unroll
    for (int g = 0; g < 4; ++g)
#pragma unroll
        for (int d = 0; d < 5; ++d) Rr[g][d] = R[h * 100 + g * 25 + d * 5 + ee];
    float bg[4];
#pragma unroll
    for (int g = 0; g < 4; ++g) bg[g] = bias[h * 20 + g * 5 + ee];
    float wmh = mhnw[h * 5 + ee];

    const float4* gp = (const float4*)gall + ((size_t)bh * 5 + ee);

    float4 rg[16];
#pragma unroll
    for (int j = 0; j < 16; ++j) rg[j] = gp[(size_t)j * 5120];

    float cstate = 0.f, nstate = 0.f, mstate = 0.f;
    float hs0 = 0.f, hs1 = 0.f, hs2 = 0.f, hs3 = 0.f, hs4 = 0.f;

    for (int t = 0; t < cS; t += 16) {
#pragma unroll
        for (int j = 0; j < 16; ++j) {
            float4 g4 = rg[j];
            rg[j] = gp[(size_t)(t + j + 16) * 5120];

            float ir = g4.x + bg[0], fr = g4.y + bg[1], zr = g4.z + bg[2], orr = g4.w + bg[3];
            ir = fmaf(hs0, Rr[0][0], ir); fr = fmaf(hs0, Rr[1][0], fr);
            zr = fmaf(hs0, Rr[2][0], zr); orr = fmaf(hs0, Rr[3][0], orr);
            ir = fmaf(hs1, Rr[0][1], ir); fr = fmaf(hs1, Rr[1][1], fr);
            zr = fmaf(hs1, Rr[2][1], zr); orr = fmaf(hs1, Rr[3][1], orr);
            ir = fmaf(hs2, Rr[0][2], ir); fr = fmaf(hs2, Rr[1][2], fr);
            zr = fmaf(hs2, Rr[2][2], zr); orr = fmaf(hs2, Rr[3][2], orr);
            ir = fmaf(hs3, Rr[0][3], ir); fr = fmaf(hs3, Rr[1][3], fr);
            zr = fmaf(hs3, Rr[2][3], zr); orr = fmaf(hs3, Rr[3][3], orr);
            ir = fmaf(hs4, Rr[0][4], ir); fr = fmaf(hs4, Rr[1][4], fr);
            zr = fmaf(hs4, Rr[2][4], zr); orr = fmaf(hs4, Rr[3][4], orr);

            float lsg = fminf(fr, 0.f) - __logf(1.f + __expf(-fabsf(fr)));
            float lfm = mstate + lsg;
            float mn = fmaxf(ir, lfm);
            float ig = __expf(ir - mn), fg = __expf(lfm - mn);
            float th = 1.f - 2.f * __builtin_amdgcn_rcpf(__expf(2.f * zr) + 1.f);
            float cn = fg * cstate + ig * th;
            float nn = fg * nstate + ig;
            float sg = __builtin_amdgcn_rcpf(1.f + __expf(-orr));
            float hn = sg * cn * __builtin_amdgcn_rcpf(nn);
            cstate = cn; nstate = nn; mstate = mn;

            hs0 = BC8(hn, 0); hs1 = BC8(hn, 1); hs2 = BC8(hn, 2);
            hs3 = BC8(hn, 3); hs4 = BC8(hn, 4);
            float mu = ((hs0 + hs1) + (hs2 + hs3) + hs4) * 0.2f;
            float d0 = hs0 - mu, d1 = hs1 - mu, d2 = hs2 - mu, d3 = hs3 - mu, d4 = hs4 - mu;
            float va = (d0 * d0 + d1 * d1 + d2 * d2 + d3 * d3 + d4 * d4) * 0.2f;
            float rs = __builtin_amdgcn_rsqf(va + 1e-5f);
            if (e < 5) sOut[grp][(t + j) * 5 + e] = (hn - mu) * rs * wmh;
        }
    }
    __syncthreads();

    for (int i = lane; i < 8 * 1280; i += 64) {
        int c = i / 1280;
        int r = i - c * 1280;
        int tt = r / 5, e2 = r - tt * 5;
        int bh2 = blockIdx.x * 8 + c;
        int b2 = bh2 >> 3, h2 = bh2 & 7;
        float* hp = hbuf + ((size_t)b2 * cS + tt) * cE + h2 * cDH + e2;
        *hp += sOut[c][r];
    }
}

// ---------------- FFN fused: LN + up-proj + GELU gate + down-proj + residual ----------------
__global__ __launch_bounds__(256) void ff_k(float* __restrict__ h, const float* __restrict__ lnw,
                                            const float* __restrict__ upw, const float* __restrict__ dnw) {
    __shared__ float lnr[8][cE];
    __shared__ float ffr[8][64];
    int row0 = blockIdx.x * 8;
    int tid = threadIdx.x;
    if (tid < 8) {
        const float* r = h + (size_t)(row0 + tid) * cE;
        float mu = 0;
        for (int k = 0; k < cE; ++k) mu += r[k];
        mu *= (1.f / cE);
        float va = 0;
        for (int k = 0; k < cE; ++k) { float d = r[k] - mu; va += d * d; }
        va *= (1.f / cE);
        float rs = rsqrtf(va + 1e-5f);
        for (int k = 0; k < cE; ++k) lnr[tid][k] = (r[k] - mu) * rs * lnw[k];
    }
    __syncthreads();
    {
        int r = tid >> 5;            // 0..7
        int f0 = (tid & 31) * 2;
#pragma unroll
        for (int ff = 0; ff < 2; ++ff) {
            int f = f0 + ff;
            float a = 0, u = 0;
            const float* wa = upw + f * cE;
            const float* wu = upw + (64 + f) * cE;
            for (int k = 0; k < cE; ++k) {
                float xv = lnr[r][k];
                a = fmaf(xv, wa[k], a);
                u = fmaf(xv, wu[k], u);
            }
            float g = 0.5f * a * (1.f + erff(a * 0.70710678118f));
            ffr[r][f] = g * u;
        }
    }
    __syncthreads();
    for (int i = tid; i < 320; i += 256) {
        int r = i / 40, e = i - r * 40;
        const float* dr = dnw + e * 64;
        const float* fr = ffr[r];
        float acc = 0.f;
        for (int k = 0; k < 64; ++k) acc = fmaf(fr[k], dr[k], acc);
        h[(size_t)(row0 + r) * cE + e] += acc;
    }
}

// ---------------- final LN + out projection ----------------
__global__ __launch_bounds__(256) void final_k(const float* __restrict__ h, const float* __restrict__ lnw,
                                               const float* __restrict__ ow, const float* __restrict__ ob,
                                               float* __restrict__ out) {
    int rid = blockIdx.x * 256 + threadIdx.x;
    const float* r = h + (size_t)rid * cE;
    float mu = 0;
    for (int k = 0; k < cE; ++k) mu += r[k];
    mu *= (1.f / cE);
    float va = 0;
    for (int k = 0; k < cE; ++k) { float d = r[k] - mu; va += d * d; }
    va *= (1.f / cE);
    float rs = rsqrtf(va + 1e-5f);
    float acc = ob[0];
    for (int k = 0; k < cE; ++k) acc += (r[k] - mu) * rs * lnw[k] * ow[k];
    out[rid] = acc;
}

extern "C" void kernel_launch(void* const* d_in, const int* in_sizes, int n_in,
                              void* d_out, int out_size, void* d_ws, size_t ws_size,
                              hipStream_t stream) {
    const float* x        = (const float*)d_in[0];
    const float* in_w     = (const float*)d_in[1];
    const float* in_b     = (const float*)d_in[2];
    const float* m_ln_w   = (const float*)d_in[3];
    const float* m_up_w   = (const float*)d_in[4];
    const float* m_conv_w = (const float*)d_in[5];
    const float* m_conv_b = (const float*)d_in[6];
    const float* m_q_w    = (const float*)d_in[7];
    const float* m_k_w    = (const float*)d_in[8];
    const float* m_v_w    = (const float*)d_in[9];
    const float* m_ig_w   = (const float*)d_in[10];
    const float* m_ig_b   = (const float*)d_in[11];
    const float* m_fg_w   = (const float*)d_in[12];
    const float* m_fg_b   = (const float*)d_in[13];
    const float* m_mhn_w  = (const float*)d_in[14];
    const float* m_skip   = (const float*)d_in[15];
    const float* m_down_w = (const float*)d_in[16];
    const float* s_ln1_w  = (const float*)d_in[17];
    const float* s_conv_w = (const float*)d_in[18];
    const float* s_conv_b = (const float*)d_in[19];
    const float* s_wi     = (const float*)d_in[20];
    const float* s_wf     = (const float*)d_in[21];
    const float* s_wz     = (const float*)d_in[22];
    const float* s_wo     = (const float*)d_in[23];
    const float* s_R      = (const float*)d_in[24];
    const float* s_bias   = (const float*)d_in[25];
    const float* s_mhn_w  = (const float*)d_in[26];
    const float* s_ln2_w  = (const float*)d_in[27];
    const float* s_ff_up  = (const float*)d_in[28];
    const float* s_ff_dn  = (const float*)d_in[29];
    const float* post_ln_w= (const float*)d_in[30];
    const float* out_w    = (const float*)d_in[31];
    const float* out_b    = (const float*)d_in[32];

    float* ws   = (float*)d_ws;
    float* h    = ws;                     // 1,310,720
    float* xmz  = h + 1310720;            // 8,388,608
    float* xc   = xmz + 8388608;          // 4,194,304
    float* qb   = xc + 4194304;           // 4,194,304
    float* kb   = qb + 4194304;           // 4,194,304
    float* vb   = kb + 4194304;           // 4,194,304
    float* ipb  = vb + 4194304;           //   262,144
    float* fpb  = ipb + 262144;           //   262,144
    float* hatt = fpb + 262144;           // 4,194,304
    float* lnbuf = xmz;
    float* xcs   = xmz + 1310720;
    float* gall  = xmz + 2621440;

    init_k<<<5120, 256, 0, stream>>>(x, in_w, in_b, h);

    auto mlstm = [&](int j) {
        ln_up_k<<<2048, 256, 0, stream>>>(h, m_ln_w + j * cE, m_up_w + (size_t)j * 256 * cE, xmz);
        conv_silu_k<128><<<16384, 256, 0, stream>>>(xmz, 256, m_conv_w + j * cI * cK, m_conv_b + j * cI, xc);
        qkv_k<<<16384, 256, 0, stream>>>(xc, xmz, m_q_w + j * 512, m_k_w + j * 512, m_v_w + j * 512, qb, kb, vb);
        gates_k<<<1024, 256, 0, stream>>>(qb, kb, vb, m_ig_w + j * cNH * 384, m_ig_b + j * cNH,
                                          m_fg_w + j * cNH * 384, m_fg_b + j * cNH, ipb, fpb);
        attn_k<<<1024, 256, 0, stream>>>(qb, kb, vb, ipb, fpb, hatt);
        down_mhn_k<<<4096, 320, 0, stream>>>(hatt, xc, xmz, m_mhn_w + j * cI, m_skip + j * cI,
                                             m_down_w + j * cE * cI, h);
    };

    mlstm(0);

    ln_rows_k<<<128, 256, 0, stream>>>(h, s_ln1_w, lnbuf);
    conv_silu_k<40><<<5120, 256, 0, stream>>>(lnbuf, 40, s_conv_w, s_conv_b, xcs);
    sgates_k<<<20480, 256, 0, stream>>>(xcs, lnbuf, s_wi, s_wf, s_wz, s_wo, gall);
    scan_k<<<128, 64, 0, stream>>>(gall, s_R, s_bias, s_mhn_w, h);

    ff_k<<<4096, 256, 0, stream>>>(h, s_ln2_w, s_ff_up, s_ff_dn);

    mlstm(1);
    mlstm(2);

    final_k<<<128, 256, 0, stream>>>(h, post_ln_w, out_w, out_b, (float*)d_out);
}

// Round 16
// 822.001 us; speedup vs baseline: 1.0781x; 1.0233x over previous
//
#include <hip/hip_runtime.h>
#include <math.h>

constexpr int cB = 128, cS = 256, cF = 10, cE = 40, cNH = 8, cDH = 5;
constexpr int cI = 128, cMDH = 16, cK = 4;

typedef __attribute__((ext_vector_type(8))) short short8v;   // 8 bf16 (4 VGPRs)
typedef __attribute__((ext_vector_type(4))) float f32x4;
typedef __attribute__((ext_vector_type(16))) float f32x16;

#define BC8(v, l) __uint_as_float(__builtin_amdgcn_ds_swizzle(__float_as_uint(v), ((l) << 5) | 0x18))

__device__ __forceinline__ short f2bf(float f) {      // fp32 -> bf16 RTNE
    unsigned u = __float_as_uint(f);
    u += 0x7FFF + ((u >> 16) & 1);
    return (short)(u >> 16);
}
__device__ __forceinline__ float bf2f(short s) {
    return __uint_as_float(((unsigned)(unsigned short)s) << 16);
}

// ---------------- h = x @ in_w.T + in_b + pos_encoding ----------------
__global__ __launch_bounds__(256) void init_k(const float* __restrict__ x, const float* __restrict__ w,
                                              const float* __restrict__ b, float* __restrict__ h) {
    int idx = blockIdx.x * 256 + threadIdx.x;     // B*S*E
    int e = idx % cE; int bs = idx / cE; int s = bs % cS;
    float acc = b[e];
    const float* xr = x + (size_t)bs * cF;
#pragma unroll
    for (int f = 0; f < cF; ++f) acc += xr[f] * w[e * cF + f];
    int i2 = e >> 1;
    float div = expf(-(float)(2 * i2) * (logf(10000.f) / 40.0f));
    float arg = (float)s * div;
    acc += (e & 1) ? cosf(arg) : sinf(arg);
    h[idx] = acc;
}

// ---------------- fused LayerNorm + up-projection (E=40 -> 256) v2 ----------------
__global__ __launch_bounds__(256) void ln_up_k(const float* __restrict__ h, const float* __restrict__ lnw,
                                               const float* __restrict__ upw, float* __restrict__ xmz) {
    __shared__ float lnr[16][cE];
    __shared__ float wT[cE * 257];
    int row0 = blockIdx.x * 16;
    int tid = threadIdx.x;
    for (int j = tid; j < 2560; j += 256) {       // 256*40/4 float4s
        float4 v = ((const float4*)upw)[j];
        int o = j / 10, kq = (j - o * 10) * 4;
        wT[(kq + 0) * 257 + o] = v.x;
        wT[(kq + 1) * 257 + o] = v.y;
        wT[(kq + 2) * 257 + o] = v.z;
        wT[(kq + 3) * 257 + o] = v.w;
    }
    if (tid < 16) {
        const float* r = h + (size_t)(row0 + tid) * cE;
        float mu = 0.f;
        for (int k = 0; k < cE; ++k) mu += r[k];
        mu *= (1.f / cE);
        float va = 0.f;
        for (int k = 0; k < cE; ++k) { float d = r[k] - mu; va += d * d; }
        va *= (1.f / cE);
        float rs = rsqrtf(va + 1e-5f);
        for (int k = 0; k < cE; ++k) lnr[tid][k] = (r[k] - mu) * rs * lnw[k];
    }
    __syncthreads();
    int o = tid;
    float acc[16];
#pragma unroll
    for (int r = 0; r < 16; ++r) acc[r] = 0.f;
    for (int k = 0; k < cE; ++k) {
        float wv = wT[k * 257 + o];
#pragma unroll
        for (int r = 0; r < 16; ++r) acc[r] = fmaf(lnr[r][k], wv, acc[r]);
    }
#pragma unroll
    for (int r = 0; r < 16; ++r) xmz[(size_t)(row0 + r) * 256 + o] = acc[r];
}

// ---------------- depthwise causal conv (K=4) + SiLU ----------------
template <int C>
__global__ __launch_bounds__(256) void conv_silu_k(const float* __restrict__ in, int instride,
                                                   const float* __restrict__ w, const float* __restrict__ bias,
                                                   float* __restrict__ out) {
    int idx = blockIdx.x * 256 + threadIdx.x;   // B*S*C
    int c = idx % C; int bs = idx / C; int s = bs % cS;
    float acc = bias[c];
#pragma unroll
    for (int j = 0; j < cK; ++j) {
        int sj = s - 3 + j;
        if (sj >= 0) acc += in[(size_t)(bs + j - 3) * instride + c] * w[c * cK + j];
    }
    float sg = 1.f / (1.f + __expf(-acc));
    out[idx] = acc * sg;
}

// ---------------- block-diagonal headwise q,k,v -> bf16 buffers ----------------
// fp32 math, bf16 stores: halves qkv write + gates/attn read traffic; attn's
// staging conversions disappear (it consumed bf16 anyway).
__global__ __launch_bounds__(256) void qkv_k(const float* __restrict__ xc, const float* __restrict__ xmz,
                                             const float* __restrict__ qw, const float* __restrict__ kw,
                                             const float* __restrict__ vw,
                                             short* __restrict__ qb, short* __restrict__ kb, short* __restrict__ vb) {
    int idx = blockIdx.x * 256 + threadIdx.x;   // B*S*I
    int c = idx & 127; int bs = idx >> 7;
    int n = c >> 2, o = c & 3;
    const float* xcr = xc + (size_t)bs * cI + n * 4;
    const float* xmr = xmz + (size_t)bs * 256 + n * 4;
    const float* qwp = qw + n * 16 + o * 4;
    const float* kwp = kw + n * 16 + o * 4;
    const float* vwp = vw + n * 16 + o * 4;
    float aq = 0, ak = 0, av = 0;
#pragma unroll
    for (int i = 0; i < 4; ++i) { float a = xcr[i], m = xmr[i]; aq += a * qwp[i]; ak += a * kwp[i]; av += m * vwp[i]; }
    qb[idx] = f2bf(aq); kb[idx] = f2bf(ak); vb[idx] = f2bf(av);
}

// ---------------- input/forget gate pre-activations ip, fp (B,NH,S) v4 ----------------
// bf16 inputs converted to fp32 during LDS staging; GEMV math unchanged (fp32).
__global__ __launch_bounds__(256, 2) void gates_k(const short* __restrict__ qb, const short* __restrict__ kb,
                                                  const short* __restrict__ vb, const float* __restrict__ igw,
                                                  const float* __restrict__ igb, const float* __restrict__ fgw,
                                                  const float* __restrict__ fgb,
                                                  float* __restrict__ ipb, float* __restrict__ fpb) {
    __shared__ float g[32 * 388];
    __shared__ float w[16 * 388];
    int row0 = blockIdx.x * 32;
    int tid = threadIdx.x;

    for (int i = tid; i < 16 * 96; i += 256) {
        int r = i / 96, c4 = i - r * 96;
        const float* src = (r < 8) ? (igw + r * 384) : (fgw + (r - 8) * 384);
        *(float4*)&w[r * 388 + c4 * 4] = ((const float4*)src)[c4];
    }
    for (int i = tid; i < 32 * 48; i += 256) {        // 48 short8-groups / row
        int r = i / 48, c8 = i - r * 48;
        size_t gr = (size_t)(row0 + r) * cI;
        const short8v* src = (c8 < 16) ? (const short8v*)(qb + gr) + c8
                           : (c8 < 32) ? (const short8v*)(kb + gr) + (c8 - 16)
                                       : (const short8v*)(vb + gr) + (c8 - 32);
        short8v v = *src;
        float* dst = &g[r * 388 + c8 * 8];
#pragma unroll
        for (int j = 0; j < 8; ++j) dst[j] = bf2f(v[j]);
    }
    __syncthreads();

    int rp = tid >> 3;              // row 0..31
    int hp = tid & 7;               // out-pair 0..7
    int o0 = 2 * hp, o1 = o0 + 1;

    const float4* gp = (const float4*)(g + rp * 388);
    const float4* w0p = (const float4*)(w + o0 * 388);
    const float4* w1p = (const float4*)(w + o1 * 388);

    float a0e = 0.f, a0o = 0.f, a1e = 0.f, a1o = 0.f;
#pragma unroll 2
    for (int c4 = 0; c4 < 96; c4 += 2) {
        float4 gv0 = gp[c4], gv1 = gp[c4 + 1];
        float4 wa0 = w0p[c4], wa1 = w0p[c4 + 1];
        float4 wb0 = w1p[c4], wb1 = w1p[c4 + 1];
        a0e = fmaf(gv0.x, wa0.x, a0e); a0e = fmaf(gv0.y, wa0.y, a0e);
        a0e = fmaf(gv0.z, wa0.z, a0e); a0e = fmaf(gv0.w, wa0.w, a0e);
        a1e = fmaf(gv0.x, wb0.x, a1e); a1e = fmaf(gv0.y, wb0.y, a1e);
        a1e = fmaf(gv0.z, wb0.z, a1e); a1e = fmaf(gv0.w, wb0.w, a1e);
        a0o = fmaf(gv1.x, wa1.x, a0o); a0o = fmaf(gv1.y, wa1.y, a0o);
        a0o = fmaf(gv1.z, wa1.z, a0o); a0o = fmaf(gv1.w, wa1.w, a0o);
        a1o = fmaf(gv1.x, wb1.x, a1o); a1o = fmaf(gv1.y, wb1.y, a1o);
        a1o = fmaf(gv1.z, wb1.z, a1o); a1o = fmaf(gv1.w, wb1.w, a1o);
    }
    float a0 = a0e + a0o, a1 = a1e + a1o;

    int h0 = o0 & 7, wch0 = o0 >> 3;
    int h1 = o1 & 7, wch1 = o1 >> 3;
    float b0 = wch0 ? fgb[h0] : igb[h0];
    float b1 = wch1 ? fgb[h1] : igb[h1];
    int grow = row0 + rp;
    int bb = grow >> 8, ss = grow & 255;
    float* d0 = (wch0 ? fpb : ipb) + (size_t)(bb * cNH + h0) * cS + ss;
    float* d1 = (wch1 ? fpb : ipb) + (size_t)(bb * cNH + h1) * cS + ss;
    *d0 = a0 + b0; *d1 = a1 + b1;
}

// ---------------- fused mLSTM attention v9: native-K 32x32 MFMA, bf16 inputs ----------------
// Same structure as v8; Q/K staging is now a straight short8v copy (inputs are
// already bf16) and V-transpose is copy-only.
constexpr int QKW = 24;    // Q/K row width (shorts), rows 48B (16B-aligned)
constexpr int VTW = 264;   // Vt row width (528B, 16B-aligned)
constexpr int CBW = 40;    // C chunk row width (80B, 16B-aligned)

__global__ __launch_bounds__(256, 3) void attn_k(const short* __restrict__ qg, const short* __restrict__ kg,
                                                 const short* __restrict__ vg, const float* __restrict__ ipg,
                                                 const float* __restrict__ fpg, float* __restrict__ hatt) {
    int bh = blockIdx.x; int b = bh >> 3, h = bh & 7;
    int tid = threadIdx.x;
    int wid = tid >> 6, lane = tid & 63;
    int colL = lane & 15, grp = lane >> 4;       // PV-space
    int col32 = lane & 31, hi = lane >> 5;       // QK-space

    __shared__ float sEA[cS], sEMx[cS], sFlr[cS];
    __shared__ short sQ[cS * QKW], sK[cS * QKW];
    __shared__ short sVt[cMDH * VTW];
    __shared__ short sCb[4][32 * CBW];
    __shared__ float sSum[4][32];

    // --- gate scans; store derived sEA / sEMx / sFlr directly ---
    {
        const float4 fp4 = ((const float4*)(fpg + (size_t)bh * cS))[lane];
        const float4 ip4 = ((const float4*)(ipg + (size_t)bh * cS))[lane];
        float fpa[4] = {fp4.x, fp4.y, fp4.z, fp4.w};
        float ipa[4] = {ip4.x, ip4.y, ip4.z, ip4.w};
        float p[4];
        float run = 0.f;
#pragma unroll
        for (int i = 0; i < 4; ++i) {
            float xx = fpa[i];
            float lsg = fminf(xx, 0.f) - log1pf(expf(-fabsf(xx)));
            run += lsg; p[i] = run;
        }
        float cum = p[3];
#pragma unroll
        for (int off = 1; off < 64; off <<= 1) { float t = __shfl_up(cum, off); if (lane >= off) cum += t; }
        float excl = cum - p[3];
        float aa[4], fcv4[4];
#pragma unroll
        for (int i = 0; i < 4; ++i) {
            fcv4[i] = excl + p[i];
            aa[i] = ipa[i] - fcv4[i];
            sEA[lane * 4 + i] = __expf(aa[i]);
        }
        float mq[4]; mq[0] = aa[0];
#pragma unroll
        for (int i = 1; i < 4; ++i) mq[i] = fmaxf(mq[i - 1], aa[i]);
        float cm = mq[3];
#pragma unroll
        for (int off = 1; off < 64; off <<= 1) { float t = __shfl_up(cm, off); if (lane >= off) cm = fmaxf(cm, t); }
        float exm = __shfl_up(cm, 1);
        if (lane == 0) exm = -3.0e38f;
#pragma unroll
        for (int i = 0; i < 4; ++i) {
            float Mx = fmaxf(exm, mq[i]);
            sEMx[lane * 4 + i] = 0.25f * __expf(-Mx);
            sFlr[lane * 4 + i] = __expf(-(fcv4[i] + Mx));
        }
    }

    // --- stage Q,K (straight copies) and V^T (copy-transpose) ---
    {
        int t = tid;
        const short8v* qp = (const short8v*)(qg + ((size_t)(b * cS) + t) * cI + h * cMDH);
        const short8v* kp = (const short8v*)(kg + ((size_t)(b * cS) + t) * cI + h * cMDH);
        const short8v* vp = (const short8v*)(vg + ((size_t)(b * cS) + t) * cI + h * cMDH);
        *(short8v*)(sQ + t * QKW) = qp[0];
        *(short8v*)(sQ + t * QKW + 8) = qp[1];
        *(short8v*)(sK + t * QKW) = kp[0];
        *(short8v*)(sK + t * QKW + 8) = kp[1];
        short8v v0 = vp[0], v1 = vp[1];
#pragma unroll
        for (int d = 0; d < 8; ++d) sVt[d * VTW + t] = v0[d];
#pragma unroll
        for (int d = 0; d < 8; ++d) sVt[(8 + d) * VTW + t] = v1[d];
    }
    __syncthreads();

    short* Cb = sCb[wid];
    float* Sm = sSum[wid];
    const int tiles2[2] = {wid, 7 - wid};        // 32-row s-tiles, balanced

    for (int sti = 0; sti < 2; ++sti) {
        int st = tiles2[sti];
        int s0 = st * 32;

        short8v aQ = *(const short8v*)(sQ + (s0 + col32) * QKW + hi * 8);
        int r16[16]; float eMx16[16];
#pragma unroll
        for (int reg = 0; reg < 16; ++reg) {
            int r = (reg & 3) + 8 * (reg >> 2) + 4 * hi;
            r16[reg] = r;
            eMx16[reg] = sEMx[s0 + r];
        }
        float sum16[16];
#pragma unroll
        for (int reg = 0; reg < 16; ++reg) sum16[reg] = 0.f;
        f32x4 hacc0 = {0.f, 0.f, 0.f, 0.f}, hacc1 = {0.f, 0.f, 0.f, 0.f};

        for (int tt = 0; tt <= st; ++tt) {
            int t0 = tt * 32;
            short8v bK = *(const short8v*)(sK + (t0 + col32) * QKW + hi * 8);
            f32x16 zz = {0.f, 0.f, 0.f, 0.f, 0.f, 0.f, 0.f, 0.f,
                         0.f, 0.f, 0.f, 0.f, 0.f, 0.f, 0.f, 0.f};
            f32x16 d = __builtin_amdgcn_mfma_f32_32x32x16_bf16(aQ, bK, zz, 0, 0, 0);
            float ea = sEA[t0 + col32];
            bool diag = (tt == st);
#pragma unroll
            for (int reg = 0; reg < 16; ++reg) {
                float v = d[reg] * (ea * eMx16[reg]);
                if (diag && col32 > r16[reg]) v = 0.f;
                sum16[reg] += v;
                Cb[r16[reg] * CBW + col32] = f2bf(v);
            }
            short8v bV  = *(const short8v*)(sVt + colL * VTW + t0 + grp * 8);
            short8v aC0 = *(const short8v*)(Cb + colL * CBW + grp * 8);
            hacc0 = __builtin_amdgcn_mfma_f32_16x16x32_bf16(aC0, bV, hacc0, 0, 0, 0);
            short8v aC1 = *(const short8v*)(Cb + (16 + colL) * CBW + grp * 8);
            hacc1 = __builtin_amdgcn_mfma_f32_16x16x32_bf16(aC1, bV, hacc1, 0, 0, 0);
        }

#pragma unroll
        for (int reg = 0; reg < 16; ++reg) {
            float s = sum16[reg];
#pragma unroll
            for (int m = 1; m < 32; m <<= 1) s += __shfl_xor(s, m);
            sum16[reg] = s;
        }
        if (col32 == 0) {
#pragma unroll
            for (int reg = 0; reg < 16; ++reg) Sm[r16[reg]] = sum16[reg];
        }

#pragma unroll
        for (int sub = 0; sub < 2; ++sub) {
            f32x4 hacc = sub ? hacc1 : hacc0;
#pragma unroll
            for (int j = 0; j < 4; ++j) {
                int rloc = sub * 16 + grp * 4 + j;
                int sr = s0 + rloc;
                float sC = Sm[rloc];
                float nrm = fmaxf(fabsf(sC), sFlr[sr]) + 1e-6f;
                hatt[((size_t)(b * cS) + sr) * cI + h * cMDH + colL] = hacc[j] / nrm;
            }
        }
    }
}

// ---------------- fused multihead-norm + gate + down-projection + residual ----------------
__global__ __launch_bounds__(320) void down_mhn_k(const float* __restrict__ hatt, const float* __restrict__ xc,
                                                  const float* __restrict__ xmz, const float* __restrict__ mhnw,
                                                  const float* __restrict__ skip, const float* __restrict__ dw,
                                                  float* __restrict__ h) {
    __shared__ float yl[8 * 128];
    int row0 = blockIdx.x * 8;
    int tid = threadIdx.x;
    for (int i = tid; i < 1024; i += 320) yl[i] = hatt[(size_t)row0 * cI + i];
    __syncthreads();
    if (tid < 64) {
        int r = tid >> 3, hh = tid & 7;
        int row = row0 + r;
        float* g = yl + r * 128 + hh * 16;
        float xv[16];
        float mu = 0.f;
#pragma unroll
        for (int d = 0; d < 16; ++d) { xv[d] = g[d]; mu += xv[d]; }
        mu *= (1.f / 16);
        float va = 0.f;
#pragma unroll
        for (int d = 0; d < 16; ++d) { float dd = xv[d] - mu; va += dd * dd; }
        va *= (1.f / 16);
        float rs = rsqrtf(va + 1e-5f);
        const float* xcr = xc + (size_t)row * cI + hh * 16;
        const float* zr  = xmz + (size_t)row * 256 + 128 + hh * 16;
#pragma unroll
        for (int d = 0; d < 16; ++d) {
            int i = hh * 16 + d;
            float z = zr[d];
            float sg = 1.f / (1.f + __expf(-z));
            g[d] = ((xv[d] - mu) * rs * mhnw[i] + skip[i] * xcr[d]) * (z * sg);
        }
    }
    __syncthreads();
    int r = tid / 40, e = tid % 40;
    const float* dr = dw + e * cI;
    const float* yr = yl + r * cI;
    float acc = 0.f;
    for (int i = 0; i < cI; ++i) acc += yr[i] * dr[i];
    h[(size_t)(row0 + r) * cE + e] += acc;
}

// ---------------- plain row LayerNorm (E=40) ----------------
__global__ __launch_bounds__(256) void ln_rows_k(const float* __restrict__ h, const float* __restrict__ w,
                                                 float* __restrict__ out) {
    int rid = blockIdx.x * 256 + threadIdx.x;
    const float* r = h + (size_t)rid * cE;
    float mu = 0;
    for (int k = 0; k < cE; ++k) mu += r[k];
    mu *= (1.f / cE);
    float va = 0;
    for (int k = 0; k < cE; ++k) { float d = r[k] - mu; va += d * d; }
    va *= (1.f / cE);
    float rs = rsqrtf(va + 1e-5f);
    float* o = out + (size_t)rid * cE;
    for (int k = 0; k < cE; ++k) o[k] = (r[k] - mu) * rs * w[k];
}

// ---------------- sLSTM gate pre-activations; gall layout (S, B*NH, E=5, G=4) ----------------
__global__ __launch_bounds__(256) void sgates_k(const float* __restrict__ xcs, const float* __restrict__ ln1,
                                                const float* __restrict__ wi, const float* __restrict__ wf,
                                                const float* __restrict__ wz, const float* __restrict__ wo,
                                                float* __restrict__ gall) {
    int idx = blockIdx.x * 256 + threadIdx.x;   // S*1024*5*4
    int g = idx & 3; int r1 = idx >> 2;
    int e = r1 % 5; int r2 = r1 / 5;
    int bh = r2 & 1023; int s = r2 >> 10;
    int b = bh >> 3, h = bh & 7;
    const float* in = (g < 2) ? xcs : ln1;
    const float* w = (g == 0) ? wi : (g == 1) ? wf : (g == 2) ? wz : wo;
    const float* ir = in + ((size_t)(b * cS) + s) * cE + h * cDH;
    const float* wp = w + h * 25 + e * 5;
    float acc = 0.f;
#pragma unroll
    for (int i = 0; i < 5; ++i) acc += ir[i] * wp[i];
    gall[idx] = acc;
}

// ---------------- sLSTM sequential scan: 8 chains per wave ----------------
__global__ __launch_bounds__(64) void scan_k(const float* __restrict__ gall, const float* __restrict__ R,
                                             const float* __restrict__ bias, const float* __restrict__ mhnw,
                                             float* __restrict__ hbuf) {
    int lane = threadIdx.x;
    int grp = lane >> 3;
    int e = lane & 7;
    int ee = e < 5 ? e : 4;
    int bh = blockIdx.x * 8 + grp;
    int h = bh & 7;

    __shared__ float sOut[8][1285];

    float Rr[4][5];
#pragma unroll
    for (int g = 0; g < 4; ++g)
#pragma unroll
        for (int d = 0; d < 5; ++d) Rr[g][d] = R[h * 100 + g * 25 + d * 5 + ee];
    float bg[4];
#pragma unroll
    for (int g = 0; g < 4; ++g) bg[g] = bias[h * 20 + g * 5 + ee];
    float wmh = mhnw[h * 5 + ee];

    const float4* gp = (const float4*)gall + ((size_t)bh * 5 + ee);

    float4 rg[16];
#pragma unroll
    for (int j = 0; j < 16; ++j) rg[j] = gp[(size_t)j * 5120];

    float cstate = 0.f, nstate = 0.f, mstate = 0.f;
    float hs0 = 0.f, hs1 = 0.f, hs2 = 0.f, hs3 = 0.f, hs4 = 0.f;

    for (int t = 0; t < cS; t += 16) {
#pragma unroll
        for (int j = 0; j < 16; ++j) {
            float4 g4 = rg[j];
            rg[j] = gp[(size_t)(t + j + 16) * 5120];

            float ir = g4.x + bg[0], fr = g4.y + bg[1], zr = g4.z + bg[2], orr = g4.w + bg[3];
            ir = fmaf(hs0, Rr[0][0], ir); fr = fmaf(hs0, Rr[1][0], fr);
            zr = fmaf(hs0, Rr[2][0], zr); orr = fmaf(hs0, Rr[3][0], orr);
            ir = fmaf(hs1, Rr[0][1], ir); fr = fmaf(hs1, Rr[1][1], fr);
            zr = fmaf(hs1, Rr[2][1], zr); orr = fmaf(hs1, Rr[3][1], orr);
            ir = fmaf(hs2, Rr[0][2], ir); fr = fmaf(hs2, Rr[1][2], fr);
            zr = fmaf(hs2, Rr[2][2], zr); orr = fmaf(hs2, Rr[3][2], orr);
            ir = fmaf(hs3, Rr[0][3], ir); fr = fmaf(hs3, Rr[1][3], fr);
            zr = fmaf(hs3, Rr[2][3], zr); orr = fmaf(hs3, Rr[3][3], orr);
            ir = fmaf(hs4, Rr[0][4], ir); fr = fmaf(hs4, Rr[1][4], fr);
            zr = fmaf(hs4, Rr[2][4], zr); orr = fmaf(hs4, Rr[3][4], orr);

            float lsg = fminf(fr, 0.f) - __logf(1.f + __expf(-fabsf(fr)));
            float lfm = mstate + lsg;
            float mn = fmaxf(ir, lfm);
            float ig = __expf(ir - mn), fg = __expf(lfm - mn);
            float th = 1.f - 2.f * __builtin_amdgcn_rcpf(__expf(2.f * zr) + 1.f);
            float cn = fg * cstate + ig * th;
            float nn = fg * nstate + ig;
            float sg = __builtin_amdgcn_rcpf(1.f + __expf(-orr));
            float hn = sg * cn * __builtin_amdgcn_rcpf(nn);
            cstate = cn; nstate = nn; mstate = mn;

            hs0 = BC8(hn, 0); hs1 = BC8(hn, 1); hs2 = BC8(hn, 2);
            hs3 = BC8(hn, 3); hs4 = BC8(hn, 4);
            float mu = ((hs0 + hs1) + (hs2 + hs3) + hs4) * 0.2f;
            float d0 = hs0 - mu, d1 = hs1 - mu, d2 = hs2 - mu, d3 = hs3 - mu, d4 = hs4 - mu;
            float va = (d0 * d0 + d1 * d1 + d2 * d2 + d3 * d3 + d4 * d4) * 0.2f;
            float rs = __builtin_amdgcn_rsqf(va + 1e-5f);
            if (e < 5) sOut[grp][(t + j) * 5 + e] = (hn - mu) * rs * wmh;
        }
    }
    __syncthreads();

    for (int i = lane; i < 8 * 1280; i += 64) {
        int c = i / 1280;
        int r = i - c * 1280;
        int tt = r / 5, e2 = r - tt * 5;
        int bh2 = blockIdx.x * 8 + c;
        int b2 = bh2 >> 3, h2 = bh2 & 7;
        float* hp = hbuf + ((size_t)b2 * cS + tt) * cE + h2 * cDH + e2;
        *hp += sOut[c][r];
    }
}

// ---------------- FFN fused: LN + up-proj + GELU gate + down-proj + residual ----------------
__global__ __launch_bounds__(256) void ff_k(float* __restrict__ h, const float* __restrict__ lnw,
                                            const float* __restrict__ upw, const float* __restrict__ dnw) {
    __shared__ float lnr[8][cE];
    __shared__ float ffr[8][64];
    int row0 = blockIdx.x * 8;
    int tid = threadIdx.x;
    if (tid < 8) {
        const float* r = h + (size_t)(row0 + tid) * cE;
        float mu = 0;
        for (int k = 0; k < cE; ++k) mu += r[k];
        mu *= (1.f / cE);
        float va = 0;
        for (int k = 0; k < cE; ++k) { float d = r[k] - mu; va += d * d; }
        va *= (1.f / cE);
        float rs = rsqrtf(va + 1e-5f);
        for (int k = 0; k < cE; ++k) lnr[tid][k] = (r[k] - mu) * rs * lnw[k];
    }
    __syncthreads();
    {
        int r = tid >> 5;            // 0..7
        int f0 = (tid & 31) * 2;
#pragma unroll
        for (int ff = 0; ff < 2; ++ff) {
            int f = f0 + ff;
            float a = 0, u = 0;
            const float* wa = upw + f * cE;
            const float* wu = upw + (64 + f) * cE;
            for (int k = 0; k < cE; ++k) {
                float xv = lnr[r][k];
                a = fmaf(xv, wa[k], a);
                u = fmaf(xv, wu[k], u);
            }
            float g = 0.5f * a * (1.f + erff(a * 0.70710678118f));
            ffr[r][f] = g * u;
        }
    }
    __syncthreads();
    for (int i = tid; i < 320; i += 256) {
        int r = i / 40, e = i - r * 40;
        const float* dr = dnw + e * 64;
        const float* fr = ffr[r];
        float acc = 0.f;
        for (int k = 0; k < 64; ++k) acc = fmaf(fr[k], dr[k], acc);
        h[(size_t)(row0 + r) * cE + e] += acc;
    }
}

// ---------------- final LN + out projection ----------------
__global__ __launch_bounds__(256) void final_k(const float* __restrict__ h, const float* __restrict__ lnw,
                                               const float* __restrict__ ow, const float* __restrict__ ob,
                                               float* __restrict__ out) {
    int rid = blockIdx.x * 256 + threadIdx.x;
    const float* r = h + (size_t)rid * cE;
    float mu = 0;
    for (int k = 0; k < cE; ++k) mu += r[k];
    mu *= (1.f / cE);
    float va = 0;
    for (int k = 0; k < cE; ++k) { float d = r[k] - mu; va += d * d; }
    va *= (1.f / cE);
    float rs = rsqrtf(va + 1e-5f);
    float acc = ob[0];
    for (int k = 0; k < cE; ++k) acc += (r[k] - mu) * rs * lnw[k] * ow[k];
    out[rid] = acc;
}

extern "C" void kernel_launch(void* const* d_in, const int* in_sizes, int n_in,
                              void* d_out, int out_size, void* d_ws, size_t ws_size,
                              hipStream_t stream) {
    const float* x        = (const float*)d_in[0];
    const float* in_w     = (const float*)d_in[1];
    const float* in_b     = (const float*)d_in[2];
    const float* m_ln_w   = (const float*)d_in[3];
    const float* m_up_w   = (const float*)d_in[4];
    const float* m_conv_w = (const float*)d_in[5];
    const float* m_conv_b = (const float*)d_in[6];
    const float* m_q_w    = (const float*)d_in[7];
    const float* m_k_w    = (const float*)d_in[8];
    const float* m_v_w    = (const float*)d_in[9];
    const float* m_ig_w   = (const float*)d_in[10];
    const float* m_ig_b   = (const float*)d_in[11];
    const float* m_fg_w   = (const float*)d_in[12];
    const float* m_fg_b   = (const float*)d_in[13];
    const float* m_mhn_w  = (const float*)d_in[14];
    const float* m_skip   = (const float*)d_in[15];
    const float* m_down_w = (const float*)d_in[16];
    const float* s_ln1_w  = (const float*)d_in[17];
    const float* s_conv_w = (const float*)d_in[18];
    const float* s_conv_b = (const float*)d_in[19];
    const float* s_wi     = (const float*)d_in[20];
    const float* s_wf     = (const float*)d_in[21];
    const float* s_wz     = (const float*)d_in[22];
    const float* s_wo     = (const float*)d_in[23];
    const float* s_R      = (const float*)d_in[24];
    const float* s_bias   = (const float*)d_in[25];
    const float* s_mhn_w  = (const float*)d_in[26];
    const float* s_ln2_w  = (const float*)d_in[27];
    const float* s_ff_up  = (const float*)d_in[28];
    const float* s_ff_dn  = (const float*)d_in[29];
    const float* post_ln_w= (const float*)d_in[30];
    const float* out_w    = (const float*)d_in[31];
    const float* out_b    = (const float*)d_in[32];

    float* ws   = (float*)d_ws;
    float* h    = ws;                     // 1,310,720
    float* xmz  = h + 1310720;            // 8,388,608
    float* xc   = xmz + 8388608;          // 4,194,304
    short* qb   = (short*)(xc + 4194304); // 4,194,304 shorts
    short* kb   = qb + 4194304;           // 4,194,304 shorts
    short* vb   = kb + 4194304;           // 4,194,304 shorts
    float* ipb  = (float*)(vb + 4194304); //   262,144
    float* fpb  = ipb + 262144;           //   262,144
    float* hatt = fpb + 262144;           // 4,194,304
    // slstm aliases into the xmz region (dead there)
    float* lnbuf = xmz;
    float* xcs   = xmz + 1310720;
    float* gall  = xmz + 2621440;

    init_k<<<5120, 256, 0, stream>>>(x, in_w, in_b, h);

    auto mlstm = [&](int j) {
        ln_up_k<<<2048, 256, 0, stream>>>(h, m_ln_w + j * cE, m_up_w + (size_t)j * 256 * cE, xmz);
        conv_silu_k<128><<<16384, 256, 0, stream>>>(xmz, 256, m_conv_w + j * cI * cK, m_conv_b + j * cI, xc);
        qkv_k<<<16384, 256, 0, stream>>>(xc, xmz, m_q_w + j * 512, m_k_w + j * 512, m_v_w + j * 512, qb, kb, vb);
        gates_k<<<1024, 256, 0, stream>>>(qb, kb, vb, m_ig_w + j * cNH * 384, m_ig_b + j * cNH,
                                          m_fg_w + j * cNH * 384, m_fg_b + j * cNH, ipb, fpb);
        attn_k<<<1024, 256, 0, stream>>>(qb, kb, vb, ipb, fpb, hatt);
        down_mhn_k<<<4096, 320, 0, stream>>>(hatt, xc, xmz, m_mhn_w + j * cI, m_skip + j * cI,
                                             m_down_w + j * cE * cI, h);
    };

    mlstm(0);

    ln_rows_k<<<128, 256, 0, stream>>>(h, s_ln1_w, lnbuf);
    conv_silu_k<40><<<5120, 256, 0, stream>>>(lnbuf, 40, s_conv_w, s_conv_b, xcs);
    sgates_k<<<20480, 256, 0, stream>>>(xcs, lnbuf, s_wi, s_wf, s_wz, s_wo, gall);
    scan_k<<<128, 64, 0, stream>>>(gall, s_R, s_bias, s_mhn_w, h);

    ff_k<<<4096, 256, 0, stream>>>(h, s_ln2_w, s_ff_up, s_ff_dn);

    mlstm(1);
    mlstm(2);

    final_k<<<128, 256, 0, stream>>>(h, post_ln_w, out_w, out_b, (float*)d_out);
}

// Round 17
// 808.743 us; speedup vs baseline: 1.0958x; 1.0164x over previous
//
#include <hip/hip_runtime.h>
#include <math.h>

constexpr int cB = 128, cS = 256, cF = 10, cE = 40, cNH = 8, cDH = 5;
constexpr int cI = 128, cMDH = 16, cK = 4;

typedef __attribute__((ext_vector_type(8))) short short8v;   // 8 bf16 (4 VGPRs)
typedef __attribute__((ext_vector_type(4))) float f32x4;
typedef __attribute__((ext_vector_type(16))) float f32x16;

#define BC8(v, l) __uint_as_float(__builtin_amdgcn_ds_swizzle(__float_as_uint(v), ((l) << 5) | 0x18))

__device__ __forceinline__ short f2bf(float f) {      // fp32 -> bf16 RTNE
    unsigned u = __float_as_uint(f);
    u += 0x7FFF + ((u >> 16) & 1);
    return (short)(u >> 16);
}
__device__ __forceinline__ float bf2f(short s) {
    return __uint_as_float(((unsigned)(unsigned short)s) << 16);
}

// ---------------- h = x @ in_w.T + in_b + pos_encoding ----------------
__global__ __launch_bounds__(256) void init_k(const float* __restrict__ x, const float* __restrict__ w,
                                              const float* __restrict__ b, float* __restrict__ h) {
    int idx = blockIdx.x * 256 + threadIdx.x;     // B*S*E
    int e = idx % cE; int bs = idx / cE; int s = bs % cS;
    float acc = b[e];
    const float* xr = x + (size_t)bs * cF;
#pragma unroll
    for (int f = 0; f < cF; ++f) acc += xr[f] * w[e * cF + f];
    int i2 = e >> 1;
    float div = expf(-(float)(2 * i2) * (logf(10000.f) / 40.0f));
    float arg = (float)s * div;
    acc += (e & 1) ? cosf(arg) : sinf(arg);
    h[idx] = acc;
}

// ---------------- fused LayerNorm + up-projection (E=40 -> 256) v2 ----------------
__global__ __launch_bounds__(256) void ln_up_k(const float* __restrict__ h, const float* __restrict__ lnw,
                                               const float* __restrict__ upw, float* __restrict__ xmz) {
    __shared__ float lnr[16][cE];
    __shared__ float wT[cE * 257];
    int row0 = blockIdx.x * 16;
    int tid = threadIdx.x;
    for (int j = tid; j < 2560; j += 256) {       // 256*40/4 float4s
        float4 v = ((const float4*)upw)[j];
        int o = j / 10, kq = (j - o * 10) * 4;
        wT[(kq + 0) * 257 + o] = v.x;
        wT[(kq + 1) * 257 + o] = v.y;
        wT[(kq + 2) * 257 + o] = v.z;
        wT[(kq + 3) * 257 + o] = v.w;
    }
    if (tid < 16) {
        const float* r = h + (size_t)(row0 + tid) * cE;
        float mu = 0.f;
        for (int k = 0; k < cE; ++k) mu += r[k];
        mu *= (1.f / cE);
        float va = 0.f;
        for (int k = 0; k < cE; ++k) { float d = r[k] - mu; va += d * d; }
        va *= (1.f / cE);
        float rs = rsqrtf(va + 1e-5f);
        for (int k = 0; k < cE; ++k) lnr[tid][k] = (r[k] - mu) * rs * lnw[k];
    }
    __syncthreads();
    int o = tid;
    float acc[16];
#pragma unroll
    for (int r = 0; r < 16; ++r) acc[r] = 0.f;
    for (int k = 0; k < cE; ++k) {
        float wv = wT[k * 257 + o];
#pragma unroll
        for (int r = 0; r < 16; ++r) acc[r] = fmaf(lnr[r][k], wv, acc[r]);
    }
#pragma unroll
    for (int r = 0; r < 16; ++r) xmz[(size_t)(row0 + r) * 256 + o] = acc[r];
}

// ---------------- depthwise causal conv (K=4) + SiLU, fp32 out (slstm path) ----------------
template <int C>
__global__ __launch_bounds__(256) void conv_silu_k(const float* __restrict__ in, int instride,
                                                   const float* __restrict__ w, const float* __restrict__ bias,
                                                   float* __restrict__ out) {
    int idx = blockIdx.x * 256 + threadIdx.x;   // B*S*C
    int c = idx % C; int bs = idx / C; int s = bs % cS;
    float acc = bias[c];
#pragma unroll
    for (int j = 0; j < cK; ++j) {
        int sj = s - 3 + j;
        if (sj >= 0) acc += in[(size_t)(bs + j - 3) * instride + c] * w[c * cK + j];
    }
    float sg = 1.f / (1.f + __expf(-acc));
    out[idx] = acc * sg;
}

// ---------------- depthwise causal conv (K=4) + SiLU, bf16 out (mlstm path) ----------------
__global__ __launch_bounds__(256) void conv_silu_bf_k(const float* __restrict__ in,
                                                      const float* __restrict__ w, const float* __restrict__ bias,
                                                      short* __restrict__ out) {
    int idx = blockIdx.x * 256 + threadIdx.x;   // B*S*128
    int c = idx & 127; int bs = idx >> 7; int s = bs & 255;
    float acc = bias[c];
#pragma unroll
    for (int j = 0; j < cK; ++j) {
        int sj = s - 3 + j;
        if (sj >= 0) acc += in[(size_t)(bs + j - 3) * 256 + c] * w[c * cK + j];
    }
    float sg = 1.f / (1.f + __expf(-acc));
    out[idx] = f2bf(acc * sg);
}

// ---------------- block-diagonal headwise q,k,v -> bf16 buffers ----------------
__global__ __launch_bounds__(256) void qkv_k(const short* __restrict__ xc, const float* __restrict__ xmz,
                                             const float* __restrict__ qw, const float* __restrict__ kw,
                                             const float* __restrict__ vw,
                                             short* __restrict__ qb, short* __restrict__ kb, short* __restrict__ vb) {
    int idx = blockIdx.x * 256 + threadIdx.x;   // B*S*I
    int c = idx & 127; int bs = idx >> 7;
    int n = c >> 2, o = c & 3;
    const short* xcr = xc + (size_t)bs * cI + n * 4;
    const float* xmr = xmz + (size_t)bs * 256 + n * 4;
    const float* qwp = qw + n * 16 + o * 4;
    const float* kwp = kw + n * 16 + o * 4;
    const float* vwp = vw + n * 16 + o * 4;
    float aq = 0, ak = 0, av = 0;
#pragma unroll
    for (int i = 0; i < 4; ++i) {
        float a = bf2f(xcr[i]), m = xmr[i];
        aq += a * qwp[i]; ak += a * kwp[i]; av += m * vwp[i];
    }
    qb[idx] = f2bf(aq); kb[idx] = f2bf(ak); vb[idx] = f2bf(av);
}

// ---------------- input/forget gate pre-activations ip, fp (B,NH,S) v4 ----------------
__global__ __launch_bounds__(256, 2) void gates_k(const short* __restrict__ qb, const short* __restrict__ kb,
                                                  const short* __restrict__ vb, const float* __restrict__ igw,
                                                  const float* __restrict__ igb, const float* __restrict__ fgw,
                                                  const float* __restrict__ fgb,
                                                  float* __restrict__ ipb, float* __restrict__ fpb) {
    __shared__ float g[32 * 388];
    __shared__ float w[16 * 388];
    int row0 = blockIdx.x * 32;
    int tid = threadIdx.x;

    for (int i = tid; i < 16 * 96; i += 256) {
        int r = i / 96, c4 = i - r * 96;
        const float* src = (r < 8) ? (igw + r * 384) : (fgw + (r - 8) * 384);
        *(float4*)&w[r * 388 + c4 * 4] = ((const float4*)src)[c4];
    }
    for (int i = tid; i < 32 * 48; i += 256) {        // 48 short8-groups / row
        int r = i / 48, c8 = i - r * 48;
        size_t gr = (size_t)(row0 + r) * cI;
        const short8v* src = (c8 < 16) ? (const short8v*)(qb + gr) + c8
                           : (c8 < 32) ? (const short8v*)(kb + gr) + (c8 - 16)
                                       : (const short8v*)(vb + gr) + (c8 - 32);
        short8v v = *src;
        float* dst = &g[r * 388 + c8 * 8];
#pragma unroll
        for (int j = 0; j < 8; ++j) dst[j] = bf2f(v[j]);
    }
    __syncthreads();

    int rp = tid >> 3;              // row 0..31
    int hp = tid & 7;               // out-pair 0..7
    int o0 = 2 * hp, o1 = o0 + 1;

    const float4* gp = (const float4*)(g + rp * 388);
    const float4* w0p = (const float4*)(w + o0 * 388);
    const float4* w1p = (const float4*)(w + o1 * 388);

    float a0e = 0.f, a0o = 0.f, a1e = 0.f, a1o = 0.f;
#pragma unroll 2
    for (int c4 = 0; c4 < 96; c4 += 2) {
        float4 gv0 = gp[c4], gv1 = gp[c4 + 1];
        float4 wa0 = w0p[c4], wa1 = w0p[c4 + 1];
        float4 wb0 = w1p[c4], wb1 = w1p[c4 + 1];
        a0e = fmaf(gv0.x, wa0.x, a0e); a0e = fmaf(gv0.y, wa0.y, a0e);
        a0e = fmaf(gv0.z, wa0.z, a0e); a0e = fmaf(gv0.w, wa0.w, a0e);
        a1e = fmaf(gv0.x, wb0.x, a1e); a1e = fmaf(gv0.y, wb0.y, a1e);
        a1e = fmaf(gv0.z, wb0.z, a1e); a1e = fmaf(gv0.w, wb0.w, a1e);
        a0o = fmaf(gv1.x, wa1.x, a0o); a0o = fmaf(gv1.y, wa1.y, a0o);
        a0o = fmaf(gv1.z, wa1.z, a0o); a0o = fmaf(gv1.w, wa1.w, a0o);
        a1o = fmaf(gv1.x, wb1.x, a1o); a1o = fmaf(gv1.y, wb1.y, a1o);
        a1o = fmaf(gv1.z, wb1.z, a1o); a1o = fmaf(gv1.w, wb1.w, a1o);
    }
    float a0 = a0e + a0o, a1 = a1e + a1o;

    int h0 = o0 & 7, wch0 = o0 >> 3;
    int h1 = o1 & 7, wch1 = o1 >> 3;
    float b0 = wch0 ? fgb[h0] : igb[h0];
    float b1 = wch1 ? fgb[h1] : igb[h1];
    int grow = row0 + rp;
    int bb = grow >> 8, ss = grow & 255;
    float* d0 = (wch0 ? fpb : ipb) + (size_t)(bb * cNH + h0) * cS + ss;
    float* d1 = (wch1 ? fpb : ipb) + (size_t)(bb * cNH + h1) * cS + ss;
    *d0 = a0 + b0; *d1 = a1 + b1;
}

// ---------------- fused mLSTM attention v9: native-K 32x32 MFMA, bf16 in/out ----------------
constexpr int QKW = 24;    // Q/K row width (shorts), rows 48B (16B-aligned)
constexpr int VTW = 264;   // Vt row width (528B, 16B-aligned)
constexpr int CBW = 40;    // C chunk row width (80B, 16B-aligned)

__global__ __launch_bounds__(256, 3) void attn_k(const short* __restrict__ qg, const short* __restrict__ kg,
                                                 const short* __restrict__ vg, const float* __restrict__ ipg,
                                                 const float* __restrict__ fpg, short* __restrict__ hatt) {
    int bh = blockIdx.x; int b = bh >> 3, h = bh & 7;
    int tid = threadIdx.x;
    int wid = tid >> 6, lane = tid & 63;
    int colL = lane & 15, grp = lane >> 4;       // PV-space
    int col32 = lane & 31, hi = lane >> 5;       // QK-space

    __shared__ float sEA[cS], sEMx[cS], sFlr[cS];
    __shared__ short sQ[cS * QKW], sK[cS * QKW];
    __shared__ short sVt[cMDH * VTW];
    __shared__ short sCb[4][32 * CBW];
    __shared__ float sSum[4][32];

    // --- gate scans; store derived sEA / sEMx / sFlr directly ---
    {
        const float4 fp4 = ((const float4*)(fpg + (size_t)bh * cS))[lane];
        const float4 ip4 = ((const float4*)(ipg + (size_t)bh * cS))[lane];
        float fpa[4] = {fp4.x, fp4.y, fp4.z, fp4.w};
        float ipa[4] = {ip4.x, ip4.y, ip4.z, ip4.w};
        float p[4];
        float run = 0.f;
#pragma unroll
        for (int i = 0; i < 4; ++i) {
            float xx = fpa[i];
            float lsg = fminf(xx, 0.f) - log1pf(expf(-fabsf(xx)));
            run += lsg; p[i] = run;
        }
        float cum = p[3];
#pragma unroll
        for (int off = 1; off < 64; off <<= 1) { float t = __shfl_up(cum, off); if (lane >= off) cum += t; }
        float excl = cum - p[3];
        float aa[4], fcv4[4];
#pragma unroll
        for (int i = 0; i < 4; ++i) {
            fcv4[i] = excl + p[i];
            aa[i] = ipa[i] - fcv4[i];
            sEA[lane * 4 + i] = __expf(aa[i]);
        }
        float mq[4]; mq[0] = aa[0];
#pragma unroll
        for (int i = 1; i < 4; ++i) mq[i] = fmaxf(mq[i - 1], aa[i]);
        float cm = mq[3];
#pragma unroll
        for (int off = 1; off < 64; off <<= 1) { float t = __shfl_up(cm, off); if (lane >= off) cm = fmaxf(cm, t); }
        float exm = __shfl_up(cm, 1);
        if (lane == 0) exm = -3.0e38f;
#pragma unroll
        for (int i = 0; i < 4; ++i) {
            float Mx = fmaxf(exm, mq[i]);
            sEMx[lane * 4 + i] = 0.25f * __expf(-Mx);
            sFlr[lane * 4 + i] = __expf(-(fcv4[i] + Mx));
        }
    }

    // --- stage Q,K (straight copies) and V^T (copy-transpose) ---
    {
        int t = tid;
        const short8v* qp = (const short8v*)(qg + ((size_t)(b * cS) + t) * cI + h * cMDH);
        const short8v* kp = (const short8v*)(kg + ((size_t)(b * cS) + t) * cI + h * cMDH);
        const short8v* vp = (const short8v*)(vg + ((size_t)(b * cS) + t) * cI + h * cMDH);
        *(short8v*)(sQ + t * QKW) = qp[0];
        *(short8v*)(sQ + t * QKW + 8) = qp[1];
        *(short8v*)(sK + t * QKW) = kp[0];
        *(short8v*)(sK + t * QKW + 8) = kp[1];
        short8v v0 = vp[0], v1 = vp[1];
#pragma unroll
        for (int d = 0; d < 8; ++d) sVt[d * VTW + t] = v0[d];
#pragma unroll
        for (int d = 0; d < 8; ++d) sVt[(8 + d) * VTW + t] = v1[d];
    }
    __syncthreads();

    short* Cb = sCb[wid];
    float* Sm = sSum[wid];
    const int tiles2[2] = {wid, 7 - wid};        // 32-row s-tiles, balanced

    for (int sti = 0; sti < 2; ++sti) {
        int st = tiles2[sti];
        int s0 = st * 32;

        short8v aQ = *(const short8v*)(sQ + (s0 + col32) * QKW + hi * 8);
        int r16[16]; float eMx16[16];
#pragma unroll
        for (int reg = 0; reg < 16; ++reg) {
            int r = (reg & 3) + 8 * (reg >> 2) + 4 * hi;
            r16[reg] = r;
            eMx16[reg] = sEMx[s0 + r];
        }
        float sum16[16];
#pragma unroll
        for (int reg = 0; reg < 16; ++reg) sum16[reg] = 0.f;
        f32x4 hacc0 = {0.f, 0.f, 0.f, 0.f}, hacc1 = {0.f, 0.f, 0.f, 0.f};

        for (int tt = 0; tt <= st; ++tt) {
            int t0 = tt * 32;
            short8v bK = *(const short8v*)(sK + (t0 + col32) * QKW + hi * 8);
            f32x16 zz = {0.f, 0.f, 0.f, 0.f, 0.f, 0.f, 0.f, 0.f,
                         0.f, 0.f, 0.f, 0.f, 0.f, 0.f, 0.f, 0.f};
            f32x16 d = __builtin_amdgcn_mfma_f32_32x32x16_bf16(aQ, bK, zz, 0, 0, 0);
            float ea = sEA[t0 + col32];
            bool diag = (tt == st);
#pragma unroll
            for (int reg = 0; reg < 16; ++reg) {
                float v = d[reg] * (ea * eMx16[reg]);
                if (diag && col32 > r16[reg]) v = 0.f;
                sum16[reg] += v;
                Cb[r16[reg] * CBW + col32] = f2bf(v);
            }
            short8v bV  = *(const short8v*)(sVt + colL * VTW + t0 + grp * 8);
            short8v aC0 = *(const short8v*)(Cb + colL * CBW + grp * 8);
            hacc0 = __builtin_amdgcn_mfma_f32_16x16x32_bf16(aC0, bV, hacc0, 0, 0, 0);
            short8v aC1 = *(const short8v*)(Cb + (16 + colL) * CBW + grp * 8);
            hacc1 = __builtin_amdgcn_mfma_f32_16x16x32_bf16(aC1, bV, hacc1, 0, 0, 0);
        }

#pragma unroll
        for (int reg = 0; reg < 16; ++reg) {
            float s = sum16[reg];
#pragma unroll
            for (int m = 1; m < 32; m <<= 1) s += __shfl_xor(s, m);
            sum16[reg] = s;
        }
        if (col32 == 0) {
#pragma unroll
            for (int reg = 0; reg < 16; ++reg) Sm[r16[reg]] = sum16[reg];
        }

#pragma unroll
        for (int sub = 0; sub < 2; ++sub) {
            f32x4 hacc = sub ? hacc1 : hacc0;
#pragma unroll
            for (int j = 0; j < 4; ++j) {
                int rloc = sub * 16 + grp * 4 + j;
                int sr = s0 + rloc;
                float sC = Sm[rloc];
                float nrm = fmaxf(fabsf(sC), sFlr[sr]) + 1e-6f;
                hatt[((size_t)(b * cS) + sr) * cI + h * cMDH + colL] = f2bf(hacc[j] / nrm);
            }
        }
    }
}

// ---------------- fused multihead-norm + gate + down-projection + residual ----------------
__global__ __launch_bounds__(320) void down_mhn_k(const short* __restrict__ hatt, const short* __restrict__ xc,
                                                  const float* __restrict__ xmz, const float* __restrict__ mhnw,
                                                  const float* __restrict__ skip, const float* __restrict__ dw,
                                                  float* __restrict__ h) {
    __shared__ float yl[8 * 128];
    int row0 = blockIdx.x * 8;
    int tid = threadIdx.x;
    for (int i = tid; i < 128; i += 320) {       // 1024 bf16 = 128 short8v
        short8v v = ((const short8v*)(hatt + (size_t)row0 * cI))[i];
        float* dst = &yl[i * 8];
#pragma unroll
        for (int j = 0; j < 8; ++j) dst[j] = bf2f(v[j]);
    }
    __syncthreads();
    if (tid < 64) {
        int r = tid >> 3, hh = tid & 7;
        int row = row0 + r;
        float* g = yl + r * 128 + hh * 16;
        float xv[16];
        float mu = 0.f;
#pragma unroll
        for (int d = 0; d < 16; ++d) { xv[d] = g[d]; mu += xv[d]; }
        mu *= (1.f / 16);
        float va = 0.f;
#pragma unroll
        for (int d = 0; d < 16; ++d) { float dd = xv[d] - mu; va += dd * dd; }
        va *= (1.f / 16);
        float rs = rsqrtf(va + 1e-5f);
        const short* xcr = xc + (size_t)row * cI + hh * 16;
        const float* zr  = xmz + (size_t)row * 256 + 128 + hh * 16;
#pragma unroll
        for (int d = 0; d < 16; ++d) {
            int i = hh * 16 + d;
            float z = zr[d];
            float sg = 1.f / (1.f + __expf(-z));
            g[d] = ((xv[d] - mu) * rs * mhnw[i] + skip[i] * bf2f(xcr[d])) * (z * sg);
        }
    }
    __syncthreads();
    int r = tid / 40, e = tid % 40;
    const float* dr = dw + e * cI;
    const float* yr = yl + r * cI;
    float acc = 0.f;
    for (int i = 0; i < cI; ++i) acc += yr[i] * dr[i];
    h[(size_t)(row0 + r) * cE + e] += acc;
}

// ---------------- plain row LayerNorm (E=40) ----------------
__global__ __launch_bounds__(256) void ln_rows_k(const float* __restrict__ h, const float* __restrict__ w,
                                                 float* __restrict__ out) {
    int rid = blockIdx.x * 256 + threadIdx.x;
    const float* r = h + (size_t)rid * cE;
    float mu = 0;
    for (int k = 0; k < cE; ++k) mu += r[k];
    mu *= (1.f / cE);
    float va = 0;
    for (int k = 0; k < cE; ++k) { float d = r[k] - mu; va += d * d; }
    va *= (1.f / cE);
    float rs = rsqrtf(va + 1e-5f);
    float* o = out + (size_t)rid * cE;
    for (int k = 0; k < cE; ++k) o[k] = (r[k] - mu) * rs * w[k];
}

// ---------------- sLSTM gate pre-activations; gall layout (S, B*NH, E=5, G=4) ----------------
__global__ __launch_bounds__(256) void sgates_k(const float* __restrict__ xcs, const float* __restrict__ ln1,
                                                const float* __restrict__ wi, const float* __restrict__ wf,
                                                const float* __restrict__ wz, const float* __restrict__ wo,
                                                float* __restrict__ gall) {
    int idx = blockIdx.x * 256 + threadIdx.x;   // S*1024*5*4
    int g = idx & 3; int r1 = idx >> 2;
    int e = r1 % 5; int r2 = r1 / 5;
    int bh = r2 & 1023; int s = r2 >> 10;
    int b = bh >> 3, h = bh & 7;
    const float* in = (g < 2) ? xcs : ln1;
    const float* w = (g == 0) ? wi : (g == 1) ? wf : (g == 2) ? wz : wo;
    const float* ir = in + ((size_t)(b * cS) + s) * cE + h * cDH;
    const float* wp = w + h * 25 + e * 5;
    float acc = 0.f;
#pragma unroll
    for (int i = 0; i < 5; ++i) acc += ir[i] * wp[i];
    gall[idx] = acc;
}

// ---------------- sLSTM sequential scan: 8 chains per wave ----------------
__global__ __launch_bounds__(64) void scan_k(const float* __restrict__ gall, const float* __restrict__ R,
                                             const float* __restrict__ bias, const float* __restrict__ mhnw,
                                             float* __restrict__ hbuf) {
    int lane = threadIdx.x;
    int grp = lane >> 3;
    int e = lane & 7;
    int ee = e < 5 ? e : 4;
    int bh = blockIdx.x * 8 + grp;
    int h = bh & 7;

    __shared__ float sOut[8][1285];

    float Rr[4][5];
#pragma unroll
    for (int g = 0; g < 4; ++g)
#pragma unroll
        for (int d = 0; d < 5; ++d) Rr[g][d] = R[h * 100 + g * 25 + d * 5 + ee];
    float bg[4];
#pragma unroll
    for (int g = 0; g < 4; ++g) bg[g] = bias[h * 20 + g * 5 + ee];
    float wmh = mhnw[h * 5 + ee];

    const float4* gp = (const float4*)gall + ((size_t)bh * 5 + ee);

    float4 rg[16];
#pragma unroll
    for (int j = 0; j < 16; ++j) rg[j] = gp[(size_t)j * 5120];

    float cstate = 0.f, nstate = 0.f, mstate = 0.f;
    float hs0 = 0.f, hs1 = 0.f, hs2 = 0.f, hs3 = 0.f, hs4 = 0.f;

    for (int t = 0; t < cS; t += 16) {
#pragma unroll
        for (int j = 0; j < 16; ++j) {
            float4 g4 = rg[j];
            rg[j] = gp[(size_t)(t + j + 16) * 5120];

            float ir = g4.x + bg[0], fr = g4.y + bg[1], zr = g4.z + bg[2], orr = g4.w + bg[3];
            ir = fmaf(hs0, Rr[0][0], ir); fr = fmaf(hs0, Rr[1][0], fr);
            zr = fmaf(hs0, Rr[2][0], zr); orr = fmaf(hs0, Rr[3][0], orr);
            ir = fmaf(hs1, Rr[0][1], ir); fr = fmaf(hs1, Rr[1][1], fr);
            zr = fmaf(hs1, Rr[2][1], zr); orr = fmaf(hs1, Rr[3][1], orr);
            ir = fmaf(hs2, Rr[0][2], ir); fr = fmaf(hs2, Rr[1][2], fr);
            zr = fmaf(hs2, Rr[2][2], zr); orr = fmaf(hs2, Rr[3][2], orr);
            ir = fmaf(hs3, Rr[0][3], ir); fr = fmaf(hs3, Rr[1][3], fr);
            zr = fmaf(hs3, Rr[2][3], zr); orr = fmaf(hs3, Rr[3][3], orr);
            ir = fmaf(hs4, Rr[0][4], ir); fr = fmaf(hs4, Rr[1][4], fr);
            zr = fmaf(hs4, Rr[2][4], zr); orr = fmaf(hs4, Rr[3][4], orr);

            float lsg = fminf(fr, 0.f) - __logf(1.f + __expf(-fabsf(fr)));
            float lfm = mstate + lsg;
            float mn = fmaxf(ir, lfm);
            float ig = __expf(ir - mn), fg = __expf(lfm - mn);
            float th = 1.f - 2.f * __builtin_amdgcn_rcpf(__expf(2.f * zr) + 1.f);
            float cn = fg * cstate + ig * th;
            float nn = fg * nstate + ig;
            float sg = __builtin_amdgcn_rcpf(1.f + __expf(-orr));
            float hn = sg * cn * __builtin_amdgcn_rcpf(nn);
            cstate = cn; nstate = nn; mstate = mn;

            hs0 = BC8(hn, 0); hs1 = BC8(hn, 1); hs2 = BC8(hn, 2);
            hs3 = BC8(hn, 3); hs4 = BC8(hn, 4);
            float mu = ((hs0 + hs1) + (hs2 + hs3) + hs4) * 0.2f;
            float d0 = hs0 - mu, d1 = hs1 - mu, d2 = hs2 - mu, d3 = hs3 - mu, d4 = hs4 - mu;
            float va = (d0 * d0 + d1 * d1 + d2 * d2 + d3 * d3 + d4 * d4) * 0.2f;
            float rs = __builtin_amdgcn_rsqf(va + 1e-5f);
            if (e < 5) sOut[grp][(t + j) * 5 + e] = (hn - mu) * rs * wmh;
        }
    }
    __syncthreads();

    for (int i = lane; i < 8 * 1280; i += 64) {
        int c = i / 1280;
        int r = i - c * 1280;
        int tt = r / 5, e2 = r - tt * 5;
        int bh2 = blockIdx.x * 8 + c;
        int b2 = bh2 >> 3, h2 = bh2 & 7;
        float* hp = hbuf + ((size_t)b2 * cS + tt) * cE + h2 * cDH + e2;
        *hp += sOut[c][r];
    }
}

// ---------------- FFN fused: LN + up-proj + GELU gate + down-proj + residual ----------------
__global__ __launch_bounds__(256) void ff_k(float* __restrict__ h, const float* __restrict__ lnw,
                                            const float* __restrict__ upw, const float* __restrict__ dnw) {
    __shared__ float lnr[8][cE];
    __shared__ float ffr[8][64];
    int row0 = blockIdx.x * 8;
    int tid = threadIdx.x;
    if (tid < 8) {
        const float* r = h + (size_t)(row0 + tid) * cE;
        float mu = 0;
        for (int k = 0; k < cE; ++k) mu += r[k];
        mu *= (1.f / cE);
        float va = 0;
        for (int k = 0; k < cE; ++k) { float d = r[k] - mu; va += d * d; }
        va *= (1.f / cE);
        float rs = rsqrtf(va + 1e-5f);
        for (int k = 0; k < cE; ++k) lnr[tid][k] = (r[k] - mu) * rs * lnw[k];
    }
    __syncthreads();
    {
        int r = tid >> 5;            // 0..7
        int f0 = (tid & 31) * 2;
#pragma unroll
        for (int ff = 0; ff < 2; ++ff) {
            int f = f0 + ff;
            float a = 0, u = 0;
            const float* wa = upw + f * cE;
            const float* wu = upw + (64 + f) * cE;
            for (int k = 0; k < cE; ++k) {
                float xv = lnr[r][k];
                a = fmaf(xv, wa[k], a);
                u = fmaf(xv, wu[k], u);
            }
            float g = 0.5f * a * (1.f + erff(a * 0.70710678118f));
            ffr[r][f] = g * u;
        }
    }
    __syncthreads();
    for (int i = tid; i < 320; i += 256) {
        int r = i / 40, e = i - r * 40;
        const float* dr = dnw + e * 64;
        const float* fr = ffr[r];
        float acc = 0.f;
        for (int k = 0; k < 64; ++k) acc = fmaf(fr[k], dr[k], acc);
        h[(size_t)(row0 + r) * cE + e] += acc;
    }
}

// ---------------- final LN + out projection ----------------
__global__ __launch_bounds__(256) void final_k(const float* __restrict__ h, const float* __restrict__ lnw,
                                               const float* __restrict__ ow, const float* __restrict__ ob,
                                               float* __restrict__ out) {
    int rid = blockIdx.x * 256 + threadIdx.x;
    const float* r = h + (size_t)rid * cE;
    float mu = 0;
    for (int k = 0; k < cE; ++k) mu += r[k];
    mu *= (1.f / cE);
    float va = 0;
    for (int k = 0; k < cE; ++k) { float d = r[k] - mu; va += d * d; }
    va *= (1.f / cE);
    float rs = rsqrtf(va + 1e-5f);
    float acc = ob[0];
    for (int k = 0; k < cE; ++k) acc += (r[k] - mu) * rs * lnw[k] * ow[k];
    out[rid] = acc;
}

extern "C" void kernel_launch(void* const* d_in, const int* in_sizes, int n_in,
                              void* d_out, int out_size, void* d_ws, size_t ws_size,
                              hipStream_t stream) {
    const float* x        = (const float*)d_in[0];
    const float* in_w     = (const float*)d_in[1];
    const float* in_b     = (const float*)d_in[2];
    const float* m_ln_w   = (const float*)d_in[3];
    const float* m_up_w   = (const float*)d_in[4];
    const float* m_conv_w = (const float*)d_in[5];
    const float* m_conv_b = (const float*)d_in[6];
    const float* m_q_w    = (const float*)d_in[7];
    const float* m_k_w    = (const float*)d_in[8];
    const float* m_v_w    = (const float*)d_in[9];
    const float* m_ig_w   = (const float*)d_in[10];
    const float* m_ig_b   = (const float*)d_in[11];
    const float* m_fg_w   = (const float*)d_in[12];
    const float* m_fg_b   = (const float*)d_in[13];
    const float* m_mhn_w  = (const float*)d_in[14];
    const float* m_skip   = (const float*)d_in[15];
    const float* m_down_w = (const float*)d_in[16];
    const float* s_ln1_w  = (const float*)d_in[17];
    const float* s_conv_w = (const float*)d_in[18];
    const float* s_conv_b = (const float*)d_in[19];
    const float* s_wi     = (const float*)d_in[20];
    const float* s_wf     = (const float*)d_in[21];
    const float* s_wz     = (const float*)d_in[22];
    const float* s_wo     = (const float*)d_in[23];
    const float* s_R      = (const float*)d_in[24];
    const float* s_bias   = (const float*)d_in[25];
    const float* s_mhn_w  = (const float*)d_in[26];
    const float* s_ln2_w  = (const float*)d_in[27];
    const float* s_ff_up  = (const float*)d_in[28];
    const float* s_ff_dn  = (const float*)d_in[29];
    const float* post_ln_w= (const float*)d_in[30];
    const float* out_w    = (const float*)d_in[31];
    const float* out_b    = (const float*)d_in[32];

    float* ws   = (float*)d_ws;
    float* h    = ws;                      // 1,310,720 floats
    float* xmz  = h + 1310720;             // 8,388,608 floats
    short* xcb  = (short*)(xmz + 8388608); // 4,194,304 shorts
    short* qb   = xcb + 4194304;           // 4,194,304 shorts
    short* kb   = qb + 4194304;            // 4,194,304 shorts
    short* vb   = kb + 4194304;            // 4,194,304 shorts
    float* ipb  = (float*)(vb + 4194304);  //   262,144 floats
    float* fpb  = ipb + 262144;            //   262,144 floats
    short* hatt = (short*)(fpb + 262144);  // 4,194,304 shorts
    // slstm aliases into the xmz region (dead there)
    float* lnbuf = xmz;
    float* xcs   = xmz + 1310720;
    float* gall  = xmz + 2621440;

    init_k<<<5120, 256, 0, stream>>>(x, in_w, in_b, h);

    auto mlstm = [&](int j) {
        ln_up_k<<<2048, 256, 0, stream>>>(h, m_ln_w + j * cE, m_up_w + (size_t)j * 256 * cE, xmz);
        conv_silu_bf_k<<<16384, 256, 0, stream>>>(xmz, m_conv_w + j * cI * cK, m_conv_b + j * cI, xcb);
        qkv_k<<<16384, 256, 0, stream>>>(xcb, xmz, m_q_w + j * 512, m_k_w + j * 512, m_v_w + j * 512, qb, kb, vb);
        gates_k<<<1024, 256, 0, stream>>>(qb, kb, vb, m_ig_w + j * cNH * 384, m_ig_b + j * cNH,
                                          m_fg_w + j * cNH * 384, m_fg_b + j * cNH, ipb, fpb);
        attn_k<<<1024, 256, 0, stream>>>(qb, kb, vb, ipb, fpb, hatt);
        down_mhn_k<<<4096, 320, 0, stream>>>(hatt, xcb, xmz, m_mhn_w + j * cI, m_skip + j * cI,
                                             m_down_w + j * cE * cI, h);
    };

    mlstm(0);

    ln_rows_k<<<128, 256, 0, stream>>>(h, s_ln1_w, lnbuf);
    conv_silu_k<40><<<5120, 256, 0, stream>>>(lnbuf, 40, s_conv_w, s_conv_b, xcs);
    sgates_k<<<20480, 256, 0, stream>>>(xcs, lnbuf, s_wi, s_wf, s_wz, s_wo, gall);
    scan_k<<<128, 64, 0, stream>>>(gall, s_R, s_bias, s_mhn_w, h);

    ff_k<<<4096, 256, 0, stream>>>(h, s_ln2_w, s_ff_up, s_ff_dn);

    mlstm(1);
    mlstm(2);

    final_k<<<128, 256, 0, stream>>>(h, post_ln_w, out_w, out_b, (float*)d_out);
}

// Round 18
// 776.590 us; speedup vs baseline: 1.1412x; 1.0414x over previous
//
#include <hip/hip_runtime.h>
#include <math.h>

constexpr int cB = 128, cS = 256, cF = 10, cE = 40, cNH = 8, cDH = 5;
constexpr int cI = 128, cMDH = 16, cK = 4;

typedef __attribute__((ext_vector_type(8))) short short8v;   // 8 bf16 (4 VGPRs)
typedef __attribute__((ext_vector_type(4))) float f32x4;
typedef __attribute__((ext_vector_type(16))) float f32x16;

#define BC8(v, l) __uint_as_float(__builtin_amdgcn_ds_swizzle(__float_as_uint(v), ((l) << 5) | 0x18))

__device__ __forceinline__ short f2bf(float f) {      // fp32 -> bf16 RTNE
    unsigned u = __float_as_uint(f);
    u += 0x7FFF + ((u >> 16) & 1);
    return (short)(u >> 16);
}
__device__ __forceinline__ float bf2f(short s) {
    return __uint_as_float(((unsigned)(unsigned short)s) << 16);
}

// ---------------- h = x @ in_w.T + in_b + pos_encoding ----------------
__global__ __launch_bounds__(256) void init_k(const float* __restrict__ x, const float* __restrict__ w,
                                              const float* __restrict__ b, float* __restrict__ h) {
    int idx = blockIdx.x * 256 + threadIdx.x;     // B*S*E
    int e = idx % cE; int bs = idx / cE; int s = bs % cS;
    float acc = b[e];
    const float* xr = x + (size_t)bs * cF;
#pragma unroll
    for (int f = 0; f < cF; ++f) acc += xr[f] * w[e * cF + f];
    int i2 = e >> 1;
    float div = expf(-(float)(2 * i2) * (logf(10000.f) / 40.0f));
    float arg = (float)s * div;
    acc += (e & 1) ? cosf(arg) : sinf(arg);
    h[idx] = acc;
}

// ---------------- fused LayerNorm + up-projection (E=40 -> 256) v2 ----------------
__global__ __launch_bounds__(256) void ln_up_k(const float* __restrict__ h, const float* __restrict__ lnw,
                                               const float* __restrict__ upw, float* __restrict__ xmz) {
    __shared__ float lnr[16][cE];
    __shared__ float wT[cE * 257];
    int row0 = blockIdx.x * 16;
    int tid = threadIdx.x;
    for (int j = tid; j < 2560; j += 256) {       // 256*40/4 float4s
        float4 v = ((const float4*)upw)[j];
        int o = j / 10, kq = (j - o * 10) * 4;
        wT[(kq + 0) * 257 + o] = v.x;
        wT[(kq + 1) * 257 + o] = v.y;
        wT[(kq + 2) * 257 + o] = v.z;
        wT[(kq + 3) * 257 + o] = v.w;
    }
    if (tid < 16) {
        const float* r = h + (size_t)(row0 + tid) * cE;
        float mu = 0.f;
        for (int k = 0; k < cE; ++k) mu += r[k];
        mu *= (1.f / cE);
        float va = 0.f;
        for (int k = 0; k < cE; ++k) { float d = r[k] - mu; va += d * d; }
        va *= (1.f / cE);
        float rs = rsqrtf(va + 1e-5f);
        for (int k = 0; k < cE; ++k) lnr[tid][k] = (r[k] - mu) * rs * lnw[k];
    }
    __syncthreads();
    int o = tid;
    float acc[16];
#pragma unroll
    for (int r = 0; r < 16; ++r) acc[r] = 0.f;
    for (int k = 0; k < cE; ++k) {
        float wv = wT[k * 257 + o];
#pragma unroll
        for (int r = 0; r < 16; ++r) acc[r] = fmaf(lnr[r][k], wv, acc[r]);
    }
#pragma unroll
    for (int r = 0; r < 16; ++r) xmz[(size_t)(row0 + r) * 256 + o] = acc[r];
}

// ---------------- depthwise causal conv (K=4) + SiLU, fp32 out (slstm path) ----------------
template <int C>
__global__ __launch_bounds__(256) void conv_silu_k(const float* __restrict__ in, int instride,
                                                   const float* __restrict__ w, const float* __restrict__ bias,
                                                   float* __restrict__ out) {
    int idx = blockIdx.x * 256 + threadIdx.x;   // B*S*C
    int c = idx % C; int bs = idx / C; int s = bs % cS;
    float acc = bias[c];
#pragma unroll
    for (int j = 0; j < cK; ++j) {
        int sj = s - 3 + j;
        if (sj >= 0) acc += in[(size_t)(bs + j - 3) * instride + c] * w[c * cK + j];
    }
    float sg = 1.f / (1.f + __expf(-acc));
    out[idx] = acc * sg;
}

// ---------------- depthwise causal conv (K=4) + SiLU, bf16 out (mlstm path) ----------------
__global__ __launch_bounds__(256) void conv_silu_bf_k(const float* __restrict__ in,
                                                      const float* __restrict__ w, const float* __restrict__ bias,
                                                      short* __restrict__ out) {
    int idx = blockIdx.x * 256 + threadIdx.x;   // B*S*128
    int c = idx & 127; int bs = idx >> 7; int s = bs & 255;
    float acc = bias[c];
#pragma unroll
    for (int j = 0; j < cK; ++j) {
        int sj = s - 3 + j;
        if (sj >= 0) acc += in[(size_t)(bs + j - 3) * 256 + c] * w[c * cK + j];
    }
    float sg = 1.f / (1.f + __expf(-acc));
    out[idx] = f2bf(acc * sg);
}

// ---------------- block-diagonal headwise q,k,v -> bf16 buffers ----------------
__global__ __launch_bounds__(256) void qkv_k(const short* __restrict__ xc, const float* __restrict__ xmz,
                                             const float* __restrict__ qw, const float* __restrict__ kw,
                                             const float* __restrict__ vw,
                                             short* __restrict__ qb, short* __restrict__ kb, short* __restrict__ vb) {
    int idx = blockIdx.x * 256 + threadIdx.x;   // B*S*I
    int c = idx & 127; int bs = idx >> 7;
    int n = c >> 2, o = c & 3;
    const short* xcr = xc + (size_t)bs * cI + n * 4;
    const float* xmr = xmz + (size_t)bs * 256 + n * 4;
    const float* qwp = qw + n * 16 + o * 4;
    const float* kwp = kw + n * 16 + o * 4;
    const float* vwp = vw + n * 16 + o * 4;
    float aq = 0, ak = 0, av = 0;
#pragma unroll
    for (int i = 0; i < 4; ++i) {
        float a = bf2f(xcr[i]), m = xmr[i];
        aq += a * qwp[i]; ak += a * kwp[i]; av += m * vwp[i];
    }
    qb[idx] = f2bf(aq); kb[idx] = f2bf(ak); vb[idx] = f2bf(av);
}

// ---------------- weight hi/lo split for MFMA gates (runs once, all 3 layers) ----------------
// wsp[j][hl][o][392]: Whi = bf16(W), Wlo = bf16(W - Whi): Whi+Wlo carries ~17
// mantissa bits so MFMA(G,Whi)+MFMA(G,Wlo) == fp32-weight GEMV to within noise.
__global__ __launch_bounds__(256) void wsplit_k(const float* __restrict__ igw, const float* __restrict__ fgw,
                                                short* __restrict__ wsp) {
    int idx = blockIdx.x * 256 + threadIdx.x;   // 3*32*392
    if (idx >= 3 * 32 * 392) return;
    int j = idx / (32 * 392);
    int rem = idx - j * (32 * 392);
    int r = rem / 392, k = rem - r * 392;
    int hl = r >> 4, o = r & 15;
    short out = 0;
    if (k < 384) {
        const float* wsrc = (o < 8) ? (igw + ((size_t)j * 8 + o) * 384)
                                    : (fgw + ((size_t)j * 8 + (o - 8)) * 384);
        float w = wsrc[k];
        short hi = f2bf(w);
        out = (hl == 0) ? hi : f2bf(w - bf2f(hi));
    }
    wsp[idx] = out;
}

// ---------------- input/forget gate pre-activations v5: MFMA ----------------
// 64 rows/block, 4 waves x 16-row tiles; K=384 = 12 chunks of 32; per wave
// 24 MFMA (hi+lo W). G rows are [q|k|v] bf16 staged to LDS; stride 392 shorts
// (784B) -> 2-way bank aliasing only (free).
constexpr int GW = 392;
__global__ __launch_bounds__(256, 2) void gates_k(const short* __restrict__ qb, const short* __restrict__ kb,
                                                  const short* __restrict__ vb, const short* __restrict__ wsp,
                                                  const float* __restrict__ igb, const float* __restrict__ fgb,
                                                  float* __restrict__ ipb, float* __restrict__ fpb) {
    __shared__ short sG[64 * GW];
    __shared__ short sW[32 * GW];
    int row0 = blockIdx.x * 64;
    int tid = threadIdx.x;

    for (int i = tid; i < 32 * 49; i += 256) {        // W hi+lo (incl. zero pad)
        int r = i / 49, c8 = i - r * 49;
        *(short8v*)&sW[r * GW + c8 * 8] = ((const short8v*)(wsp + r * GW))[c8];
    }
    for (int i = tid; i < 64 * 48; i += 256) {        // G rows = [q|k|v]
        int r = i / 48, c8 = i - r * 48;
        size_t gr = (size_t)(row0 + r) * cI;
        const short8v* src = (c8 < 16) ? (const short8v*)(qb + gr) + c8
                           : (c8 < 32) ? (const short8v*)(kb + gr) + (c8 - 16)
                                       : (const short8v*)(vb + gr) + (c8 - 32);
        *(short8v*)&sG[r * GW + c8 * 8] = *src;
    }
    __syncthreads();

    int wid = tid >> 6, lane = tid & 63;
    int colL = lane & 15, grp = lane >> 4;
    const short* gRow = sG + (wid * 16 + colL) * GW;   // A row = lane&15
    const short* wHi  = sW + colL * GW;                // B col = lane&15
    const short* wLo  = sW + (16 + colL) * GW;

    f32x4 acc = {0.f, 0.f, 0.f, 0.f};
    for (int kc = 0; kc < 12; ++kc) {
        short8v a  = *(const short8v*)(gRow + kc * 32 + grp * 8);
        short8v bh = *(const short8v*)(wHi + kc * 32 + grp * 8);
        short8v bl = *(const short8v*)(wLo + kc * 32 + grp * 8);
        acc = __builtin_amdgcn_mfma_f32_16x16x32_bf16(a, bh, acc, 0, 0, 0);
        acc = __builtin_amdgcn_mfma_f32_16x16x32_bf16(a, bl, acc, 0, 0, 0);
    }

    int o = colL;                     // D col = lane&15 = output
    int hh = o & 7, wch = o >> 3;
    float bias = wch ? fgb[hh] : igb[hh];
    float* dst = wch ? fpb : ipb;
#pragma unroll
    for (int j = 0; j < 4; ++j) {     // D row = grp*4+j
        int grow = row0 + wid * 16 + grp * 4 + j;
        int bb = grow >> 8, ss = grow & 255;
        dst[(size_t)(bb * cNH + hh) * cS + ss] = acc[j] + bias;
    }
}

// ---------------- fused mLSTM attention v9: native-K 32x32 MFMA, bf16 in/out ----------------
constexpr int QKW = 24;    // Q/K row width (shorts), rows 48B (16B-aligned)
constexpr int VTW = 264;   // Vt row width (528B, 16B-aligned)
constexpr int CBW = 40;    // C chunk row width (80B, 16B-aligned)

__global__ __launch_bounds__(256, 3) void attn_k(const short* __restrict__ qg, const short* __restrict__ kg,
                                                 const short* __restrict__ vg, const float* __restrict__ ipg,
                                                 const float* __restrict__ fpg, short* __restrict__ hatt) {
    int bh = blockIdx.x; int b = bh >> 3, h = bh & 7;
    int tid = threadIdx.x;
    int wid = tid >> 6, lane = tid & 63;
    int colL = lane & 15, grp = lane >> 4;       // PV-space
    int col32 = lane & 31, hi = lane >> 5;       // QK-space

    __shared__ float sEA[cS], sEMx[cS], sFlr[cS];
    __shared__ short sQ[cS * QKW], sK[cS * QKW];
    __shared__ short sVt[cMDH * VTW];
    __shared__ short sCb[4][32 * CBW];
    __shared__ float sSum[4][32];

    // --- gate scans; store derived sEA / sEMx / sFlr directly ---
    {
        const float4 fp4 = ((const float4*)(fpg + (size_t)bh * cS))[lane];
        const float4 ip4 = ((const float4*)(ipg + (size_t)bh * cS))[lane];
        float fpa[4] = {fp4.x, fp4.y, fp4.z, fp4.w};
        float ipa[4] = {ip4.x, ip4.y, ip4.z, ip4.w};
        float p[4];
        float run = 0.f;
#pragma unroll
        for (int i = 0; i < 4; ++i) {
            float xx = fpa[i];
            float lsg = fminf(xx, 0.f) - log1pf(expf(-fabsf(xx)));
            run += lsg; p[i] = run;
        }
        float cum = p[3];
#pragma unroll
        for (int off = 1; off < 64; off <<= 1) { float t = __shfl_up(cum, off); if (lane >= off) cum += t; }
        float excl = cum - p[3];
        float aa[4], fcv4[4];
#pragma unroll
        for (int i = 0; i < 4; ++i) {
            fcv4[i] = excl + p[i];
            aa[i] = ipa[i] - fcv4[i];
            sEA[lane * 4 + i] = __expf(aa[i]);
        }
        float mq[4]; mq[0] = aa[0];
#pragma unroll
        for (int i = 1; i < 4; ++i) mq[i] = fmaxf(mq[i - 1], aa[i]);
        float cm = mq[3];
#pragma unroll
        for (int off = 1; off < 64; off <<= 1) { float t = __shfl_up(cm, off); if (lane >= off) cm = fmaxf(cm, t); }
        float exm = __shfl_up(cm, 1);
        if (lane == 0) exm = -3.0e38f;
#pragma unroll
        for (int i = 0; i < 4; ++i) {
            float Mx = fmaxf(exm, mq[i]);
            sEMx[lane * 4 + i] = 0.25f * __expf(-Mx);
            sFlr[lane * 4 + i] = __expf(-(fcv4[i] + Mx));
        }
    }

    // --- stage Q,K (straight copies) and V^T (copy-transpose) ---
    {
        int t = tid;
        const short8v* qp = (const short8v*)(qg + ((size_t)(b * cS) + t) * cI + h * cMDH);
        const short8v* kp = (const short8v*)(kg + ((size_t)(b * cS) + t) * cI + h * cMDH);
        const short8v* vp = (const short8v*)(vg + ((size_t)(b * cS) + t) * cI + h * cMDH);
        *(short8v*)(sQ + t * QKW) = qp[0];
        *(short8v*)(sQ + t * QKW + 8) = qp[1];
        *(short8v*)(sK + t * QKW) = kp[0];
        *(short8v*)(sK + t * QKW + 8) = kp[1];
        short8v v0 = vp[0], v1 = vp[1];
#pragma unroll
        for (int d = 0; d < 8; ++d) sVt[d * VTW + t] = v0[d];
#pragma unroll
        for (int d = 0; d < 8; ++d) sVt[(8 + d) * VTW + t] = v1[d];
    }
    __syncthreads();

    short* Cb = sCb[wid];
    float* Sm = sSum[wid];
    const int tiles2[2] = {wid, 7 - wid};        // 32-row s-tiles, balanced

    for (int sti = 0; sti < 2; ++sti) {
        int st = tiles2[sti];
        int s0 = st * 32;

        short8v aQ = *(const short8v*)(sQ + (s0 + col32) * QKW + hi * 8);
        int r16[16]; float eMx16[16];
#pragma unroll
        for (int reg = 0; reg < 16; ++reg) {
            int r = (reg & 3) + 8 * (reg >> 2) + 4 * hi;
            r16[reg] = r;
            eMx16[reg] = sEMx[s0 + r];
        }
        float sum16[16];
#pragma unroll
        for (int reg = 0; reg < 16; ++reg) sum16[reg] = 0.f;
        f32x4 hacc0 = {0.f, 0.f, 0.f, 0.f}, hacc1 = {0.f, 0.f, 0.f, 0.f};

        for (int tt = 0; tt <= st; ++tt) {
            int t0 = tt * 32;
            short8v bK = *(const short8v*)(sK + (t0 + col32) * QKW + hi * 8);
            f32x16 zz = {0.f, 0.f, 0.f, 0.f, 0.f, 0.f, 0.f, 0.f,
                         0.f, 0.f, 0.f, 0.f, 0.f, 0.f, 0.f, 0.f};
            f32x16 d = __builtin_amdgcn_mfma_f32_32x32x16_bf16(aQ, bK, zz, 0, 0, 0);
            float ea = sEA[t0 + col32];
            bool diag = (tt == st);
#pragma unroll
            for (int reg = 0; reg < 16; ++reg) {
                float v = d[reg] * (ea * eMx16[reg]);
                if (diag && col32 > r16[reg]) v = 0.f;
                sum16[reg] += v;
                Cb[r16[reg] * CBW + col32] = f2bf(v);
            }
            short8v bV  = *(const short8v*)(sVt + colL * VTW + t0 + grp * 8);
            short8v aC0 = *(const short8v*)(Cb + colL * CBW + grp * 8);
            hacc0 = __builtin_amdgcn_mfma_f32_16x16x32_bf16(aC0, bV, hacc0, 0, 0, 0);
            short8v aC1 = *(const short8v*)(Cb + (16 + colL) * CBW + grp * 8);
            hacc1 = __builtin_amdgcn_mfma_f32_16x16x32_bf16(aC1, bV, hacc1, 0, 0, 0);
        }

#pragma unroll
        for (int reg = 0; reg < 16; ++reg) {
            float s = sum16[reg];
#pragma unroll
            for (int m = 1; m < 32; m <<= 1) s += __shfl_xor(s, m);
            sum16[reg] = s;
        }
        if (col32 == 0) {
#pragma unroll
            for (int reg = 0; reg < 16; ++reg) Sm[r16[reg]] = sum16[reg];
        }

#pragma unroll
        for (int sub = 0; sub < 2; ++sub) {
            f32x4 hacc = sub ? hacc1 : hacc0;
#pragma unroll
            for (int j = 0; j < 4; ++j) {
                int rloc = sub * 16 + grp * 4 + j;
                int sr = s0 + rloc;
                float sC = Sm[rloc];
                float nrm = fmaxf(fabsf(sC), sFlr[sr]) + 1e-6f;
                hatt[((size_t)(b * cS) + sr) * cI + h * cMDH + colL] = f2bf(hacc[j] / nrm);
            }
        }
    }
}

// ---------------- fused multihead-norm + gate + down-projection + residual ----------------
__global__ __launch_bounds__(320) void down_mhn_k(const short* __restrict__ hatt, const short* __restrict__ xc,
                                                  const float* __restrict__ xmz, const float* __restrict__ mhnw,
                                                  const float* __restrict__ skip, const float* __restrict__ dw,
                                                  float* __restrict__ h) {
    __shared__ float yl[8 * 128];
    int row0 = blockIdx.x * 8;
    int tid = threadIdx.x;
    for (int i = tid; i < 128; i += 320) {       // 1024 bf16 = 128 short8v
        short8v v = ((const short8v*)(hatt + (size_t)row0 * cI))[i];
        float* dst = &yl[i * 8];
#pragma unroll
        for (int j = 0; j < 8; ++j) dst[j] = bf2f(v[j]);
    }
    __syncthreads();
    if (tid < 64) {
        int r = tid >> 3, hh = tid & 7;
        int row = row0 + r;
        float* g = yl + r * 128 + hh * 16;
        float xv[16];
        float mu = 0.f;
#pragma unroll
        for (int d = 0; d < 16; ++d) { xv[d] = g[d]; mu += xv[d]; }
        mu *= (1.f / 16);
        float va = 0.f;
#pragma unroll
        for (int d = 0; d < 16; ++d) { float dd = xv[d] - mu; va += dd * dd; }
        va *= (1.f / 16);
        float rs = rsqrtf(va + 1e-5f);
        const short* xcr = xc + (size_t)row * cI + hh * 16;
        const float* zr  = xmz + (size_t)row * 256 + 128 + hh * 16;
#pragma unroll
        for (int d = 0; d < 16; ++d) {
            int i = hh * 16 + d;
            float z = zr[d];
            float sg = 1.f / (1.f + __expf(-z));
            g[d] = ((xv[d] - mu) * rs * mhnw[i] + skip[i] * bf2f(xcr[d])) * (z * sg);
        }
    }
    __syncthreads();
    int r = tid / 40, e = tid % 40;
    const float* dr = dw + e * cI;
    const float* yr = yl + r * cI;
    float acc = 0.f;
    for (int i = 0; i < cI; ++i) acc += yr[i] * dr[i];
    h[(size_t)(row0 + r) * cE + e] += acc;
}

// ---------------- plain row LayerNorm (E=40) ----------------
__global__ __launch_bounds__(256) void ln_rows_k(const float* __restrict__ h, const float* __restrict__ w,
                                                 float* __restrict__ out) {
    int rid = blockIdx.x * 256 + threadIdx.x;
    const float* r = h + (size_t)rid * cE;
    float mu = 0;
    for (int k = 0; k < cE; ++k) mu += r[k];
    mu *= (1.f / cE);
    float va = 0;
    for (int k = 0; k < cE; ++k) { float d = r[k] - mu; va += d * d; }
    va *= (1.f / cE);
    float rs = rsqrtf(va + 1e-5f);
    float* o = out + (size_t)rid * cE;
    for (int k = 0; k < cE; ++k) o[k] = (r[k] - mu) * rs * w[k];
}

// ---------------- sLSTM gate pre-activations; gall layout (S, B*NH, E=5, G=4) ----------------
__global__ __launch_bounds__(256) void sgates_k(const float* __restrict__ xcs, const float* __restrict__ ln1,
                                                const float* __restrict__ wi, const float* __restrict__ wf,
                                                const float* __restrict__ wz, const float* __restrict__ wo,
                                                float* __restrict__ gall) {
    int idx = blockIdx.x * 256 + threadIdx.x;   // S*1024*5*4
    int g = idx & 3; int r1 = idx >> 2;
    int e = r1 % 5; int r2 = r1 / 5;
    int bh = r2 & 1023; int s = r2 >> 10;
    int b = bh >> 3, h = bh & 7;
    const float* in = (g < 2) ? xcs : ln1;
    const float* w = (g == 0) ? wi : (g == 1) ? wf : (g == 2) ? wz : wo;
    const float* ir = in + ((size_t)(b * cS) + s) * cE + h * cDH;
    const float* wp = w + h * 25 + e * 5;
    float acc = 0.f;
#pragma unroll
    for (int i = 0; i < 5; ++i) acc += ir[i] * wp[i];
    gall[idx] = acc;
}

// ---------------- sLSTM sequential scan: 8 chains per wave ----------------
__global__ __launch_bounds__(64) void scan_k(const float* __restrict__ gall, const float* __restrict__ R,
                                             const float* __restrict__ bias, const float* __restrict__ mhnw,
                                             float* __restrict__ hbuf) {
    int lane = threadIdx.x;
    int grp = lane >> 3;
    int e = lane & 7;
    int ee = e < 5 ? e : 4;
    int bh = blockIdx.x * 8 + grp;
    int h = bh & 7;

    __shared__ float sOut[8][1285];

    float Rr[4][5];
#pragma unroll
    for (int g = 0; g < 4; ++g)
#pragma unroll
        for (int d = 0; d < 5; ++d) Rr[g][d] = R[h * 100 + g * 25 + d * 5 + ee];
    float bg[4];
#pragma unroll
    for (int g = 0; g < 4; ++g) bg[g] = bias[h * 20 + g * 5 + ee];
    float wmh = mhnw[h * 5 + ee];

    const float4* gp = (const float4*)gall + ((size_t)bh * 5 + ee);

    float4 rg[16];
#pragma unroll
    for (int j = 0; j < 16; ++j) rg[j] = gp[(size_t)j * 5120];

    float cstate = 0.f, nstate = 0.f, mstate = 0.f;
    float hs0 = 0.f, hs1 = 0.f, hs2 = 0.f, hs3 = 0.f, hs4 = 0.f;

    for (int t = 0; t < cS; t += 16) {
#pragma unroll
        for (int j = 0; j < 16; ++j) {
            float4 g4 = rg[j];
            rg[j] = gp[(size_t)(t + j + 16) * 5120];

            float ir = g4.x + bg[0], fr = g4.y + bg[1], zr = g4.z + bg[2], orr = g4.w + bg[3];
            ir = fmaf(hs0, Rr[0][0], ir); fr = fmaf(hs0, Rr[1][0], fr);
            zr = fmaf(hs0, Rr[2][0], zr); orr = fmaf(hs0, Rr[3][0], orr);
            ir = fmaf(hs1, Rr[0][1], ir); fr = fmaf(hs1, Rr[1][1], fr);
            zr = fmaf(hs1, Rr[2][1], zr); orr = fmaf(hs1, Rr[3][1], orr);
            ir = fmaf(hs2, Rr[0][2], ir); fr = fmaf(hs2, Rr[1][2], fr);
            zr = fmaf(hs2, Rr[2][2], zr); orr = fmaf(hs2, Rr[3][2], orr);
            ir = fmaf(hs3, Rr[0][3], ir); fr = fmaf(hs3, Rr[1][3], fr);
            zr = fmaf(hs3, Rr[2][3], zr); orr = fmaf(hs3, Rr[3][3], orr);
            ir = fmaf(hs4, Rr[0][4], ir); fr = fmaf(hs4, Rr[1][4], fr);
            zr = fmaf(hs4, Rr[2][4], zr); orr = fmaf(hs4, Rr[3][4], orr);

            float lsg = fminf(fr, 0.f) - __logf(1.f + __expf(-fabsf(fr)));
            float lfm = mstate + lsg;
            float mn = fmaxf(ir, lfm);
            float ig = __expf(ir - mn), fg = __expf(lfm - mn);
            float th = 1.f - 2.f * __builtin_amdgcn_rcpf(__expf(2.f * zr) + 1.f);
            float cn = fg * cstate + ig * th;
            float nn = fg * nstate + ig;
            float sg = __builtin_amdgcn_rcpf(1.f + __expf(-orr));
            float hn = sg * cn * __builtin_amdgcn_rcpf(nn);
            cstate = cn; nstate = nn; mstate = mn;

            hs0 = BC8(hn, 0); hs1 = BC8(hn, 1); hs2 = BC8(hn, 2);
            hs3 = BC8(hn, 3); hs4 = BC8(hn, 4);
            float mu = ((hs0 + hs1) + (hs2 + hs3) + hs4) * 0.2f;
            float d0 = hs0 - mu, d1 = hs1 - mu, d2 = hs2 - mu, d3 = hs3 - mu, d4 = hs4 - mu;
            float va = (d0 * d0 + d1 * d1 + d2 * d2 + d3 * d3 + d4 * d4) * 0.2f;
            float rs = __builtin_amdgcn_rsqf(va + 1e-5f);
            if (e < 5) sOut[grp][(t + j) * 5 + e] = (hn - mu) * rs * wmh;
        }
    }
    __syncthreads();

    for (int i = lane; i < 8 * 1280; i += 64) {
        int c = i / 1280;
        int r = i - c * 1280;
        int tt = r / 5, e2 = r - tt * 5;
        int bh2 = blockIdx.x * 8 + c;
        int b2 = bh2 >> 3, h2 = bh2 & 7;
        float* hp = hbuf + ((size_t)b2 * cS + tt) * cE + h2 * cDH + e2;
        *hp += sOut[c][r];
    }
}

// ---------------- FFN fused: LN + up-proj + GELU gate + down-proj + residual ----------------
__global__ __launch_bounds__(256) void ff_k(float* __restrict__ h, const float* __restrict__ lnw,
                                            const float* __restrict__ upw, const float* __restrict__ dnw) {
    __shared__ float lnr[8][cE];
    __shared__ float ffr[8][64];
    int row0 = blockIdx.x * 8;
    int tid = threadIdx.x;
    if (tid < 8) {
        const float* r = h + (size_t)(row0 + tid) * cE;
        float mu = 0;
        for (int k = 0; k < cE; ++k) mu += r[k];
        mu *= (1.f / cE);
        float va = 0;
        for (int k = 0; k < cE; ++k) { float d = r[k] - mu; va += d * d; }
        va *= (1.f / cE);
        float rs = rsqrtf(va + 1e-5f);
        for (int k = 0; k < cE; ++k) lnr[tid][k] = (r[k] - mu) * rs * lnw[k];
    }
    __syncthreads();
    {
        int r = tid >> 5;            // 0..7
        int f0 = (tid & 31) * 2;
#pragma unroll
        for (int ff = 0; ff < 2; ++ff) {
            int f = f0 + ff;
            float a = 0, u = 0;
            const float* wa = upw + f * cE;
            const float* wu = upw + (64 + f) * cE;
            for (int k = 0; k < cE; ++k) {
                float xv = lnr[r][k];
                a = fmaf(xv, wa[k], a);
                u = fmaf(xv, wu[k], u);
            }
            float g = 0.5f * a * (1.f + erff(a * 0.70710678118f));
            ffr[r][f] = g * u;
        }
    }
    __syncthreads();
    for (int i = tid; i < 320; i += 256) {
        int r = i / 40, e = i - r * 40;
        const float* dr = dnw + e * 64;
        const float* fr = ffr[r];
        float acc = 0.f;
        for (int k = 0; k < 64; ++k) acc = fmaf(fr[k], dr[k], acc);
        h[(size_t)(row0 + r) * cE + e] += acc;
    }
}

// ---------------- final LN + out projection ----------------
__global__ __launch_bounds__(256) void final_k(const float* __restrict__ h, const float* __restrict__ lnw,
                                               const float* __restrict__ ow, const float* __restrict__ ob,
                                               float* __restrict__ out) {
    int rid = blockIdx.x * 256 + threadIdx.x;
    const float* r = h + (size_t)rid * cE;
    float mu = 0;
    for (int k = 0; k < cE; ++k) mu += r[k];
    mu *= (1.f / cE);
    float va = 0;
    for (int k = 0; k < cE; ++k) { float d = r[k] - mu; va += d * d; }
    va *= (1.f / cE);
    float rs = rsqrtf(va + 1e-5f);
    float acc = ob[0];
    for (int k = 0; k < cE; ++k) acc += (r[k] - mu) * rs * lnw[k] * ow[k];
    out[rid] = acc;
}

extern "C" void kernel_launch(void* const* d_in, const int* in_sizes, int n_in,
                              void* d_out, int out_size, void* d_ws, size_t ws_size,
                              hipStream_t stream) {
    const float* x        = (const float*)d_in[0];
    const float* in_w     = (const float*)d_in[1];
    const float* in_b     = (const float*)d_in[2];
    const float* m_ln_w   = (const float*)d_in[3];
    const float* m_up_w   = (const float*)d_in[4];
    const float* m_conv_w = (const float*)d_in[5];
    const float* m_conv_b = (const float*)d_in[6];
    const float* m_q_w    = (const float*)d_in[7];
    const float* m_k_w    = (const float*)d_in[8];
    const float* m_v_w    = (const float*)d_in[9];
    const float* m_ig_w   = (const float*)d_in[10];
    const float* m_ig_b   = (const float*)d_in[11];
    const float* m_fg_w   = (const float*)d_in[12];
    const float* m_fg_b   = (const float*)d_in[13];
    const float* m_mhn_w  = (const float*)d_in[14];
    const float* m_skip   = (const float*)d_in[15];
    const float* m_down_w = (const float*)d_in[16];
    const float* s_ln1_w  = (const float*)d_in[17];
    const float* s_conv_w = (const float*)d_in[18];
    const float* s_conv_b = (const float*)d_in[19];
    const float* s_wi     = (const float*)d_in[20];
    const float* s_wf     = (const float*)d_in[21];
    const float* s_wz     = (const float*)d_in[22];
    const float* s_wo     = (const float*)d_in[23];
    const float* s_R      = (const float*)d_in[24];
    const float* s_bias   = (const float*)d_in[25];
    const float* s_mhn_w  = (const float*)d_in[26];
    const float* s_ln2_w  = (const float*)d_in[27];
    const float* s_ff_up  = (const float*)d_in[28];
    const float* s_ff_dn  = (const float*)d_in[29];
    const float* post_ln_w= (const float*)d_in[30];
    const float* out_w    = (const float*)d_in[31];
    const float* out_b    = (const float*)d_in[32];

    float* ws   = (float*)d_ws;
    float* h    = ws;                      // 1,310,720 floats
    float* xmz  = h + 1310720;             // 8,388,608 floats
    short* xcb  = (short*)(xmz + 8388608); // 4,194,304 shorts
    short* qb   = xcb + 4194304;           // 4,194,304 shorts
    short* kb   = qb + 4194304;            // 4,194,304 shorts
    short* vb   = kb + 4194304;            // 4,194,304 shorts
    float* ipb  = (float*)(vb + 4194304);  //   262,144 floats
    float* fpb  = ipb + 262144;            //   262,144 floats
    short* hatt = (short*)(fpb + 262144);  // 4,194,304 shorts
    short* wsp  = hatt + 4194304;          //    37,632 shorts (3 layers x [2][16][392])
    // slstm aliases into the xmz region (dead there)
    float* lnbuf = xmz;
    float* xcs   = xmz + 1310720;
    float* gall  = xmz + 2621440;

    wsplit_k<<<147, 256, 0, stream>>>(m_ig_w, m_fg_w, wsp);
    init_k<<<5120, 256, 0, stream>>>(x, in_w, in_b, h);

    auto mlstm = [&](int j) {
        ln_up_k<<<2048, 256, 0, stream>>>(h, m_ln_w + j * cE, m_up_w + (size_t)j * 256 * cE, xmz);
        conv_silu_bf_k<<<16384, 256, 0, stream>>>(xmz, m_conv_w + j * cI * cK, m_conv_b + j * cI, xcb);
        qkv_k<<<16384, 256, 0, stream>>>(xcb, xmz, m_q_w + j * 512, m_k_w + j * 512, m_v_w + j * 512, qb, kb, vb);
        gates_k<<<512, 256, 0, stream>>>(qb, kb, vb, wsp + (size_t)j * 32 * GW,
                                         m_ig_b + j * cNH, m_fg_b + j * cNH, ipb, fpb);
        attn_k<<<1024, 256, 0, stream>>>(qb, kb, vb, ipb, fpb, hatt);
        down_mhn_k<<<4096, 320, 0, stream>>>(hatt, xcb, xmz, m_mhn_w + j * cI, m_skip + j * cI,
                                             m_down_w + j * cE * cI, h);
    };

    mlstm(0);

    ln_rows_k<<<128, 256, 0, stream>>>(h, s_ln1_w, lnbuf);
    conv_silu_k<40><<<5120, 256, 0, stream>>>(lnbuf, 40, s_conv_w, s_conv_b, xcs);
    sgates_k<<<20480, 256, 0, stream>>>(xcs, lnbuf, s_wi, s_wf, s_wz, s_wo, gall);
    scan_k<<<128, 64, 0, stream>>>(gall, s_R, s_bias, s_mhn_w, h);

    ff_k<<<4096, 256, 0, stream>>>(h, s_ln2_w, s_ff_up, s_ff_dn);

    mlstm(1);
    mlstm(2);

    final_k<<<128, 256, 0, stream>>>(h, post_ln_w, out_w, out_b, (float*)d_out);
}